// Round 9
// baseline (556.338 us; speedup 1.0000x reference)
//
#include <hip/hip_runtime.h>
#include <hip/hip_bf16.h>

// SCConv: two-level radix binning (pass A: 8-bucket groups with run-reserved
// scatter; pass B: per-group 1024-bin LDS-staged counting sort to
// (bucket,row) order with coalesced flush, emitting rowoff/bend + a
// per-bucket row permutation sorted by row length), 3 fused powcat-GEMMs on
// MFMA (split-bf16 3-term), then ONE merged streaming spmm over all output
// segments (depth-4 predicated pipelined gathers, length-balanced waves).

#define RPB 128
#define COL_MASK 0x7FFFFu
#define LROW_SH 19
#define DID_SH 26
#define MAXNB 4352
#define MAXNG 544
#define GRID_BIN 256
#define SPMM_GRID 2048

// sort_grp phasing: destination positions are processed in windows of
// SORT_PH; LDS capacity covers PH + max single-bin size.
#define SORT_PH     16384
#define SORT_LOG    14
#define SORT_MAXBIN 2048
#define SORT_CAP    (SORT_PH + SORT_MAXBIN)   // 18432 entries = 144 KB
#define MAXPH 8

typedef __attribute__((ext_vector_type(8))) short short8;
typedef __attribute__((ext_vector_type(4))) float f32x4;

__device__ __forceinline__ int   ntld_i(const int* p)   { return __builtin_nontemporal_load(p); }
__device__ __forceinline__ float ntld_f(const float* p) { return __builtin_nontemporal_load(p); }
__device__ __forceinline__ float4 ntld_f4(const float* p) {
    const unsigned long long* q = (const unsigned long long*)p;
    unsigned long long a = __builtin_nontemporal_load(q);
    unsigned long long b = __builtin_nontemporal_load(q + 1);
    float4 v;
    v.x = __uint_as_float((unsigned)a);
    v.y = __uint_as_float((unsigned)(a >> 32));
    v.z = __uint_as_float((unsigned)b);
    v.w = __uint_as_float((unsigned)(b >> 32));
    return v;
}
__device__ __forceinline__ void ntst_f4(float* p, float4 v) {
    unsigned long long a = (unsigned long long)__float_as_uint(v.x)
                         | ((unsigned long long)__float_as_uint(v.y) << 32);
    unsigned long long b = (unsigned long long)__float_as_uint(v.z)
                         | ((unsigned long long)__float_as_uint(v.w) << 32);
    unsigned long long* q = (unsigned long long*)p;
    __builtin_nontemporal_store(a, q);
    __builtin_nontemporal_store(b, q + 1);
}

// ---------------- bf16 helpers (RNE) --------------------------------------
__device__ __forceinline__ unsigned short f2bf(float f) {
    unsigned u = __float_as_uint(f);
    unsigned r = u + 0x7FFFu + ((u >> 16) & 1u);
    return (unsigned short)(r >> 16);
}

__device__ __forceinline__ void split8(float4 a0, float4 a1, short8& hi, short8& lo) {
    float v[8] = {a0.x, a0.y, a0.z, a0.w, a1.x, a1.y, a1.z, a1.w};
    #pragma unroll
    for (int e = 0; e < 8; ++e) {
        unsigned short h = f2bf(v[e]);
        float hf = __uint_as_float((unsigned)h << 16);
        hi[e] = (short)h;
        lo[e] = (short)f2bf(v[e] - hf);
    }
}

// ---------------- W -> MFMA B-fragment precompute (once per launch) -------
// Frag layout per set (16384 ushorts = 32KB):
//   [kk(4)][nf(4)][h(2: hi,lo)][lane(64)][e(8)]
// lane l, elem e: k = kk*32 + 8*(l>>4) + e ; col = nf*16 + (l&15)
struct WAll { const float* w[7]; };

__global__ __launch_bounds__(256) void winit(WAll wa, unsigned short* __restrict__ frags)
{
    const int s = blockIdx.x;
    const float* __restrict__ W = wa.w[s];
    unsigned short* __restrict__ out = frags + (size_t)s * 16384;
    for (int slot = threadIdx.x; slot < 1024; slot += 256) {
        const int l  = slot & 63;
        const int nf = (slot >> 6) & 3;
        const int kk = slot >> 8;
        const int col = nf * 16 + (l & 15);
        const int kb  = kk * 32 + 8 * (l >> 4);
        short8 vh, vl;
        #pragma unroll
        for (int e = 0; e < 8; ++e) {
            float w = W[(size_t)(kb + e) * 64 + col];
            unsigned short h = f2bf(w);
            float hf = __uint_as_float((unsigned)h << 16);
            vh[e] = (short)h;
            vl[e] = (short)f2bf(w - hf);
        }
        *(short8*)(out + ((size_t)((kk * 4 + nf) * 2 + 0) * 64 + l) * 8) = vh;
        *(short8*)(out + ((size_t)((kk * 4 + nf) * 2 + 1) * 64 + l) * 8) = vl;
    }
}

// ---------------- MFMA powcat-GEMM (up to 3 weight sets per X) ------------
__device__ __forceinline__ void mfma_set(
    const short8 Ah[4], const short8 Al[4],
    const unsigned short* __restrict__ F, const float* __restrict__ bias,
    unsigned short* __restrict__ D, int nrows, int row0w, int l)
{
    const int lg = l >> 4, lr = l & 15;
    const short8* __restrict__ Fv = (const short8*)F;
    f32x4 acc[4];
    #pragma unroll
    for (int nf = 0; nf < 4; ++nf) {
        float b = bias[nf * 16 + lr];
        f32x4 bi = {b, b, b, b};
        acc[nf] = bi;
    }
    #pragma unroll
    for (int kk = 0; kk < 4; ++kk) {
        #pragma unroll
        for (int nf = 0; nf < 4; ++nf) {
            short8 bh = Fv[((kk * 4 + nf) * 2 + 0) * 64 + l];
            short8 bl = Fv[((kk * 4 + nf) * 2 + 1) * 64 + l];
            acc[nf] = __builtin_amdgcn_mfma_f32_16x16x32_bf16(Ah[kk], bh, acc[nf], 0, 0, 0);
            acc[nf] = __builtin_amdgcn_mfma_f32_16x16x32_bf16(Al[kk], bh, acc[nf], 0, 0, 0);
            acc[nf] = __builtin_amdgcn_mfma_f32_16x16x32_bf16(Ah[kk], bl, acc[nf], 0, 0, 0);
        }
    }
    #pragma unroll
    for (int nf = 0; nf < 4; ++nf) {
        #pragma unroll
        for (int j = 0; j < 4; ++j) {
            int row = row0w + lg * 4 + j;   // C/D: col=lane&15, row=4*(lane>>4)+reg
            if (row < nrows)
                D[(size_t)row * 64 + nf * 16 + lr] = f2bf(acc[nf][j]);
        }
    }
}

__global__ __launch_bounds__(256) void gemm_powcat_mfma(
    const float* __restrict__ X, int nrows, int nsets,
    const unsigned short* __restrict__ F0, const float* __restrict__ b0, unsigned short* __restrict__ D0,
    const unsigned short* __restrict__ F1, const float* __restrict__ b1, unsigned short* __restrict__ D1,
    const unsigned short* __restrict__ F2, const float* __restrict__ b2, unsigned short* __restrict__ D2)
{
    __shared__ float Xs[64][68];   // pad stride 68 -> balanced LDS banks
    const int tid = threadIdx.x;
    const int row0 = blockIdx.x * 64;

    #pragma unroll
    for (int it = 0; it < 4; ++it) {
        int idx = tid + it * 256;
        int r = idx >> 4, c4 = idx & 15;
        float4 v = make_float4(0.f, 0.f, 0.f, 0.f);
        if (row0 + r < nrows)
            v = ntld_f4(X + (size_t)(row0 + r) * 64 + c4 * 4);
        *(float4*)&Xs[r][c4 * 4] = v;
    }
    __syncthreads();

    const int w = tid >> 6, l = tid & 63;
    const int lg = l >> 4, lr = l & 15;

    // A-frags (shared across all weight sets): powcat K=128 = [X | X^2]
    short8 Ah[4], Al[4];
    #pragma unroll
    for (int kk = 0; kk < 4; ++kk) {
        const float* p = &Xs[w * 16 + lr][(kk & 1) * 32 + 8 * lg];
        float4 a0 = *(const float4*)p;
        float4 a1 = *(const float4*)(p + 4);
        if (kk >= 2) {
            a0.x *= a0.x; a0.y *= a0.y; a0.z *= a0.z; a0.w *= a0.w;
            a1.x *= a1.x; a1.y *= a1.y; a1.z *= a1.z; a1.w *= a1.w;
        }
        split8(a0, a1, Ah[kk], Al[kk]);
    }

    const int row0w = row0 + w * 16;
    mfma_set(Ah, Al, F0, b0, D0, nrows, row0w, l);
    if (nsets > 1) mfma_set(Ah, Al, F1, b1, D1, nrows, row0w, l);
    if (nsets > 2) mfma_set(Ah, Al, F2, b2, D2, nrows, row0w, l);
}

// ---------------- 7-slot flat COO view ------------------------------------
struct Bin7 {
    const int *r0, *r1, *r2, *r3, *r4, *r5, *r6;
    const int *c0, *c1, *c2, *c3, *c4, *c5, *c6;
    const float *v0, *v1, *v2, *v3, *v4, *v5, *v6;
    int p1, p2, p3, p4, p5, p6, p7;   // cumulative prefix ends
    int t0, t1, t2, t3, t4, t5, t6;   // bucket-tile base per slot
};

struct Ent { int r; int tb; unsigned cw; float v; };

template<bool FULL>
__device__ __forceinline__ Ent decode(const Bin7& B, int i) {
    Ent e;
    if (i < B.p1) {
        int li = i;
        e.r = ntld_i(B.r0 + li); e.tb = B.t0;
        if (FULL) { e.cw = (unsigned)ntld_i(B.c0 + li) | (0u << DID_SH); e.v = ntld_f(B.v0 + li); }
    } else if (i < B.p2) {
        int li = i - B.p1;
        e.r = ntld_i(B.r1 + li); e.tb = B.t1;
        if (FULL) { e.cw = (unsigned)ntld_i(B.c1 + li) | (1u << DID_SH); e.v = ntld_f(B.v1 + li); }
    } else if (i < B.p3) {
        int li = i - B.p2;
        e.r = ntld_i(B.r2 + li); e.tb = B.t2;
        if (FULL) { e.cw = (unsigned)ntld_i(B.c2 + li) | (2u << DID_SH); e.v = ntld_f(B.v2 + li); }
    } else if (i < B.p4) {
        int li = i - B.p3;
        e.r = ntld_i(B.r3 + li); e.tb = B.t3;
        if (FULL) { e.cw = (unsigned)ntld_i(B.c3 + li) | (3u << DID_SH); e.v = ntld_f(B.v3 + li); }
    } else if (i < B.p5) {
        int li = i - B.p4;
        e.r = ntld_i(B.r4 + li); e.tb = B.t4;
        if (FULL) { e.cw = (unsigned)ntld_i(B.c4 + li) | (4u << DID_SH); e.v = ntld_f(B.v4 + li); }
    } else if (i < B.p6) {
        int li = i - B.p5;
        e.r = ntld_i(B.r5 + li); e.tb = B.t5;
        if (FULL) { e.cw = (unsigned)ntld_i(B.c5 + li) | (5u << DID_SH); e.v = ntld_f(B.v5 + li); }
    } else {
        int li = i - B.p6;
        e.r = ntld_i(B.r6 + li); e.tb = B.t6;
        if (FULL) { e.cw = (unsigned)ntld_i(B.c6 + li) | (6u << DID_SH); e.v = ntld_f(B.v6 + li); }
    }
    return e;
}

// ---------------- group histogram (8 buckets per group) -------------------
__global__ __launch_bounds__(1024) void bhist_grp(
    Bin7 B, int* __restrict__ gcount, int NG, int chunk)
{
    __shared__ int h[MAXNG];
    for (int i = threadIdx.x; i < NG; i += 1024) h[i] = 0;
    __syncthreads();
    const int s = blockIdx.x * chunk;
    int e = s + chunk;  if (e > B.p7) e = B.p7;
    for (int i = s + threadIdx.x; i < e; i += 1024) {
        Ent en = decode<false>(B, i);
        atomicAdd(&h[(en.tb + (en.r >> 7)) >> 3], 1);
    }
    __syncthreads();
    for (int i = threadIdx.x; i < NG; i += 1024)
        if (h[i]) atomicAdd(&gcount[i], h[i]);
}

// ---------------- pass A: run-reserved scatter into group segments --------
// payA word: col(19) | lrow(7)<<19 | (bucket&7)<<26 | did<<29
__global__ __launch_bounds__(1024) void scatter_grp(
    Bin7 B, int* __restrict__ gcur, uint2* __restrict__ payA,
    int NG, int chunk)
{
    __shared__ int lbase[MAXNG];
    __shared__ int lcur[MAXNG];
    for (int i = threadIdx.x; i < NG; i += 1024) lcur[i] = 0;
    __syncthreads();
    const int s = blockIdx.x * chunk;
    int e = s + chunk;  if (e > B.p7) e = B.p7;

    for (int i = s + threadIdx.x; i < e; i += 1024) {
        Ent en = decode<false>(B, i);
        atomicAdd(&lcur[(en.tb + (en.r >> 7)) >> 3], 1);
    }
    __syncthreads();
    for (int i = threadIdx.x; i < NG; i += 1024) {
        int c = lcur[i];
        lbase[i] = c ? atomicAdd(&gcur[i], c) : 0;
        lcur[i] = 0;
    }
    __syncthreads();
    for (int i = s + threadIdx.x; i < e; i += 1024) {
        Ent en = decode<true>(B, i);
        int b = en.tb + (en.r >> 7);
        int g = b >> 3;
        int pos = lbase[g] + atomicAdd(&lcur[g], 1);
        unsigned col = en.cw & COL_MASK;
        unsigned did = en.cw >> DID_SH;
        unsigned cwA = col | ((unsigned)(en.r & 127) << LROW_SH)
                     | ((unsigned)(b & 7) << 26) | (did << 29);
        payA[pos] = make_uint2(cwA, __float_as_uint(en.v));
    }
}

// ---------------- pass B: per-group 1024-bin LDS-staged counting sort -----
// Sort key = bits 19..28 of payA word (lrow | (bucket&7)<<7). Entries are
// scattered into LDS at their sorted position (phased by destination window
// of SORT_PH), then flushed coalesced. Emits rowoff (row start positions),
// bend per bucket, and rowperm: per-bucket row order sorted by descending
// row length (so the 4 quarter-waves sharing a wave get equal-length rows).
__global__ __launch_bounds__(1024) void sort_grp(
    const uint2* __restrict__ payA, const int* __restrict__ goff,
    const int* __restrict__ gcur, int* __restrict__ rowoff,
    int* __restrict__ bend, uint2* __restrict__ payB,
    unsigned char* __restrict__ rowperm, int NBtot)
{
    __shared__ uint2 lpay[SORT_CAP];      // 144 KB
    __shared__ int cnt[1024];             // hist, then cur
    __shared__ int off[1024];             // exclusive scan (immutable)
    __shared__ unsigned char cnts8[1024]; // clamped counts for ranking
    __shared__ int wsum[16];
    __shared__ int phstart[MAXPH + 1];
    __shared__ int s_nph, s_maxbin;

    const int g = blockIdx.x;
    const int tid = threadIdx.x;
    const int seg0 = goff[g], seg1 = gcur[g];
    const int n = seg1 - seg0;

    cnt[tid] = 0;
    if (tid == 0) s_maxbin = 0;
    __syncthreads();
    for (int i = seg0 + tid; i < seg1; i += 1024) {
        unsigned w = __builtin_nontemporal_load(&payA[i].x);
        atomicAdd(&cnt[(w >> 19) & 1023], 1);
    }
    __syncthreads();

    // block-wide exclusive scan over 1024 bins + max bin size
    const int lane = tid & 63, wv = tid >> 6;
    const int tot = cnt[tid];
    atomicMax(&s_maxbin, tot);
    cnts8[tid] = (unsigned char)(tot > 255 ? 255 : tot);
    int x = tot;
    #pragma unroll
    for (int o = 1; o < 64; o <<= 1) {
        int y = __shfl_up(x, o);
        if (lane >= o) x += y;
    }
    if (lane == 63) wsum[wv] = x;
    __syncthreads();
    if (tid < 16) {
        int ss = wsum[tid];
        #pragma unroll
        for (int o = 1; o < 16; o <<= 1) {
            int y = __shfl_up(ss, o, 16);
            if (tid >= o) ss += y;
        }
        wsum[tid] = ss;
    }
    __syncthreads();
    const int excl = (x - tot) + ((wv == 0) ? 0 : wsum[wv - 1]);
    off[tid] = excl;
    rowoff[(size_t)g * 1024 + tid] = seg0 + excl;
    {
        int b = g * 8 + (tid >> 7);
        if (b < NBtot && (tid & 127) == 127) bend[b] = seg0 + excl + tot;
    }
    __syncthreads();   // off[] + cnts8[] complete
    cnt[tid] = excl;   // cnt becomes cur
    {
        int p = excl >> SORT_LOG;
        int pprev = (tid == 0) ? -1 : (off[tid - 1] >> SORT_LOG);
        for (int q = pprev + 1; q <= p && q <= MAXPH; ++q) phstart[q] = excl;
        if (tid == 1023) s_nph = p + 1;
    }

    // rank rows by descending length within each 128-row bucket (bijective:
    // ties broken by index). rowperm[bucket*128 + rank] = local row.
    {
        const int myr = tid & 127, b0 = tid & ~127;
        const unsigned char myc = cnts8[tid];
        int rank = 0;
        #pragma unroll 8
        for (int r = 0; r < 128; ++r) {
            unsigned char c = cnts8[b0 + r];
            rank += (c > myc) || (c == myc && r < myr);
        }
        rowperm[(size_t)g * 1024 + b0 + rank] = (unsigned char)myr;
    }
    __syncthreads();

    const int nph = s_nph;
    if (n <= 0) return;

    if (s_maxbin <= SORT_MAXBIN && nph <= MAXPH) {
        for (int ph = 0; ph < nph; ++ph) {
            const int ps = phstart[ph];
            const int pe = (ph + 1 < nph) ? phstart[ph + 1] : n;
            for (int i = seg0 + tid; i < seg1; i += 1024) {
                unsigned long long pv = __builtin_nontemporal_load(
                    (const unsigned long long*)(payA + i));
                unsigned w = (unsigned)pv;
                int bin = (w >> 19) & 1023;
                if ((off[bin] >> SORT_LOG) == ph) {
                    int pos = atomicAdd(&cnt[bin], 1);
                    lpay[pos - ps] = make_uint2(w, (unsigned)(pv >> 32));
                }
            }
            __syncthreads();
            for (int k = tid; k < pe - ps; k += 1024) {
                uint2 pv = lpay[k];
                unsigned cw = (pv.x & 0x03FFFFFFu) | ((pv.x >> 29) << 26);
                unsigned long long o2 = (unsigned long long)cw
                                      | ((unsigned long long)pv.y << 32);
                __builtin_nontemporal_store(o2,
                    (unsigned long long*)(payB + seg0 + ps + k));
            }
            __syncthreads();
        }
    } else {
        // fallback: direct global scatter (pathological bin sizes only)
        for (int i = seg0 + tid; i < seg1; i += 1024) {
            unsigned long long pv = __builtin_nontemporal_load(
                (const unsigned long long*)(payA + i));
            unsigned w = (unsigned)pv;
            int bin = (w >> 19) & 1023;
            int pos = seg0 + atomicAdd(&cnt[bin], 1);
            unsigned cw = (w & 0x03FFFFFFu) | ((w >> 29) << 26);
            payB[pos] = make_uint2(cw, (unsigned)(pv >> 32));
        }
    }
}

// ---------------- shfl-based single-block exclusive scan ------------------
__global__ __launch_bounds__(1024) void scan_small(
    const int* __restrict__ in, int* __restrict__ boff,
    int* __restrict__ bcur, int n)
{
    __shared__ int wsum[16];
    __shared__ int carry;
    const int tid = threadIdx.x, lane = tid & 63, wv = tid >> 6;
    if (tid == 0) carry = 0;
    __syncthreads();
    for (int base = 0; base < n; base += 4096) {
        int i = base + tid * 4;
        int v0 = (i + 0 < n) ? in[i + 0] : 0;
        int v1 = (i + 1 < n) ? in[i + 1] : 0;
        int v2 = (i + 2 < n) ? in[i + 2] : 0;
        int v3 = (i + 3 < n) ? in[i + 3] : 0;
        int tsum = v0 + v1 + v2 + v3;
        int x = tsum;
        #pragma unroll
        for (int off = 1; off < 64; off <<= 1) {
            int y = __shfl_up(x, off);
            if (lane >= off) x += y;
        }
        if (lane == 63) wsum[wv] = x;
        int c0 = carry;
        __syncthreads();
        if (tid < 16) {
            int ss = wsum[tid];
            #pragma unroll
            for (int off = 1; off < 16; off <<= 1) {
                int y = __shfl_up(ss, off, 16);
                if (tid >= off) ss += y;
            }
            wsum[tid] = ss;
        }
        __syncthreads();
        int wpre = (wv == 0) ? 0 : wsum[wv - 1];
        int excl = c0 + wpre + (x - tsum);
        if (i + 0 < n) { boff[i + 0] = excl; bcur[i + 0] = excl; } excl += v0;
        if (i + 1 < n) { boff[i + 1] = excl; bcur[i + 1] = excl; } excl += v1;
        if (i + 2 < n) { boff[i + 2] = excl; bcur[i + 2] = excl; } excl += v2;
        if (i + 3 < n) { boff[i + 3] = excl; bcur[i + 3] = excl; }
        __syncthreads();
        if (tid == 0) carry = c0 + wsum[15];
        __syncthreads();
    }
}

// ---------------- streaming row accumulate (depth-4, predicated) ----------
__device__ __forceinline__ float mval(uint2 p, int didMask) {
    int did = (int)(p.x >> DID_SH) & 7;
    return ((didMask >> did) & 1) ? __uint_as_float(p.y) : 0.f;
}
__device__ __forceinline__ uint2 dgather(uint2 p, int l,
    const unsigned short* const* dptr)
{
    const uint2* Dg = reinterpret_cast<const uint2*>(dptr[(p.x >> DID_SH) & 7]);
    return Dg[(size_t)(p.x & COL_MASK) * 16 + l];
}
__device__ __forceinline__ void facc(float4& a, float v, uint2 d) {
    a.x = fmaf(v, __uint_as_float((d.x & 0xFFFFu) << 16), a.x);
    a.y = fmaf(v, __uint_as_float(d.x & 0xFFFF0000u), a.y);
    a.z = fmaf(v, __uint_as_float((d.y & 0xFFFFu) << 16), a.z);
    a.w = fmaf(v, __uint_as_float(d.y & 0xFFFF0000u), a.w);
}

__device__ __forceinline__ float4 row_accum(
    const uint2* __restrict__ payB, int js, int je,
    const unsigned short* const* dptr, int l, int didMask)
{
    float4 a = make_float4(0.f, 0.f, 0.f, 0.f);
    const int n = je - js;
    if (n <= 0) return a;
    const uint2* base = payB + js;
    const uint2 Z = make_uint2(0u, 0u);

    // prologue: predicated loads (missing slots zero-filled -> fma adds 0)
    float v0, v1 = 0.f, v2 = 0.f, v3 = 0.f;
    uint2 d0, d1 = Z, d2 = Z, d3 = Z;
    {
        uint2 p = base[0]; v0 = mval(p, didMask); d0 = dgather(p, l, dptr);
        if (n > 1) { p = base[1]; v1 = mval(p, didMask); d1 = dgather(p, l, dptr); }
        if (n > 2) { p = base[2]; v2 = mval(p, didMask); d2 = dgather(p, l, dptr); }
        if (n > 3) { p = base[3]; v3 = mval(p, didMask); d3 = dgather(p, l, dptr); }
    }

    int i = 0;
    while (true) {
        const bool more = (i + 4 < n);
        float w0 = 0.f, w1 = 0.f, w2 = 0.f, w3 = 0.f;
        uint2 e0 = Z, e1 = Z, e2 = Z, e3 = Z;
        if (more) {
            // issue next quad's gathers before waiting on d0..d3 -> 4 in flight
            uint2 q = base[i + 4]; w0 = mval(q, didMask); e0 = dgather(q, l, dptr);
            if (i + 5 < n) { q = base[i + 5]; w1 = mval(q, didMask); e1 = dgather(q, l, dptr); }
            if (i + 6 < n) { q = base[i + 6]; w2 = mval(q, didMask); e2 = dgather(q, l, dptr); }
            if (i + 7 < n) { q = base[i + 7]; w3 = mval(q, didMask); e3 = dgather(q, l, dptr); }
        }
        facc(a, v0, d0);
        facc(a, v1, d1);
        facc(a, v2, d2);
        facc(a, v3, d3);
        if (!more) break;
        i += 4;
        v0 = w0; v1 = w1; v2 = w2; v3 = w3;
        d0 = e0; d1 = e1; d2 = e2; d3 = e3;
    }
    return a;
}

// ---------------- merged streaming SpMM over all segments (tier 1) --------
__global__ __launch_bounds__(256) void spmm_stream_all(
    const uint2* __restrict__ payB, const int* __restrict__ rowoff,
    const int* __restrict__ bend, const unsigned char* __restrict__ rowperm,
    const unsigned short* __restrict__ d0, const unsigned short* __restrict__ d1,
    const unsigned short* __restrict__ d2, const unsigned short* __restrict__ d3,
    const unsigned short* __restrict__ d4, const unsigned short* __restrict__ d5,
    const unsigned short* __restrict__ d6,
    float* __restrict__ out, int NB0, int NB01, int NBall,
    int N0, int N1, int N2)
{
    __shared__ const unsigned short* dptr[8];
    const int tid = threadIdx.x;
    if (tid < 8) {
        const unsigned short* tbl[8] = {d0, d1, d2, d3, d4, d5, d6, d0};
        dptr[tid] = tbl[tid];
    }
    __syncthreads();

    const int qw = tid >> 4, l = tid & 15;

    for (int t = blockIdx.x; t < NBall; t += gridDim.x) {
        int tb, nrows; float scale; float* oseg;
        if (t < NB0)       { tb = 0;    nrows = N0; oseg = out;                          scale = 0.5f; }
        else if (t < NB01) { tb = NB0;  nrows = N1; oseg = out + (size_t)N0 * 64;        scale = 1.0f / 3.0f; }
        else               { tb = NB01; nrows = N2; oseg = out + (size_t)(N0 + N1) * 64; scale = 0.5f; }
        const int row0 = (t - tb) * RPB;
        const int rbase = t * RPB;
        const int bendt = bend[t];
        const unsigned char* perm = rowperm + (size_t)t * RPB;

        #pragma unroll 1
        for (int rr = 0; rr < 8; ++rr) {
            const int lr = perm[rr * 16 + qw];   // length-balanced wave rows
            const int row = row0 + lr;
            const int js = rowoff[rbase + lr];
            const int je = (lr == 127) ? bendt : rowoff[rbase + lr + 1];
            float4 a = row_accum(payB, js, je, dptr, l, 0x7F);
            if (row < nrows) {
                float* o = oseg + (size_t)row * 64 + l * 4;
                a.x = fmaxf(a.x, 0.f) * scale;
                a.y = fmaxf(a.y, 0.f) * scale;
                a.z = fmaxf(a.z, 0.f) * scale;
                a.w = fmaxf(a.w, 0.f) * scale;
                ntst_f4(o, a);
            }
        }
    }
}

// ---------------- per-segment streaming SpMM (tier 2) ---------------------
__global__ __launch_bounds__(256) void spmm_stream7(
    const uint2* __restrict__ payB, const int* __restrict__ rowoff,
    const int* __restrict__ bend, const unsigned char* __restrict__ rowperm,
    const unsigned short* __restrict__ d0, const unsigned short* __restrict__ d1,
    const unsigned short* __restrict__ d2, const unsigned short* __restrict__ d3,
    const unsigned short* __restrict__ d4, const unsigned short* __restrict__ d5,
    const unsigned short* __restrict__ d6,
    float* __restrict__ out, int tile0, int nrows,
    int firstWrite, int doRelu, float scale, int didMask)
{
    __shared__ const unsigned short* dptr[8];
    const int tid = threadIdx.x;
    if (tid < 8) {
        const unsigned short* tbl[8] = {d0, d1, d2, d3, d4, d5, d6, d0};
        dptr[tid] = tbl[tid];
    }
    __syncthreads();

    const int t = tile0 + blockIdx.x;
    const int qw = tid >> 4, l = tid & 15;
    const int row0 = blockIdx.x * RPB;
    const int rbase = t * RPB;
    const int bendt = bend[t];
    const unsigned char* perm = rowperm + (size_t)t * RPB;

    #pragma unroll 1
    for (int rr = 0; rr < 8; ++rr) {
        const int lr = perm[rr * 16 + qw];
        const int row = row0 + lr;
        const int js = rowoff[rbase + lr];
        const int je = (lr == 127) ? bendt : rowoff[rbase + lr + 1];
        float4 a = row_accum(payB, js, je, dptr, l, didMask);

        if (row < nrows) {
            float* o = out + (size_t)row * 64 + l * 4;
            if (!firstWrite) {
                float4 cur = *reinterpret_cast<float4*>(o);
                a.x += cur.x; a.y += cur.y; a.z += cur.z; a.w += cur.w;
            }
            if (doRelu) {
                a.x = fmaxf(a.x, 0.f) * scale;
                a.y = fmaxf(a.y, 0.f) * scale;
                a.z = fmaxf(a.z, 0.f) * scale;
                a.w = fmaxf(a.w, 0.f) * scale;
            }
            ntst_f4(o, a);
        }
    }
}

extern "C" void kernel_launch(void* const* d_in, const int* in_sizes, int n_in,
                              void* d_out, int out_size, void* d_ws, size_t ws_size,
                              hipStream_t stream)
{
    const float* X0 = (const float*)d_in[0];
    const float* X1 = (const float*)d_in[1];
    const float* X2 = (const float*)d_in[2];
    const int N0 = in_sizes[0] / 64;
    const int N1 = in_sizes[1] / 64;
    const int N2 = in_sizes[2] / 64;

    auto Wp = [&](int i) { return (const float*)d_in[24 + 2 * i]; };
    auto bp = [&](int i) { return (const float*)d_in[25 + 2 * i]; };
    auto Sr = [&](int i) { return (const int*)d_in[3 + 3 * i]; };
    auto Sc = [&](int i) { return (const int*)d_in[4 + 3 * i]; };
    auto Sv = [&](int i) { return (const float*)d_in[5 + 3 * i]; };
    auto Sn = [&](int i) { return in_sizes[3 + 3 * i]; };

    const size_t offY1 = (size_t)N0 * 64;
    const size_t offY2 = (size_t)(N0 + N1) * 64;
    const float TH = 1.0f / 3.0f;

    const int NB0 = (N0 + RPB - 1) / RPB;
    const int NB1 = (N1 + RPB - 1) / RPB;
    const int NB2 = (N2 + RPB - 1) / RPB;

    float* out = (float*)d_out;
    auto align256 = [](size_t x) { return (x + 255) & ~(size_t)255; };

    // -------- W fragment precompute (all 7 sets, once) --------
    const size_t FRAG_SET = 16384;  // ushorts per set (32 KB)
    const size_t fragB = align256(7 * FRAG_SET * sizeof(unsigned short));
    if (ws_size <= fragB) return;   // pathological; cannot run
    unsigned short* wfrags = (unsigned short*)d_ws;
    char* ws = (char*)d_ws + fragB;
    const size_t ws_avail = ws_size - fragB;
    auto wf = [&](int i) { return wfrags + (size_t)i * FRAG_SET; };

    WAll wa;
    for (int i = 0; i < 7; ++i) wa.w[i] = Wp(i);
    winit<<<7, 256, 0, stream>>>(wa, wfrags);

    // -------- tier 1: everything at once --------
    const int NBall = NB0 + NB1 + NB2;
    const int NGall = (NBall + 7) / 8;
    const int nnzAll = Sn(0)+Sn(1)+Sn(2)+Sn(3)+Sn(4)+Sn(5)+Sn(6);
    const size_t payT1 = align256((size_t)nnzAll * sizeof(uint2));
    const size_t cntT1 = align256((size_t)(NBall + 8) * sizeof(int));
    const size_t rowT1 = align256((size_t)NGall * 1024 * sizeof(int));
    const size_t permT1 = align256((size_t)NGall * 1024);
    const size_t denseT1 = ((size_t)2*N0 + 3*N1 + 2*N2) * 64 * sizeof(unsigned short);
    const size_t regionT1 = denseT1 > payT1 ? denseT1 : payT1;  // dense ∪ payA
    const size_t needT1 = payT1 + 4 * cntT1 + rowT1 + permT1 + regionT1;

    if (ws_avail >= needT1 && NBall <= MAXNB) {
        uint2* payB  = (uint2*)ws;
        int* goff    = (int*)(ws + payT1);
        int* gcur    = (int*)(ws + payT1 + 1 * cntT1);
        int* bend    = (int*)(ws + payT1 + 2 * cntT1);
        int* gcount  = (int*)(ws + payT1 + 3 * cntT1);
        int* rowoff  = (int*)(ws + payT1 + 4 * cntT1);
        unsigned char* rowperm = (unsigned char*)(ws + payT1 + 4 * cntT1 + rowT1);
        char* region = ws + payT1 + 4 * cntT1 + rowT1 + permT1;
        uint2* payA  = (uint2*)region;                // dead after sort_grp
        unsigned short* db = (unsigned short*)region; // gemms write after sort_grp
        unsigned short* dn2n = db;
        unsigned short* de2n = dn2n + (size_t)N0 * 64;
        unsigned short* dn2e = de2n + (size_t)N1 * 64;
        unsigned short* de2e = dn2e + (size_t)N0 * 64;
        unsigned short* dt2e = de2e + (size_t)N1 * 64;
        unsigned short* de2t = dt2e + (size_t)N2 * 64;
        unsigned short* dt2t = de2t + (size_t)N1 * 64;

        Bin7 B;
        // did: 0 n2n(L0) 1 e2n(D1invB1) 2 n2e(D2B1TD1inv) 3 e2e(L1) 4 t2e(B2D3) 5 e2t(B2TD2inv) 6 t2t(L2)
        B.r0 = Sr(0); B.c0 = Sc(0); B.v0 = Sv(0);
        B.r1 = Sr(3); B.c1 = Sc(3); B.v1 = Sv(3);
        B.r2 = Sr(4); B.c2 = Sc(4); B.v2 = Sv(4);
        B.r3 = Sr(1); B.c3 = Sc(1); B.v3 = Sv(1);
        B.r4 = Sr(6); B.c4 = Sc(6); B.v4 = Sv(6);
        B.r5 = Sr(5); B.c5 = Sc(5); B.v5 = Sv(5);
        B.r6 = Sr(2); B.c6 = Sc(2); B.v6 = Sv(2);
        B.p1 = Sn(0);
        B.p2 = B.p1 + Sn(3);
        B.p3 = B.p2 + Sn(4);
        B.p4 = B.p3 + Sn(1);
        B.p5 = B.p4 + Sn(6);
        B.p6 = B.p5 + Sn(5);
        B.p7 = B.p6 + Sn(2);
        B.t0 = 0;   B.t1 = 0;
        B.t2 = NB0; B.t3 = NB0; B.t4 = NB0;
        B.t5 = NB0 + NB1; B.t6 = NB0 + NB1;

        const int chunk = (B.p7 + GRID_BIN - 1) / GRID_BIN;
        hipMemsetAsync(gcount, 0, (size_t)NGall * sizeof(int), stream);
        bhist_grp<<<GRID_BIN, 1024, 0, stream>>>(B, gcount, NGall, chunk);
        scan_small<<<1, 1024, 0, stream>>>(gcount, goff, gcur, NGall);
        scatter_grp<<<GRID_BIN, 1024, 0, stream>>>(B, gcur, payA, NGall, chunk);
        sort_grp<<<NGall, 1024, 0, stream>>>(payA, goff, gcur, rowoff, bend,
                                             payB, rowperm, NBall);

        gemm_powcat_mfma<<<(N0 + 63) / 64, 256, 0, stream>>>(
            X0, N0, 2,
            wf(0), bp(0), dn2n,
            wf(1), bp(1), dn2e,
            wf(0), bp(0), dn2n);
        gemm_powcat_mfma<<<(N1 + 63) / 64, 256, 0, stream>>>(
            X1, N1, 3,
            wf(3), bp(3), de2n,
            wf(2), bp(2), de2e,
            wf(4), bp(4), de2t);
        gemm_powcat_mfma<<<(N2 + 63) / 64, 256, 0, stream>>>(
            X2, N2, 2,
            wf(5), bp(5), dt2e,
            wf(6), bp(6), dt2t,
            wf(5), bp(5), dt2e);

        const int grid = NBall < SPMM_GRID ? NBall : SPMM_GRID;
        spmm_stream_all<<<grid, 256, 0, stream>>>(payB, rowoff, bend, rowperm,
            dn2n, de2n, dn2e, de2e, dt2e, de2t, dt2t,
            out, NB0, NB0 + NB1, NBall, N0, N1, N2);
        return;
    }

    // -------- tier 2: two-group phased layout (same kernels) --------
    const int NBtotA = NB0 + NB2;
    const int NBmax = NBtotA > NB1 ? NBtotA : NB1;
    const int NGmax = (NBmax + 7) / 8;
    const int nnzA = Sn(0) + Sn(3) + Sn(5) + Sn(2);
    const int nnzB = Sn(4) + Sn(6) + Sn(1);
    const int nnzMax = nnzA > nnzB ? nnzA : nnzB;

    const size_t payBsz = align256((size_t)nnzMax * sizeof(uint2));
    const size_t cntB = align256((size_t)(NBmax + 8) * sizeof(int));
    const size_t rowB = align256((size_t)NGmax * 1024 * sizeof(int));
    const size_t permB = align256((size_t)NGmax * 1024);
    const size_t denseOff = payBsz + 4 * cntB + rowB + permB;

    uint2* bpayB = (uint2*)ws;
    int* goff    = (int*)(ws + payBsz);
    int* gcur    = (int*)(ws + payBsz + 1 * cntB);
    int* bend    = (int*)(ws + payBsz + 2 * cntB);
    int* gcount  = (int*)(ws + payBsz + 3 * cntB);
    int* rowoff  = (int*)(ws + payBsz + 4 * cntB);
    unsigned char* rowperm = (unsigned char*)(ws + payBsz + 4 * cntB + rowB);
    unsigned short* dense = (unsigned short*)(ws + denseOff);
    uint2* payA  = (uint2*)dense;   // transient, dead before gemms write dense

    const size_t need_full = denseOff +
        ((size_t)N0 + N2 + N1) * 64 * sizeof(unsigned short);
    const bool fullB = (ws_avail >= need_full);

    // ---- group A: did 0=n2n(Y0) 1=e2n(Y0) 2=e2t(Y2) 3=t2t(Y2)
    {
        Bin7 B;
        B.r0 = Sr(0); B.c0 = Sc(0); B.v0 = Sv(0);
        B.r1 = Sr(3); B.c1 = Sc(3); B.v1 = Sv(3);
        B.r2 = Sr(5); B.c2 = Sc(5); B.v2 = Sv(5);
        B.r3 = Sr(2); B.c3 = Sc(2); B.v3 = Sv(2);
        B.r4 = B.r3; B.c4 = B.c3; B.v4 = B.v3;
        B.r5 = B.r3; B.c5 = B.c3; B.v5 = B.v3;
        B.r6 = B.r3; B.c6 = B.c3; B.v6 = B.v3;
        B.p1 = Sn(0);
        B.p2 = B.p1 + Sn(3);
        B.p3 = B.p2 + Sn(5);
        B.p4 = B.p3 + Sn(2);
        B.p5 = B.p4; B.p6 = B.p4; B.p7 = B.p4;
        B.t0 = 0; B.t1 = 0; B.t2 = NB0; B.t3 = NB0;
        B.t4 = NB0; B.t5 = NB0; B.t6 = NB0;

        const int NGA = (NBtotA + 7) / 8;
        const int chunk = (B.p7 + GRID_BIN - 1) / GRID_BIN;
        hipMemsetAsync(gcount, 0, (size_t)NGA * sizeof(int), stream);
        bhist_grp<<<GRID_BIN, 1024, 0, stream>>>(B, gcount, NGA, chunk);
        scan_small<<<1, 1024, 0, stream>>>(gcount, goff, gcur, NGA);
        scatter_grp<<<GRID_BIN, 1024, 0, stream>>>(B, gcur, payA, NGA, chunk);
        sort_grp<<<NGA, 1024, 0, stream>>>(payA, goff, gcur, rowoff, bend,
                                           bpayB, rowperm, NBtotA);

        unsigned short* dn2n = dense;
        unsigned short* de2n = dense + (size_t)N0 * 64;
        gemm_powcat_mfma<<<(N0 + 63) / 64, 256, 0, stream>>>(
            X0, N0, 1, wf(0), bp(0), dn2n,
            wf(0), bp(0), dn2n, wf(0), bp(0), dn2n);
        gemm_powcat_mfma<<<(N1 + 63) / 64, 256, 0, stream>>>(
            X1, N1, 1, wf(3), bp(3), de2n,
            wf(3), bp(3), de2n, wf(3), bp(3), de2n);
        spmm_stream7<<<NB0, 256, 0, stream>>>(bpayB, rowoff, bend, rowperm,
            dn2n, de2n, dn2n, dn2n, dn2n, dn2n, dn2n,
            out, 0, N0, 1, 1, 0.5f, 0x7F);

        unsigned short* de2t = dense;
        unsigned short* dt2t = dense + (size_t)N1 * 64;
        gemm_powcat_mfma<<<(N1 + 63) / 64, 256, 0, stream>>>(
            X1, N1, 1, wf(4), bp(4), de2t,
            wf(4), bp(4), de2t, wf(4), bp(4), de2t);
        gemm_powcat_mfma<<<(N2 + 63) / 64, 256, 0, stream>>>(
            X2, N2, 1, wf(6), bp(6), dt2t,
            wf(6), bp(6), dt2t, wf(6), bp(6), dt2t);
        spmm_stream7<<<NB2, 256, 0, stream>>>(bpayB, rowoff, bend, rowperm,
            de2t, de2t, de2t, dt2t, de2t, de2t, de2t,
            out + offY2, NB0, N2, 1, 1, 0.5f, 0x7F);
    }

    // ---- group B (Y1): did 0=n2e 1=t2e 2=e2e
    {
        Bin7 B;
        B.r0 = Sr(4); B.c0 = Sc(4); B.v0 = Sv(4);
        B.r1 = Sr(6); B.c1 = Sc(6); B.v1 = Sv(6);
        B.r2 = Sr(1); B.c2 = Sc(1); B.v2 = Sv(1);
        B.r3 = B.r2; B.c3 = B.c2; B.v3 = B.v2;
        B.r4 = B.r2; B.c4 = B.c2; B.v4 = B.v2;
        B.r5 = B.r2; B.c5 = B.c2; B.v5 = B.v2;
        B.r6 = B.r2; B.c6 = B.c2; B.v6 = B.v2;
        B.p1 = Sn(4);
        B.p2 = B.p1 + Sn(6);
        B.p3 = B.p2 + Sn(1);
        B.p4 = B.p3; B.p5 = B.p3; B.p6 = B.p3; B.p7 = B.p3;
        B.t0 = 0; B.t1 = 0; B.t2 = 0; B.t3 = 0; B.t4 = 0; B.t5 = 0; B.t6 = 0;

        const int NGB = (NB1 + 7) / 8;
        const int chunk = (B.p7 + GRID_BIN - 1) / GRID_BIN;
        hipMemsetAsync(gcount, 0, (size_t)NGB * sizeof(int), stream);
        bhist_grp<<<GRID_BIN, 1024, 0, stream>>>(B, gcount, NGB, chunk);
        scan_small<<<1, 1024, 0, stream>>>(gcount, goff, gcur, NGB);
        scatter_grp<<<GRID_BIN, 1024, 0, stream>>>(B, gcur, payA, NGB, chunk);
        sort_grp<<<NGB, 1024, 0, stream>>>(payA, goff, gcur, rowoff, bend,
                                           bpayB, rowperm, NB1);

        if (fullB) {
            unsigned short* dn2e = dense;
            unsigned short* dt2e = dense + (size_t)N0 * 64;
            unsigned short* de2e = dense + ((size_t)N0 + N2) * 64;
            gemm_powcat_mfma<<<(N0 + 63) / 64, 256, 0, stream>>>(
                X0, N0, 1, wf(1), bp(1), dn2e,
                wf(1), bp(1), dn2e, wf(1), bp(1), dn2e);
            gemm_powcat_mfma<<<(N2 + 63) / 64, 256, 0, stream>>>(
                X2, N2, 1, wf(5), bp(5), dt2e,
                wf(5), bp(5), dt2e, wf(5), bp(5), dt2e);
            gemm_powcat_mfma<<<(N1 + 63) / 64, 256, 0, stream>>>(
                X1, N1, 1, wf(2), bp(2), de2e,
                wf(2), bp(2), de2e, wf(2), bp(2), de2e);
            spmm_stream7<<<NB1, 256, 0, stream>>>(bpayB, rowoff, bend, rowperm,
                dn2e, dt2e, de2e, dn2e, dn2e, dn2e, dn2e,
                out + offY1, 0, N1, 1, 1, TH, 0x7F);
        } else {
            unsigned short* dn2e = dense;
            unsigned short* dt2e = dense + (size_t)N0 * 64;
            gemm_powcat_mfma<<<(N0 + 63) / 64, 256, 0, stream>>>(
                X0, N0, 1, wf(1), bp(1), dn2e,
                wf(1), bp(1), dn2e, wf(1), bp(1), dn2e);
            gemm_powcat_mfma<<<(N2 + 63) / 64, 256, 0, stream>>>(
                X2, N2, 1, wf(5), bp(5), dt2e,
                wf(5), bp(5), dt2e, wf(5), bp(5), dt2e);
            spmm_stream7<<<NB1, 256, 0, stream>>>(bpayB, rowoff, bend, rowperm,
                dn2e, dt2e, dn2e, dn2e, dn2e, dn2e, dn2e,
                out + offY1, 0, N1, 1, 0, 0.f, 0x3);
            unsigned short* de2e = dense;
            gemm_powcat_mfma<<<(N1 + 63) / 64, 256, 0, stream>>>(
                X1, N1, 1, wf(2), bp(2), de2e,
                wf(2), bp(2), de2e, wf(2), bp(2), de2e);
            spmm_stream7<<<NB1, 256, 0, stream>>>(bpayB, rowoff, bend, rowperm,
                de2e, de2e, de2e, de2e, de2e, de2e, de2e,
                out + offY1, 0, N1, 0, 1, TH, 0x4);
        }
    }
}

// Round 10
// 510.836 us; speedup vs baseline: 1.0891x; 1.0891x over previous
//
#include <hip/hip_runtime.h>
#include <hip/hip_bf16.h>

// SCConv: two-level radix binning (pass A: 8-bucket groups with run-reserved
// scatter, folding the dense-table base into the column index; pass B:
// per-group 1024-bin LDS-staged counting sort to (bucket,row) order with
// coalesced flush, emitting rowoff/bend + a per-bucket row permutation
// sorted by row length), 3 fused powcat-GEMMs on MFMA (split-bf16 3-term),
// then ONE merged streaming spmm over all output segments (depth-2
// pipelined gathers from a single combined dense table).

#define RPB 128
#define COL_MASK 0x7FFFFu
#define LROW_SH 19
#define DID_SH 26
#define CCOL_MASK 0x1FFFFFu   // combined column: 21 bits
#define CLROW_SH 21
#define CBKT_SH 28
#define MAXNB 4352
#define MAXNG 544
#define GRID_BIN 256
#define SPMM_GRID 2048

// sort phasing: destination positions are processed in windows of SORT_PH;
// LDS capacity covers PH + max single-bin size.
#define SORT_PH     16384
#define SORT_LOG    14
#define SORT_MAXBIN 2048
#define SORT_CAP    (SORT_PH + SORT_MAXBIN)   // 18432 entries = 144 KB
#define MAXPH 8

typedef __attribute__((ext_vector_type(8))) short short8;
typedef __attribute__((ext_vector_type(4))) float f32x4;

__device__ __forceinline__ int   ntld_i(const int* p)   { return __builtin_nontemporal_load(p); }
__device__ __forceinline__ float ntld_f(const float* p) { return __builtin_nontemporal_load(p); }
__device__ __forceinline__ float4 ntld_f4(const float* p) {
    const unsigned long long* q = (const unsigned long long*)p;
    unsigned long long a = __builtin_nontemporal_load(q);
    unsigned long long b = __builtin_nontemporal_load(q + 1);
    float4 v;
    v.x = __uint_as_float((unsigned)a);
    v.y = __uint_as_float((unsigned)(a >> 32));
    v.z = __uint_as_float((unsigned)b);
    v.w = __uint_as_float((unsigned)(b >> 32));
    return v;
}
__device__ __forceinline__ void ntst_f4(float* p, float4 v) {
    unsigned long long a = (unsigned long long)__float_as_uint(v.x)
                         | ((unsigned long long)__float_as_uint(v.y) << 32);
    unsigned long long b = (unsigned long long)__float_as_uint(v.z)
                         | ((unsigned long long)__float_as_uint(v.w) << 32);
    unsigned long long* q = (unsigned long long*)p;
    __builtin_nontemporal_store(a, q);
    __builtin_nontemporal_store(b, q + 1);
}

// ---------------- bf16 helpers (RNE) --------------------------------------
__device__ __forceinline__ unsigned short f2bf(float f) {
    unsigned u = __float_as_uint(f);
    unsigned r = u + 0x7FFFu + ((u >> 16) & 1u);
    return (unsigned short)(r >> 16);
}

__device__ __forceinline__ void split8(float4 a0, float4 a1, short8& hi, short8& lo) {
    float v[8] = {a0.x, a0.y, a0.z, a0.w, a1.x, a1.y, a1.z, a1.w};
    #pragma unroll
    for (int e = 0; e < 8; ++e) {
        unsigned short h = f2bf(v[e]);
        float hf = __uint_as_float((unsigned)h << 16);
        hi[e] = (short)h;
        lo[e] = (short)f2bf(v[e] - hf);
    }
}

// ---------------- W -> MFMA B-fragment precompute (once per launch) -------
struct WAll { const float* w[7]; };

__global__ __launch_bounds__(256) void winit(WAll wa, unsigned short* __restrict__ frags)
{
    const int s = blockIdx.x;
    const float* __restrict__ W = wa.w[s];
    unsigned short* __restrict__ out = frags + (size_t)s * 16384;
    for (int slot = threadIdx.x; slot < 1024; slot += 256) {
        const int l  = slot & 63;
        const int nf = (slot >> 6) & 3;
        const int kk = slot >> 8;
        const int col = nf * 16 + (l & 15);
        const int kb  = kk * 32 + 8 * (l >> 4);
        short8 vh, vl;
        #pragma unroll
        for (int e = 0; e < 8; ++e) {
            float w = W[(size_t)(kb + e) * 64 + col];
            unsigned short h = f2bf(w);
            float hf = __uint_as_float((unsigned)h << 16);
            vh[e] = (short)h;
            vl[e] = (short)f2bf(w - hf);
        }
        *(short8*)(out + ((size_t)((kk * 4 + nf) * 2 + 0) * 64 + l) * 8) = vh;
        *(short8*)(out + ((size_t)((kk * 4 + nf) * 2 + 1) * 64 + l) * 8) = vl;
    }
}

// ---------------- MFMA powcat-GEMM (up to 3 weight sets per X) ------------
__device__ __forceinline__ void mfma_set(
    const short8 Ah[4], const short8 Al[4],
    const unsigned short* __restrict__ F, const float* __restrict__ bias,
    unsigned short* __restrict__ D, int nrows, int row0w, int l)
{
    const int lg = l >> 4, lr = l & 15;
    const short8* __restrict__ Fv = (const short8*)F;
    f32x4 acc[4];
    #pragma unroll
    for (int nf = 0; nf < 4; ++nf) {
        float b = bias[nf * 16 + lr];
        f32x4 bi = {b, b, b, b};
        acc[nf] = bi;
    }
    #pragma unroll
    for (int kk = 0; kk < 4; ++kk) {
        #pragma unroll
        for (int nf = 0; nf < 4; ++nf) {
            short8 bh = Fv[((kk * 4 + nf) * 2 + 0) * 64 + l];
            short8 bl = Fv[((kk * 4 + nf) * 2 + 1) * 64 + l];
            acc[nf] = __builtin_amdgcn_mfma_f32_16x16x32_bf16(Ah[kk], bh, acc[nf], 0, 0, 0);
            acc[nf] = __builtin_amdgcn_mfma_f32_16x16x32_bf16(Al[kk], bh, acc[nf], 0, 0, 0);
            acc[nf] = __builtin_amdgcn_mfma_f32_16x16x32_bf16(Ah[kk], bl, acc[nf], 0, 0, 0);
        }
    }
    #pragma unroll
    for (int nf = 0; nf < 4; ++nf) {
        #pragma unroll
        for (int j = 0; j < 4; ++j) {
            int row = row0w + lg * 4 + j;   // C/D: col=lane&15, row=4*(lane>>4)+reg
            if (row < nrows)
                D[(size_t)row * 64 + nf * 16 + lr] = f2bf(acc[nf][j]);
        }
    }
}

__global__ __launch_bounds__(256) void gemm_powcat_mfma(
    const float* __restrict__ X, int nrows, int nsets,
    const unsigned short* __restrict__ F0, const float* __restrict__ b0, unsigned short* __restrict__ D0,
    const unsigned short* __restrict__ F1, const float* __restrict__ b1, unsigned short* __restrict__ D1,
    const unsigned short* __restrict__ F2, const float* __restrict__ b2, unsigned short* __restrict__ D2)
{
    __shared__ float Xs[64][68];   // pad stride 68 -> balanced LDS banks
    const int tid = threadIdx.x;
    const int row0 = blockIdx.x * 64;

    #pragma unroll
    for (int it = 0; it < 4; ++it) {
        int idx = tid + it * 256;
        int r = idx >> 4, c4 = idx & 15;
        float4 v = make_float4(0.f, 0.f, 0.f, 0.f);
        if (row0 + r < nrows)
            v = ntld_f4(X + (size_t)(row0 + r) * 64 + c4 * 4);
        *(float4*)&Xs[r][c4 * 4] = v;
    }
    __syncthreads();

    const int w = tid >> 6, l = tid & 63;
    const int lg = l >> 4, lr = l & 15;

    // A-frags (shared across all weight sets): powcat K=128 = [X | X^2]
    short8 Ah[4], Al[4];
    #pragma unroll
    for (int kk = 0; kk < 4; ++kk) {
        const float* p = &Xs[w * 16 + lr][(kk & 1) * 32 + 8 * lg];
        float4 a0 = *(const float4*)p;
        float4 a1 = *(const float4*)(p + 4);
        if (kk >= 2) {
            a0.x *= a0.x; a0.y *= a0.y; a0.z *= a0.z; a0.w *= a0.w;
            a1.x *= a1.x; a1.y *= a1.y; a1.z *= a1.z; a1.w *= a1.w;
        }
        split8(a0, a1, Ah[kk], Al[kk]);
    }

    const int row0w = row0 + w * 16;
    mfma_set(Ah, Al, F0, b0, D0, nrows, row0w, l);
    if (nsets > 1) mfma_set(Ah, Al, F1, b1, D1, nrows, row0w, l);
    if (nsets > 2) mfma_set(Ah, Al, F2, b2, D2, nrows, row0w, l);
}

// ---------------- 7-slot flat COO view ------------------------------------
struct Bin7 {
    const int *r0, *r1, *r2, *r3, *r4, *r5, *r6;
    const int *c0, *c1, *c2, *c3, *c4, *c5, *c6;
    const float *v0, *v1, *v2, *v3, *v4, *v5, *v6;
    int p1, p2, p3, p4, p5, p6, p7;   // cumulative prefix ends
    int t0, t1, t2, t3, t4, t5, t6;   // bucket-tile base per slot
};

struct CBase { int b[8]; };           // per-did combined-column row base

struct Ent { int r; int tb; unsigned cw; float v; };

template<bool FULL>
__device__ __forceinline__ Ent decode(const Bin7& B, int i) {
    Ent e;
    if (i < B.p1) {
        int li = i;
        e.r = ntld_i(B.r0 + li); e.tb = B.t0;
        if (FULL) { e.cw = (unsigned)ntld_i(B.c0 + li) | (0u << DID_SH); e.v = ntld_f(B.v0 + li); }
    } else if (i < B.p2) {
        int li = i - B.p1;
        e.r = ntld_i(B.r1 + li); e.tb = B.t1;
        if (FULL) { e.cw = (unsigned)ntld_i(B.c1 + li) | (1u << DID_SH); e.v = ntld_f(B.v1 + li); }
    } else if (i < B.p3) {
        int li = i - B.p2;
        e.r = ntld_i(B.r2 + li); e.tb = B.t2;
        if (FULL) { e.cw = (unsigned)ntld_i(B.c2 + li) | (2u << DID_SH); e.v = ntld_f(B.v2 + li); }
    } else if (i < B.p4) {
        int li = i - B.p3;
        e.r = ntld_i(B.r3 + li); e.tb = B.t3;
        if (FULL) { e.cw = (unsigned)ntld_i(B.c3 + li) | (3u << DID_SH); e.v = ntld_f(B.v3 + li); }
    } else if (i < B.p5) {
        int li = i - B.p4;
        e.r = ntld_i(B.r4 + li); e.tb = B.t4;
        if (FULL) { e.cw = (unsigned)ntld_i(B.c4 + li) | (4u << DID_SH); e.v = ntld_f(B.v4 + li); }
    } else if (i < B.p6) {
        int li = i - B.p5;
        e.r = ntld_i(B.r5 + li); e.tb = B.t5;
        if (FULL) { e.cw = (unsigned)ntld_i(B.c5 + li) | (5u << DID_SH); e.v = ntld_f(B.v5 + li); }
    } else {
        int li = i - B.p6;
        e.r = ntld_i(B.r6 + li); e.tb = B.t6;
        if (FULL) { e.cw = (unsigned)ntld_i(B.c6 + li) | (6u << DID_SH); e.v = ntld_f(B.v6 + li); }
    }
    return e;
}

// ---------------- group histogram (8 buckets per group) -------------------
__global__ __launch_bounds__(1024) void bhist_grp(
    Bin7 B, int* __restrict__ gcount, int NG, int chunk)
{
    __shared__ int h[MAXNG];
    for (int i = threadIdx.x; i < NG; i += 1024) h[i] = 0;
    __syncthreads();
    const int s = blockIdx.x * chunk;
    int e = s + chunk;  if (e > B.p7) e = B.p7;
    for (int i = s + threadIdx.x; i < e; i += 1024) {
        Ent en = decode<false>(B, i);
        atomicAdd(&h[(en.tb + (en.r >> 7)) >> 3], 1);
    }
    __syncthreads();
    for (int i = threadIdx.x; i < NG; i += 1024)
        if (h[i]) atomicAdd(&gcount[i], h[i]);
}

// ---------------- pass A (tier 1): scatter with combined column -----------
// payA word: colC(21) | lrow(7)<<21 | (bucket&7)<<28
__global__ __launch_bounds__(1024) void scatter_grpC(
    Bin7 B, CBase cb, int* __restrict__ gcur, uint2* __restrict__ payA,
    int NG, int chunk)
{
    __shared__ int lbase[MAXNG];
    __shared__ int lcur[MAXNG];
    __shared__ int cbs[8];
    if (threadIdx.x < 8) cbs[threadIdx.x] = cb.b[threadIdx.x];
    for (int i = threadIdx.x; i < NG; i += 1024) lcur[i] = 0;
    __syncthreads();
    const int s = blockIdx.x * chunk;
    int e = s + chunk;  if (e > B.p7) e = B.p7;

    for (int i = s + threadIdx.x; i < e; i += 1024) {
        Ent en = decode<false>(B, i);
        atomicAdd(&lcur[(en.tb + (en.r >> 7)) >> 3], 1);
    }
    __syncthreads();
    for (int i = threadIdx.x; i < NG; i += 1024) {
        int c = lcur[i];
        lbase[i] = c ? atomicAdd(&gcur[i], c) : 0;
        lcur[i] = 0;
    }
    __syncthreads();
    for (int i = s + threadIdx.x; i < e; i += 1024) {
        Ent en = decode<true>(B, i);
        int b = en.tb + (en.r >> 7);
        int g = b >> 3;
        int pos = lbase[g] + atomicAdd(&lcur[g], 1);
        int did = (int)(en.cw >> DID_SH);
        unsigned colC = (en.cw & COL_MASK) + (unsigned)cbs[did];
        unsigned cwA = colC | ((unsigned)(en.r & 127) << CLROW_SH)
                     | ((unsigned)(b & 7) << CBKT_SH);
        payA[pos] = make_uint2(cwA, __float_as_uint(en.v));
    }
}

// ---------------- pass B (tier 1): 1024-bin LDS-staged counting sort ------
// Sort key = bits 21..30 (lrow | (bucket&7)<<7). payB.x = pure colC.
// Emits rowoff, bend, and rowperm (rows ranked by descending length).
__global__ __launch_bounds__(1024) void sort_grpC(
    const uint2* __restrict__ payA, const int* __restrict__ goff,
    const int* __restrict__ gcur, int* __restrict__ rowoff,
    int* __restrict__ bend, uint2* __restrict__ payB,
    unsigned char* __restrict__ rowperm, int NBtot)
{
    __shared__ uint2 lpay[SORT_CAP];      // 144 KB
    __shared__ int cnt[1024];             // hist, then cur
    __shared__ int off[1024];             // exclusive scan (immutable)
    __shared__ unsigned char cnts8[1024]; // clamped counts for ranking
    __shared__ int wsum[16];
    __shared__ int phstart[MAXPH + 1];
    __shared__ int s_nph, s_maxbin;

    const int g = blockIdx.x;
    const int tid = threadIdx.x;
    const int seg0 = goff[g], seg1 = gcur[g];
    const int n = seg1 - seg0;

    cnt[tid] = 0;
    if (tid == 0) s_maxbin = 0;
    __syncthreads();
    for (int i = seg0 + tid; i < seg1; i += 1024) {
        unsigned w = __builtin_nontemporal_load(&payA[i].x);
        atomicAdd(&cnt[(w >> CLROW_SH) & 1023], 1);
    }
    __syncthreads();

    const int lane = tid & 63, wv = tid >> 6;
    const int tot = cnt[tid];
    atomicMax(&s_maxbin, tot);
    cnts8[tid] = (unsigned char)(tot > 255 ? 255 : tot);
    int x = tot;
    #pragma unroll
    for (int o = 1; o < 64; o <<= 1) {
        int y = __shfl_up(x, o);
        if (lane >= o) x += y;
    }
    if (lane == 63) wsum[wv] = x;
    __syncthreads();
    if (tid < 16) {
        int ss = wsum[tid];
        #pragma unroll
        for (int o = 1; o < 16; o <<= 1) {
            int y = __shfl_up(ss, o, 16);
            if (tid >= o) ss += y;
        }
        wsum[tid] = ss;
    }
    __syncthreads();
    const int excl = (x - tot) + ((wv == 0) ? 0 : wsum[wv - 1]);
    off[tid] = excl;
    rowoff[(size_t)g * 1024 + tid] = seg0 + excl;
    {
        int b = g * 8 + (tid >> 7);
        if (b < NBtot && (tid & 127) == 127) bend[b] = seg0 + excl + tot;
    }
    __syncthreads();   // off[] + cnts8[] complete
    cnt[tid] = excl;   // cnt becomes cur
    {
        int p = excl >> SORT_LOG;
        int pprev = (tid == 0) ? -1 : (off[tid - 1] >> SORT_LOG);
        for (int q = pprev + 1; q <= p && q <= MAXPH; ++q) phstart[q] = excl;
        if (tid == 1023) s_nph = p + 1;
    }

    // rank rows by descending length within each 128-row bucket (bijective)
    {
        const int myr = tid & 127, b0 = tid & ~127;
        const unsigned char myc = cnts8[tid];
        int rank = 0;
        #pragma unroll 8
        for (int r = 0; r < 128; ++r) {
            unsigned char c = cnts8[b0 + r];
            rank += (c > myc) || (c == myc && r < myr);
        }
        rowperm[(size_t)g * 1024 + b0 + rank] = (unsigned char)myr;
    }
    __syncthreads();

    const int nph = s_nph;
    if (n <= 0) return;

    if (s_maxbin <= SORT_MAXBIN && nph <= MAXPH) {
        for (int ph = 0; ph < nph; ++ph) {
            const int ps = phstart[ph];
            const int pe = (ph + 1 < nph) ? phstart[ph + 1] : n;
            for (int i = seg0 + tid; i < seg1; i += 1024) {
                unsigned long long pv = __builtin_nontemporal_load(
                    (const unsigned long long*)(payA + i));
                unsigned w = (unsigned)pv;
                int bin = (w >> CLROW_SH) & 1023;
                if ((off[bin] >> SORT_LOG) == ph) {
                    int pos = atomicAdd(&cnt[bin], 1);
                    lpay[pos - ps] = make_uint2(w, (unsigned)(pv >> 32));
                }
            }
            __syncthreads();
            for (int k = tid; k < pe - ps; k += 1024) {
                uint2 pv = lpay[k];
                unsigned long long o2 = (unsigned long long)(pv.x & CCOL_MASK)
                                      | ((unsigned long long)pv.y << 32);
                __builtin_nontemporal_store(o2,
                    (unsigned long long*)(payB + seg0 + ps + k));
            }
            __syncthreads();
        }
    } else {
        // fallback: direct global scatter (pathological bin sizes only)
        for (int i = seg0 + tid; i < seg1; i += 1024) {
            unsigned long long pv = __builtin_nontemporal_load(
                (const unsigned long long*)(payA + i));
            unsigned w = (unsigned)pv;
            int bin = (w >> CLROW_SH) & 1023;
            int pos = seg0 + atomicAdd(&cnt[bin], 1);
            payB[pos] = make_uint2(w & CCOL_MASK, (unsigned)(pv >> 32));
        }
    }
}

// ---------------- tier-2 kernels (old did-encoded scheme, unchanged) ------
__global__ __launch_bounds__(1024) void scatter_grp(
    Bin7 B, int* __restrict__ gcur, uint2* __restrict__ payA,
    int NG, int chunk)
{
    __shared__ int lbase[MAXNG];
    __shared__ int lcur[MAXNG];
    for (int i = threadIdx.x; i < NG; i += 1024) lcur[i] = 0;
    __syncthreads();
    const int s = blockIdx.x * chunk;
    int e = s + chunk;  if (e > B.p7) e = B.p7;

    for (int i = s + threadIdx.x; i < e; i += 1024) {
        Ent en = decode<false>(B, i);
        atomicAdd(&lcur[(en.tb + (en.r >> 7)) >> 3], 1);
    }
    __syncthreads();
    for (int i = threadIdx.x; i < NG; i += 1024) {
        int c = lcur[i];
        lbase[i] = c ? atomicAdd(&gcur[i], c) : 0;
        lcur[i] = 0;
    }
    __syncthreads();
    for (int i = s + threadIdx.x; i < e; i += 1024) {
        Ent en = decode<true>(B, i);
        int b = en.tb + (en.r >> 7);
        int g = b >> 3;
        int pos = lbase[g] + atomicAdd(&lcur[g], 1);
        unsigned col = en.cw & COL_MASK;
        unsigned did = en.cw >> DID_SH;
        unsigned cwA = col | ((unsigned)(en.r & 127) << LROW_SH)
                     | ((unsigned)(b & 7) << 26) | (did << 29);
        payA[pos] = make_uint2(cwA, __float_as_uint(en.v));
    }
}

__global__ __launch_bounds__(1024) void sort_grp(
    const uint2* __restrict__ payA, const int* __restrict__ goff,
    const int* __restrict__ gcur, int* __restrict__ rowoff,
    int* __restrict__ bend, uint2* __restrict__ payB,
    unsigned char* __restrict__ rowperm, int NBtot)
{
    __shared__ uint2 lpay[SORT_CAP];
    __shared__ int cnt[1024];
    __shared__ int off[1024];
    __shared__ unsigned char cnts8[1024];
    __shared__ int wsum[16];
    __shared__ int phstart[MAXPH + 1];
    __shared__ int s_nph, s_maxbin;

    const int g = blockIdx.x;
    const int tid = threadIdx.x;
    const int seg0 = goff[g], seg1 = gcur[g];
    const int n = seg1 - seg0;

    cnt[tid] = 0;
    if (tid == 0) s_maxbin = 0;
    __syncthreads();
    for (int i = seg0 + tid; i < seg1; i += 1024) {
        unsigned w = __builtin_nontemporal_load(&payA[i].x);
        atomicAdd(&cnt[(w >> 19) & 1023], 1);
    }
    __syncthreads();

    const int lane = tid & 63, wv = tid >> 6;
    const int tot = cnt[tid];
    atomicMax(&s_maxbin, tot);
    cnts8[tid] = (unsigned char)(tot > 255 ? 255 : tot);
    int x = tot;
    #pragma unroll
    for (int o = 1; o < 64; o <<= 1) {
        int y = __shfl_up(x, o);
        if (lane >= o) x += y;
    }
    if (lane == 63) wsum[wv] = x;
    __syncthreads();
    if (tid < 16) {
        int ss = wsum[tid];
        #pragma unroll
        for (int o = 1; o < 16; o <<= 1) {
            int y = __shfl_up(ss, o, 16);
            if (tid >= o) ss += y;
        }
        wsum[tid] = ss;
    }
    __syncthreads();
    const int excl = (x - tot) + ((wv == 0) ? 0 : wsum[wv - 1]);
    off[tid] = excl;
    rowoff[(size_t)g * 1024 + tid] = seg0 + excl;
    {
        int b = g * 8 + (tid >> 7);
        if (b < NBtot && (tid & 127) == 127) bend[b] = seg0 + excl + tot;
    }
    __syncthreads();
    cnt[tid] = excl;
    {
        int p = excl >> SORT_LOG;
        int pprev = (tid == 0) ? -1 : (off[tid - 1] >> SORT_LOG);
        for (int q = pprev + 1; q <= p && q <= MAXPH; ++q) phstart[q] = excl;
        if (tid == 1023) s_nph = p + 1;
    }

    {
        const int myr = tid & 127, b0 = tid & ~127;
        const unsigned char myc = cnts8[tid];
        int rank = 0;
        #pragma unroll 8
        for (int r = 0; r < 128; ++r) {
            unsigned char c = cnts8[b0 + r];
            rank += (c > myc) || (c == myc && r < myr);
        }
        rowperm[(size_t)g * 1024 + b0 + rank] = (unsigned char)myr;
    }
    __syncthreads();

    const int nph = s_nph;
    if (n <= 0) return;

    if (s_maxbin <= SORT_MAXBIN && nph <= MAXPH) {
        for (int ph = 0; ph < nph; ++ph) {
            const int ps = phstart[ph];
            const int pe = (ph + 1 < nph) ? phstart[ph + 1] : n;
            for (int i = seg0 + tid; i < seg1; i += 1024) {
                unsigned long long pv = __builtin_nontemporal_load(
                    (const unsigned long long*)(payA + i));
                unsigned w = (unsigned)pv;
                int bin = (w >> 19) & 1023;
                if ((off[bin] >> SORT_LOG) == ph) {
                    int pos = atomicAdd(&cnt[bin], 1);
                    lpay[pos - ps] = make_uint2(w, (unsigned)(pv >> 32));
                }
            }
            __syncthreads();
            for (int k = tid; k < pe - ps; k += 1024) {
                uint2 pv = lpay[k];
                unsigned cw = (pv.x & 0x03FFFFFFu) | ((pv.x >> 29) << 26);
                unsigned long long o2 = (unsigned long long)cw
                                      | ((unsigned long long)pv.y << 32);
                __builtin_nontemporal_store(o2,
                    (unsigned long long*)(payB + seg0 + ps + k));
            }
            __syncthreads();
        }
    } else {
        for (int i = seg0 + tid; i < seg1; i += 1024) {
            unsigned long long pv = __builtin_nontemporal_load(
                (const unsigned long long*)(payA + i));
            unsigned w = (unsigned)pv;
            int bin = (w >> 19) & 1023;
            int pos = seg0 + atomicAdd(&cnt[bin], 1);
            unsigned cw = (w & 0x03FFFFFFu) | ((w >> 29) << 26);
            payB[pos] = make_uint2(cw, (unsigned)(pv >> 32));
        }
    }
}

// ---------------- shfl-based single-block exclusive scan ------------------
__global__ __launch_bounds__(1024) void scan_small(
    const int* __restrict__ in, int* __restrict__ boff,
    int* __restrict__ bcur, int n)
{
    __shared__ int wsum[16];
    __shared__ int carry;
    const int tid = threadIdx.x, lane = tid & 63, wv = tid >> 6;
    if (tid == 0) carry = 0;
    __syncthreads();
    for (int base = 0; base < n; base += 4096) {
        int i = base + tid * 4;
        int v0 = (i + 0 < n) ? in[i + 0] : 0;
        int v1 = (i + 1 < n) ? in[i + 1] : 0;
        int v2 = (i + 2 < n) ? in[i + 2] : 0;
        int v3 = (i + 3 < n) ? in[i + 3] : 0;
        int tsum = v0 + v1 + v2 + v3;
        int x = tsum;
        #pragma unroll
        for (int off = 1; off < 64; off <<= 1) {
            int y = __shfl_up(x, off);
            if (lane >= off) x += y;
        }
        if (lane == 63) wsum[wv] = x;
        int c0 = carry;
        __syncthreads();
        if (tid < 16) {
            int ss = wsum[tid];
            #pragma unroll
            for (int off = 1; off < 16; off <<= 1) {
                int y = __shfl_up(ss, off, 16);
                if (tid >= off) ss += y;
            }
            wsum[tid] = ss;
        }
        __syncthreads();
        int wpre = (wv == 0) ? 0 : wsum[wv - 1];
        int excl = c0 + wpre + (x - tsum);
        if (i + 0 < n) { boff[i + 0] = excl; bcur[i + 0] = excl; } excl += v0;
        if (i + 1 < n) { boff[i + 1] = excl; bcur[i + 1] = excl; } excl += v1;
        if (i + 2 < n) { boff[i + 2] = excl; bcur[i + 2] = excl; } excl += v2;
        if (i + 3 < n) { boff[i + 3] = excl; bcur[i + 3] = excl; }
        __syncthreads();
        if (tid == 0) carry = c0 + wsum[15];
        __syncthreads();
    }
}

// ---------------- combined-table row accumulate (depth-2 pipelined) -------
__device__ __forceinline__ void facc(float4& a, float v, uint2 d) {
    a.x = fmaf(v, __uint_as_float((d.x & 0xFFFFu) << 16), a.x);
    a.y = fmaf(v, __uint_as_float(d.x & 0xFFFF0000u), a.y);
    a.z = fmaf(v, __uint_as_float((d.y & 0xFFFFu) << 16), a.z);
    a.w = fmaf(v, __uint_as_float(d.y & 0xFFFF0000u), a.w);
}

__device__ __forceinline__ float4 row_accumC(
    const uint2* __restrict__ payB, int js, int je,
    const uint2* __restrict__ Dg, int l)
{
    float4 a = make_float4(0.f, 0.f, 0.f, 0.f);
    const int n = je - js;
    if (n <= 0) return a;
    const uint2* base = payB + js;
    uint2 p0 = base[0];
    uint2 p1 = base[(n > 1) ? 1 : 0];
    float v0 = __uint_as_float(p0.y);
    float v1 = (n > 1) ? __uint_as_float(p1.y) : 0.f;
    uint2 d0 = Dg[(size_t)p0.x * 16 + l];
    uint2 d1 = Dg[(size_t)p1.x * 16 + l];
    int i = 0;
    while (true) {
        int i2 = (i + 2 < n) ? i + 2 : n - 1;
        int i3 = (i + 3 < n) ? i + 3 : n - 1;
        uint2 q0 = base[i2];
        uint2 q1 = base[i3];
        float w0 = (i + 2 < n) ? __uint_as_float(q0.y) : 0.f;
        float w1 = (i + 3 < n) ? __uint_as_float(q1.y) : 0.f;
        uint2 e0 = Dg[(size_t)q0.x * 16 + l];   // issued before d0/d1 waited on
        uint2 e1 = Dg[(size_t)q1.x * 16 + l];   // -> 2 gathers in flight
        facc(a, v0, d0);
        facc(a, v1, d1);
        i += 2;
        if (i >= n) break;
        v0 = w0; v1 = w1; d0 = e0; d1 = e1;
    }
    return a;
}

// ---------------- merged streaming SpMM (tier 1, combined table) ----------
__global__ __launch_bounds__(256) void spmm_stream_allC(
    const uint2* __restrict__ payB, const int* __restrict__ rowoff,
    const int* __restrict__ bend, const unsigned char* __restrict__ rowperm,
    const unsigned short* __restrict__ dense,
    float* __restrict__ out, int NB0, int NB01, int NBall,
    int N0, int N1, int N2)
{
    const uint2* __restrict__ Dg = reinterpret_cast<const uint2*>(dense);
    const int tid = threadIdx.x;
    const int qw = tid >> 4, l = tid & 15;

    for (int t = blockIdx.x; t < NBall; t += gridDim.x) {
        int tb, nrows; float scale; float* oseg;
        if (t < NB0)       { tb = 0;    nrows = N0; oseg = out;                          scale = 0.5f; }
        else if (t < NB01) { tb = NB0;  nrows = N1; oseg = out + (size_t)N0 * 64;        scale = 1.0f / 3.0f; }
        else               { tb = NB01; nrows = N2; oseg = out + (size_t)(N0 + N1) * 64; scale = 0.5f; }
        const int row0 = (t - tb) * RPB;
        const int rbase = t * RPB;
        const int bendt = bend[t];
        const unsigned char* perm = rowperm + (size_t)t * RPB;

        #pragma unroll 1
        for (int rr = 0; rr < 8; ++rr) {
            const int lr = perm[rr * 16 + qw];   // length-balanced wave rows
            const int row = row0 + lr;
            const int js = rowoff[rbase + lr];
            const int je = (lr == 127) ? bendt : rowoff[rbase + lr + 1];
            float4 a = row_accumC(payB, js, je, Dg, l);
            if (row < nrows) {
                float* o = oseg + (size_t)row * 64 + l * 4;
                a.x = fmaxf(a.x, 0.f) * scale;
                a.y = fmaxf(a.y, 0.f) * scale;
                a.z = fmaxf(a.z, 0.f) * scale;
                a.w = fmaxf(a.w, 0.f) * scale;
                ntst_f4(o, a);
            }
        }
    }
}

// ---------------- tier-2 per-segment SpMM (old scheme, unchanged) ---------
__device__ __forceinline__ float mval(uint2 p, int didMask) {
    int did = (int)(p.x >> DID_SH) & 7;
    return ((didMask >> did) & 1) ? __uint_as_float(p.y) : 0.f;
}
__device__ __forceinline__ uint2 dgather(uint2 p, int l,
    const unsigned short* const* dptr)
{
    const uint2* Dg = reinterpret_cast<const uint2*>(dptr[(p.x >> DID_SH) & 7]);
    return Dg[(size_t)(p.x & COL_MASK) * 16 + l];
}

__device__ __forceinline__ float4 row_accum(
    const uint2* __restrict__ payB, int js, int je,
    const unsigned short* const* dptr, int l, int didMask)
{
    float4 a = make_float4(0.f, 0.f, 0.f, 0.f);
    const int n = je - js;
    if (n <= 0) return a;
    const uint2* base = payB + js;
    uint2 p0 = base[0];
    uint2 p1 = base[(n > 1) ? 1 : 0];
    float v0 = mval(p0, didMask);
    float v1 = (n > 1) ? mval(p1, didMask) : 0.f;
    uint2 d0 = dgather(p0, l, dptr);
    uint2 d1 = dgather(p1, l, dptr);
    int i = 0;
    while (true) {
        int i2 = (i + 2 < n) ? i + 2 : n - 1;
        int i3 = (i + 3 < n) ? i + 3 : n - 1;
        uint2 q0 = base[i2];
        uint2 q1 = base[i3];
        float w0 = (i + 2 < n) ? mval(q0, didMask) : 0.f;
        float w1 = (i + 3 < n) ? mval(q1, didMask) : 0.f;
        uint2 e0 = dgather(q0, l, dptr);
        uint2 e1 = dgather(q1, l, dptr);
        facc(a, v0, d0);
        facc(a, v1, d1);
        i += 2;
        if (i >= n) break;
        v0 = w0; v1 = w1; d0 = e0; d1 = e1;
    }
    return a;
}

__global__ __launch_bounds__(256) void spmm_stream7(
    const uint2* __restrict__ payB, const int* __restrict__ rowoff,
    const int* __restrict__ bend, const unsigned char* __restrict__ rowperm,
    const unsigned short* __restrict__ d0, const unsigned short* __restrict__ d1,
    const unsigned short* __restrict__ d2, const unsigned short* __restrict__ d3,
    const unsigned short* __restrict__ d4, const unsigned short* __restrict__ d5,
    const unsigned short* __restrict__ d6,
    float* __restrict__ out, int tile0, int nrows,
    int firstWrite, int doRelu, float scale, int didMask)
{
    __shared__ const unsigned short* dptr[8];
    const int tid = threadIdx.x;
    if (tid < 8) {
        const unsigned short* tbl[8] = {d0, d1, d2, d3, d4, d5, d6, d0};
        dptr[tid] = tbl[tid];
    }
    __syncthreads();

    const int t = tile0 + blockIdx.x;
    const int qw = tid >> 4, l = tid & 15;
    const int row0 = blockIdx.x * RPB;
    const int rbase = t * RPB;
    const int bendt = bend[t];
    const unsigned char* perm = rowperm + (size_t)t * RPB;

    #pragma unroll 1
    for (int rr = 0; rr < 8; ++rr) {
        const int lr = perm[rr * 16 + qw];
        const int row = row0 + lr;
        const int js = rowoff[rbase + lr];
        const int je = (lr == 127) ? bendt : rowoff[rbase + lr + 1];
        float4 a = row_accum(payB, js, je, dptr, l, didMask);

        if (row < nrows) {
            float* o = out + (size_t)row * 64 + l * 4;
            if (!firstWrite) {
                float4 cur = *reinterpret_cast<float4*>(o);
                a.x += cur.x; a.y += cur.y; a.z += cur.z; a.w += cur.w;
            }
            if (doRelu) {
                a.x = fmaxf(a.x, 0.f) * scale;
                a.y = fmaxf(a.y, 0.f) * scale;
                a.z = fmaxf(a.z, 0.f) * scale;
                a.w = fmaxf(a.w, 0.f) * scale;
            }
            ntst_f4(o, a);
        }
    }
}

extern "C" void kernel_launch(void* const* d_in, const int* in_sizes, int n_in,
                              void* d_out, int out_size, void* d_ws, size_t ws_size,
                              hipStream_t stream)
{
    const float* X0 = (const float*)d_in[0];
    const float* X1 = (const float*)d_in[1];
    const float* X2 = (const float*)d_in[2];
    const int N0 = in_sizes[0] / 64;
    const int N1 = in_sizes[1] / 64;
    const int N2 = in_sizes[2] / 64;

    auto Wp = [&](int i) { return (const float*)d_in[24 + 2 * i]; };
    auto bp = [&](int i) { return (const float*)d_in[25 + 2 * i]; };
    auto Sr = [&](int i) { return (const int*)d_in[3 + 3 * i]; };
    auto Sc = [&](int i) { return (const int*)d_in[4 + 3 * i]; };
    auto Sv = [&](int i) { return (const float*)d_in[5 + 3 * i]; };
    auto Sn = [&](int i) { return in_sizes[3 + 3 * i]; };

    const size_t offY1 = (size_t)N0 * 64;
    const size_t offY2 = (size_t)(N0 + N1) * 64;
    const float TH = 1.0f / 3.0f;

    const int NB0 = (N0 + RPB - 1) / RPB;
    const int NB1 = (N1 + RPB - 1) / RPB;
    const int NB2 = (N2 + RPB - 1) / RPB;

    float* out = (float*)d_out;
    auto align256 = [](size_t x) { return (x + 255) & ~(size_t)255; };

    // -------- W fragment precompute (all 7 sets, once) --------
    const size_t FRAG_SET = 16384;  // ushorts per set (32 KB)
    const size_t fragB = align256(7 * FRAG_SET * sizeof(unsigned short));
    if (ws_size <= fragB) return;   // pathological; cannot run
    unsigned short* wfrags = (unsigned short*)d_ws;
    char* ws = (char*)d_ws + fragB;
    const size_t ws_avail = ws_size - fragB;
    auto wf = [&](int i) { return wfrags + (size_t)i * FRAG_SET; };

    WAll wa;
    for (int i = 0; i < 7; ++i) wa.w[i] = Wp(i);
    winit<<<7, 256, 0, stream>>>(wa, wfrags);

    // -------- tier 1: everything at once --------
    const int NBall = NB0 + NB1 + NB2;
    const int NGall = (NBall + 7) / 8;
    const int nnzAll = Sn(0)+Sn(1)+Sn(2)+Sn(3)+Sn(4)+Sn(5)+Sn(6);
    const size_t payT1 = align256((size_t)nnzAll * sizeof(uint2));
    const size_t cntT1 = align256((size_t)(NBall + 8) * sizeof(int));
    const size_t rowT1 = align256((size_t)NGall * 1024 * sizeof(int));
    const size_t permT1 = align256((size_t)NGall * 1024);
    const size_t denseT1 = ((size_t)2*N0 + 3*N1 + 2*N2) * 64 * sizeof(unsigned short);
    const size_t regionT1 = denseT1 > payT1 ? denseT1 : payT1;  // dense ∪ payA
    const size_t needT1 = payT1 + 4 * cntT1 + rowT1 + permT1 + regionT1;
    const long long denseRows = (long long)2*N0 + 3LL*N1 + 2LL*N2;

    if (ws_avail >= needT1 && NBall <= MAXNB && denseRows < (1LL << 21)) {
        uint2* payB  = (uint2*)ws;
        int* goff    = (int*)(ws + payT1);
        int* gcur    = (int*)(ws + payT1 + 1 * cntT1);
        int* bend    = (int*)(ws + payT1 + 2 * cntT1);
        int* gcount  = (int*)(ws + payT1 + 3 * cntT1);
        int* rowoff  = (int*)(ws + payT1 + 4 * cntT1);
        unsigned char* rowperm = (unsigned char*)(ws + payT1 + 4 * cntT1 + rowT1);
        char* region = ws + payT1 + 4 * cntT1 + rowT1 + permT1;
        uint2* payA  = (uint2*)region;                // dead after sort_grpC
        unsigned short* db = (unsigned short*)region; // gemms write after sort
        unsigned short* dn2n = db;
        unsigned short* de2n = dn2n + (size_t)N0 * 64;
        unsigned short* dn2e = de2n + (size_t)N1 * 64;
        unsigned short* de2e = dn2e + (size_t)N0 * 64;
        unsigned short* dt2e = de2e + (size_t)N1 * 64;
        unsigned short* de2t = dt2e + (size_t)N2 * 64;
        unsigned short* dt2t = de2t + (size_t)N1 * 64;

        Bin7 B;
        // did: 0 n2n(L0) 1 e2n(D1invB1) 2 n2e(D2B1TD1inv) 3 e2e(L1) 4 t2e(B2D3) 5 e2t(B2TD2inv) 6 t2t(L2)
        B.r0 = Sr(0); B.c0 = Sc(0); B.v0 = Sv(0);
        B.r1 = Sr(3); B.c1 = Sc(3); B.v1 = Sv(3);
        B.r2 = Sr(4); B.c2 = Sc(4); B.v2 = Sv(4);
        B.r3 = Sr(1); B.c3 = Sc(1); B.v3 = Sv(1);
        B.r4 = Sr(6); B.c4 = Sc(6); B.v4 = Sv(6);
        B.r5 = Sr(5); B.c5 = Sc(5); B.v5 = Sv(5);
        B.r6 = Sr(2); B.c6 = Sc(2); B.v6 = Sv(2);
        B.p1 = Sn(0);
        B.p2 = B.p1 + Sn(3);
        B.p3 = B.p2 + Sn(4);
        B.p4 = B.p3 + Sn(1);
        B.p5 = B.p4 + Sn(6);
        B.p6 = B.p5 + Sn(5);
        B.p7 = B.p6 + Sn(2);
        B.t0 = 0;   B.t1 = 0;
        B.t2 = NB0; B.t3 = NB0; B.t4 = NB0;
        B.t5 = NB0 + NB1; B.t6 = NB0 + NB1;

        CBase cb;   // row base of each did's dense table in the combined table
        cb.b[0] = 0;
        cb.b[1] = N0;
        cb.b[2] = N0 + N1;
        cb.b[3] = 2*N0 + N1;
        cb.b[4] = 2*N0 + 2*N1;
        cb.b[5] = 2*N0 + 2*N1 + N2;
        cb.b[6] = 2*N0 + 3*N1 + N2;
        cb.b[7] = 0;

        const int chunk = (B.p7 + GRID_BIN - 1) / GRID_BIN;
        hipMemsetAsync(gcount, 0, (size_t)NGall * sizeof(int), stream);
        bhist_grp<<<GRID_BIN, 1024, 0, stream>>>(B, gcount, NGall, chunk);
        scan_small<<<1, 1024, 0, stream>>>(gcount, goff, gcur, NGall);
        scatter_grpC<<<GRID_BIN, 1024, 0, stream>>>(B, cb, gcur, payA, NGall, chunk);
        sort_grpC<<<NGall, 1024, 0, stream>>>(payA, goff, gcur, rowoff, bend,
                                              payB, rowperm, NBall);

        gemm_powcat_mfma<<<(N0 + 63) / 64, 256, 0, stream>>>(
            X0, N0, 2,
            wf(0), bp(0), dn2n,
            wf(1), bp(1), dn2e,
            wf(0), bp(0), dn2n);
        gemm_powcat_mfma<<<(N1 + 63) / 64, 256, 0, stream>>>(
            X1, N1, 3,
            wf(3), bp(3), de2n,
            wf(2), bp(2), de2e,
            wf(4), bp(4), de2t);
        gemm_powcat_mfma<<<(N2 + 63) / 64, 256, 0, stream>>>(
            X2, N2, 2,
            wf(5), bp(5), dt2e,
            wf(6), bp(6), dt2t,
            wf(5), bp(5), dt2e);

        const int grid = NBall < SPMM_GRID ? NBall : SPMM_GRID;
        spmm_stream_allC<<<grid, 256, 0, stream>>>(payB, rowoff, bend, rowperm,
            db, out, NB0, NB0 + NB1, NBall, N0, N1, N2);
        return;
    }

    // -------- tier 2: two-group phased layout (old did-encoded scheme) ----
    const int NBtotA = NB0 + NB2;
    const int NBmax = NBtotA > NB1 ? NBtotA : NB1;
    const int NGmax = (NBmax + 7) / 8;
    const int nnzA = Sn(0) + Sn(3) + Sn(5) + Sn(2);
    const int nnzB = Sn(4) + Sn(6) + Sn(1);
    const int nnzMax = nnzA > nnzB ? nnzA : nnzB;

    const size_t payBsz = align256((size_t)nnzMax * sizeof(uint2));
    const size_t cntB = align256((size_t)(NBmax + 8) * sizeof(int));
    const size_t rowB = align256((size_t)NGmax * 1024 * sizeof(int));
    const size_t permB = align256((size_t)NGmax * 1024);
    const size_t denseOff = payBsz + 4 * cntB + rowB + permB;

    uint2* bpayB = (uint2*)ws;
    int* goff    = (int*)(ws + payBsz);
    int* gcur    = (int*)(ws + payBsz + 1 * cntB);
    int* bend    = (int*)(ws + payBsz + 2 * cntB);
    int* gcount  = (int*)(ws + payBsz + 3 * cntB);
    int* rowoff  = (int*)(ws + payBsz + 4 * cntB);
    unsigned char* rowperm = (unsigned char*)(ws + payBsz + 4 * cntB + rowB);
    unsigned short* dense = (unsigned short*)(ws + denseOff);
    uint2* payA  = (uint2*)dense;   // transient, dead before gemms write dense

    const size_t need_full = denseOff +
        ((size_t)N0 + N2 + N1) * 64 * sizeof(unsigned short);
    const bool fullB = (ws_avail >= need_full);

    // ---- group A: did 0=n2n(Y0) 1=e2n(Y0) 2=e2t(Y2) 3=t2t(Y2)
    {
        Bin7 B;
        B.r0 = Sr(0); B.c0 = Sc(0); B.v0 = Sv(0);
        B.r1 = Sr(3); B.c1 = Sc(3); B.v1 = Sv(3);
        B.r2 = Sr(5); B.c2 = Sc(5); B.v2 = Sv(5);
        B.r3 = Sr(2); B.c3 = Sc(2); B.v3 = Sv(2);
        B.r4 = B.r3; B.c4 = B.c3; B.v4 = B.v3;
        B.r5 = B.r3; B.c5 = B.c3; B.v5 = B.v3;
        B.r6 = B.r3; B.c6 = B.c3; B.v6 = B.v3;
        B.p1 = Sn(0);
        B.p2 = B.p1 + Sn(3);
        B.p3 = B.p2 + Sn(5);
        B.p4 = B.p3 + Sn(2);
        B.p5 = B.p4; B.p6 = B.p4; B.p7 = B.p4;
        B.t0 = 0; B.t1 = 0; B.t2 = NB0; B.t3 = NB0;
        B.t4 = NB0; B.t5 = NB0; B.t6 = NB0;

        const int NGA = (NBtotA + 7) / 8;
        const int chunk = (B.p7 + GRID_BIN - 1) / GRID_BIN;
        hipMemsetAsync(gcount, 0, (size_t)NGA * sizeof(int), stream);
        bhist_grp<<<GRID_BIN, 1024, 0, stream>>>(B, gcount, NGA, chunk);
        scan_small<<<1, 1024, 0, stream>>>(gcount, goff, gcur, NGA);
        scatter_grp<<<GRID_BIN, 1024, 0, stream>>>(B, gcur, payA, NGA, chunk);
        sort_grp<<<NGA, 1024, 0, stream>>>(payA, goff, gcur, rowoff, bend,
                                           bpayB, rowperm, NBtotA);

        unsigned short* dn2n = dense;
        unsigned short* de2n = dense + (size_t)N0 * 64;
        gemm_powcat_mfma<<<(N0 + 63) / 64, 256, 0, stream>>>(
            X0, N0, 1, wf(0), bp(0), dn2n,
            wf(0), bp(0), dn2n, wf(0), bp(0), dn2n);
        gemm_powcat_mfma<<<(N1 + 63) / 64, 256, 0, stream>>>(
            X1, N1, 1, wf(3), bp(3), de2n,
            wf(3), bp(3), de2n, wf(3), bp(3), de2n);
        spmm_stream7<<<NB0, 256, 0, stream>>>(bpayB, rowoff, bend, rowperm,
            dn2n, de2n, dn2n, dn2n, dn2n, dn2n, dn2n,
            out, 0, N0, 1, 1, 0.5f, 0x7F);

        unsigned short* de2t = dense;
        unsigned short* dt2t = dense + (size_t)N1 * 64;
        gemm_powcat_mfma<<<(N1 + 63) / 64, 256, 0, stream>>>(
            X1, N1, 1, wf(4), bp(4), de2t,
            wf(4), bp(4), de2t, wf(4), bp(4), de2t);
        gemm_powcat_mfma<<<(N2 + 63) / 64, 256, 0, stream>>>(
            X2, N2, 1, wf(6), bp(6), dt2t,
            wf(6), bp(6), dt2t, wf(6), bp(6), dt2t);
        spmm_stream7<<<NB2, 256, 0, stream>>>(bpayB, rowoff, bend, rowperm,
            de2t, de2t, de2t, dt2t, de2t, de2t, de2t,
            out + offY2, NB0, N2, 1, 1, 0.5f, 0x7F);
    }

    // ---- group B (Y1): did 0=n2e 1=t2e 2=e2e
    {
        Bin7 B;
        B.r0 = Sr(4); B.c0 = Sc(4); B.v0 = Sv(4);
        B.r1 = Sr(6); B.c1 = Sc(6); B.v1 = Sv(6);
        B.r2 = Sr(1); B.c2 = Sc(1); B.v2 = Sv(1);
        B.r3 = B.r2; B.c3 = B.c2; B.v3 = B.v2;
        B.r4 = B.r2; B.c4 = B.c2; B.v4 = B.v2;
        B.r5 = B.r2; B.c5 = B.c2; B.v5 = B.v2;
        B.r6 = B.r2; B.c6 = B.c2; B.v6 = B.v2;
        B.p1 = Sn(4);
        B.p2 = B.p1 + Sn(6);
        B.p3 = B.p2 + Sn(1);
        B.p4 = B.p3; B.p5 = B.p3; B.p6 = B.p3; B.p7 = B.p3;
        B.t0 = 0; B.t1 = 0; B.t2 = 0; B.t3 = 0; B.t4 = 0; B.t5 = 0; B.t6 = 0;

        const int NGB = (NB1 + 7) / 8;
        const int chunk = (B.p7 + GRID_BIN - 1) / GRID_BIN;
        hipMemsetAsync(gcount, 0, (size_t)NGB * sizeof(int), stream);
        bhist_grp<<<GRID_BIN, 1024, 0, stream>>>(B, gcount, NGB, chunk);
        scan_small<<<1, 1024, 0, stream>>>(gcount, goff, gcur, NGB);
        scatter_grp<<<GRID_BIN, 1024, 0, stream>>>(B, gcur, payA, NGB, chunk);
        sort_grp<<<NGB, 1024, 0, stream>>>(payA, goff, gcur, rowoff, bend,
                                           bpayB, rowperm, NB1);

        if (fullB) {
            unsigned short* dn2e = dense;
            unsigned short* dt2e = dense + (size_t)N0 * 64;
            unsigned short* de2e = dense + ((size_t)N0 + N2) * 64;
            gemm_powcat_mfma<<<(N0 + 63) / 64, 256, 0, stream>>>(
                X0, N0, 1, wf(1), bp(1), dn2e,
                wf(1), bp(1), dn2e, wf(1), bp(1), dn2e);
            gemm_powcat_mfma<<<(N2 + 63) / 64, 256, 0, stream>>>(
                X2, N2, 1, wf(5), bp(5), dt2e,
                wf(5), bp(5), dt2e, wf(5), bp(5), dt2e);
            gemm_powcat_mfma<<<(N1 + 63) / 64, 256, 0, stream>>>(
                X1, N1, 1, wf(2), bp(2), de2e,
                wf(2), bp(2), de2e, wf(2), bp(2), de2e);
            spmm_stream7<<<NB1, 256, 0, stream>>>(bpayB, rowoff, bend, rowperm,
                dn2e, dt2e, de2e, dn2e, dn2e, dn2e, dn2e,
                out + offY1, 0, N1, 1, 1, TH, 0x7F);
        } else {
            unsigned short* dn2e = dense;
            unsigned short* dt2e = dense + (size_t)N0 * 64;
            gemm_powcat_mfma<<<(N0 + 63) / 64, 256, 0, stream>>>(
                X0, N0, 1, wf(1), bp(1), dn2e,
                wf(1), bp(1), dn2e, wf(1), bp(1), dn2e);
            gemm_powcat_mfma<<<(N2 + 63) / 64, 256, 0, stream>>>(
                X2, N2, 1, wf(5), bp(5), dt2e,
                wf(5), bp(5), dt2e, wf(5), bp(5), dt2e);
            spmm_stream7<<<NB1, 256, 0, stream>>>(bpayB, rowoff, bend, rowperm,
                dn2e, dt2e, dn2e, dn2e, dn2e, dn2e, dn2e,
                out + offY1, 0, N1, 1, 0, 0.f, 0x3);
            unsigned short* de2e = dense;
            gemm_powcat_mfma<<<(N1 + 63) / 64, 256, 0, stream>>>(
                X1, N1, 1, wf(2), bp(2), de2e,
                wf(2), bp(2), de2e, wf(2), bp(2), de2e);
            spmm_stream7<<<NB1, 256, 0, stream>>>(bpayB, rowoff, bend, rowperm,
                de2e, de2e, de2e, de2e, de2e, de2e, de2e,
                out + offY1, 0, N1, 0, 1, TH, 0x4);
        }
    }
}

// Round 11
// 503.841 us; speedup vs baseline: 1.1042x; 1.0139x over previous
//
#include <hip/hip_runtime.h>
#include <hip/hip_bf16.h>

// SCConv: two-level radix binning (pass A: 8-bucket groups with run-reserved
// scatter, folding the dense-table base into the column index; pass B:
// per-group 1024-bin LDS-staged counting sort to (bucket,row) order with
// coalesced flush, emitting rowoff/bend + a per-bucket row permutation
// sorted by row length), 3 fused powcat-GEMMs on MFMA (split-bf16 3-term),
// then ONE merged streaming spmm over all output segments (8-lanes-per-row
// dwordx4 gathers, depth-2 pipelined, single combined dense table).

#define RPB 128
#define COL_MASK 0x7FFFFu
#define LROW_SH 19
#define DID_SH 26
#define CCOL_MASK 0x1FFFFFu   // combined column: 21 bits
#define CLROW_SH 21
#define CBKT_SH 28
#define MAXNB 4352
#define MAXNG 544
#define GRID_BIN 256
#define SPMM_GRID 2048

// sort phasing: destination positions are processed in windows of SORT_PH;
// LDS capacity covers PH + max single-bin size.
#define SORT_PH     16384
#define SORT_LOG    14
#define SORT_MAXBIN 2048
#define SORT_CAP    (SORT_PH + SORT_MAXBIN)   // 18432 entries = 144 KB
#define MAXPH 8

typedef __attribute__((ext_vector_type(8))) short short8;
typedef __attribute__((ext_vector_type(4))) float f32x4;

__device__ __forceinline__ int   ntld_i(const int* p)   { return __builtin_nontemporal_load(p); }
__device__ __forceinline__ float ntld_f(const float* p) { return __builtin_nontemporal_load(p); }
__device__ __forceinline__ float4 ntld_f4(const float* p) {
    const unsigned long long* q = (const unsigned long long*)p;
    unsigned long long a = __builtin_nontemporal_load(q);
    unsigned long long b = __builtin_nontemporal_load(q + 1);
    float4 v;
    v.x = __uint_as_float((unsigned)a);
    v.y = __uint_as_float((unsigned)(a >> 32));
    v.z = __uint_as_float((unsigned)b);
    v.w = __uint_as_float((unsigned)(b >> 32));
    return v;
}
__device__ __forceinline__ void ntst_f4(float* p, float4 v) {
    unsigned long long a = (unsigned long long)__float_as_uint(v.x)
                         | ((unsigned long long)__float_as_uint(v.y) << 32);
    unsigned long long b = (unsigned long long)__float_as_uint(v.z)
                         | ((unsigned long long)__float_as_uint(v.w) << 32);
    unsigned long long* q = (unsigned long long*)p;
    __builtin_nontemporal_store(a, q);
    __builtin_nontemporal_store(b, q + 1);
}

// ---------------- bf16 helpers (RNE) --------------------------------------
__device__ __forceinline__ unsigned short f2bf(float f) {
    unsigned u = __float_as_uint(f);
    unsigned r = u + 0x7FFFu + ((u >> 16) & 1u);
    return (unsigned short)(r >> 16);
}

__device__ __forceinline__ void split8(float4 a0, float4 a1, short8& hi, short8& lo) {
    float v[8] = {a0.x, a0.y, a0.z, a0.w, a1.x, a1.y, a1.z, a1.w};
    #pragma unroll
    for (int e = 0; e < 8; ++e) {
        unsigned short h = f2bf(v[e]);
        float hf = __uint_as_float((unsigned)h << 16);
        hi[e] = (short)h;
        lo[e] = (short)f2bf(v[e] - hf);
    }
}

// ---------------- W -> MFMA B-fragment precompute (once per launch) -------
struct WAll { const float* w[7]; };

__global__ __launch_bounds__(256) void winit(WAll wa, unsigned short* __restrict__ frags)
{
    const int s = blockIdx.x;
    const float* __restrict__ W = wa.w[s];
    unsigned short* __restrict__ out = frags + (size_t)s * 16384;
    for (int slot = threadIdx.x; slot < 1024; slot += 256) {
        const int l  = slot & 63;
        const int nf = (slot >> 6) & 3;
        const int kk = slot >> 8;
        const int col = nf * 16 + (l & 15);
        const int kb  = kk * 32 + 8 * (l >> 4);
        short8 vh, vl;
        #pragma unroll
        for (int e = 0; e < 8; ++e) {
            float w = W[(size_t)(kb + e) * 64 + col];
            unsigned short h = f2bf(w);
            float hf = __uint_as_float((unsigned)h << 16);
            vh[e] = (short)h;
            vl[e] = (short)f2bf(w - hf);
        }
        *(short8*)(out + ((size_t)((kk * 4 + nf) * 2 + 0) * 64 + l) * 8) = vh;
        *(short8*)(out + ((size_t)((kk * 4 + nf) * 2 + 1) * 64 + l) * 8) = vl;
    }
}

// ---------------- MFMA powcat-GEMM (up to 3 weight sets per X) ------------
__device__ __forceinline__ void mfma_set(
    const short8 Ah[4], const short8 Al[4],
    const unsigned short* __restrict__ F, const float* __restrict__ bias,
    unsigned short* __restrict__ D, int nrows, int row0w, int l)
{
    const int lg = l >> 4, lr = l & 15;
    const short8* __restrict__ Fv = (const short8*)F;
    f32x4 acc[4];
    #pragma unroll
    for (int nf = 0; nf < 4; ++nf) {
        float b = bias[nf * 16 + lr];
        f32x4 bi = {b, b, b, b};
        acc[nf] = bi;
    }
    #pragma unroll
    for (int kk = 0; kk < 4; ++kk) {
        #pragma unroll
        for (int nf = 0; nf < 4; ++nf) {
            short8 bh = Fv[((kk * 4 + nf) * 2 + 0) * 64 + l];
            short8 bl = Fv[((kk * 4 + nf) * 2 + 1) * 64 + l];
            acc[nf] = __builtin_amdgcn_mfma_f32_16x16x32_bf16(Ah[kk], bh, acc[nf], 0, 0, 0);
            acc[nf] = __builtin_amdgcn_mfma_f32_16x16x32_bf16(Al[kk], bh, acc[nf], 0, 0, 0);
            acc[nf] = __builtin_amdgcn_mfma_f32_16x16x32_bf16(Ah[kk], bl, acc[nf], 0, 0, 0);
        }
    }
    #pragma unroll
    for (int nf = 0; nf < 4; ++nf) {
        #pragma unroll
        for (int j = 0; j < 4; ++j) {
            int row = row0w + lg * 4 + j;   // C/D: col=lane&15, row=4*(lane>>4)+reg
            if (row < nrows)
                D[(size_t)row * 64 + nf * 16 + lr] = f2bf(acc[nf][j]);
        }
    }
}

__global__ __launch_bounds__(256) void gemm_powcat_mfma(
    const float* __restrict__ X, int nrows, int nsets,
    const unsigned short* __restrict__ F0, const float* __restrict__ b0, unsigned short* __restrict__ D0,
    const unsigned short* __restrict__ F1, const float* __restrict__ b1, unsigned short* __restrict__ D1,
    const unsigned short* __restrict__ F2, const float* __restrict__ b2, unsigned short* __restrict__ D2)
{
    __shared__ float Xs[64][68];   // pad stride 68 -> balanced LDS banks
    const int tid = threadIdx.x;
    const int row0 = blockIdx.x * 64;

    #pragma unroll
    for (int it = 0; it < 4; ++it) {
        int idx = tid + it * 256;
        int r = idx >> 4, c4 = idx & 15;
        float4 v = make_float4(0.f, 0.f, 0.f, 0.f);
        if (row0 + r < nrows)
            v = ntld_f4(X + (size_t)(row0 + r) * 64 + c4 * 4);
        *(float4*)&Xs[r][c4 * 4] = v;
    }
    __syncthreads();

    const int w = tid >> 6, l = tid & 63;
    const int lg = l >> 4, lr = l & 15;

    // A-frags (shared across all weight sets): powcat K=128 = [X | X^2]
    short8 Ah[4], Al[4];
    #pragma unroll
    for (int kk = 0; kk < 4; ++kk) {
        const float* p = &Xs[w * 16 + lr][(kk & 1) * 32 + 8 * lg];
        float4 a0 = *(const float4*)p;
        float4 a1 = *(const float4*)(p + 4);
        if (kk >= 2) {
            a0.x *= a0.x; a0.y *= a0.y; a0.z *= a0.z; a0.w *= a0.w;
            a1.x *= a1.x; a1.y *= a1.y; a1.z *= a1.z; a1.w *= a1.w;
        }
        split8(a0, a1, Ah[kk], Al[kk]);
    }

    const int row0w = row0 + w * 16;
    mfma_set(Ah, Al, F0, b0, D0, nrows, row0w, l);
    if (nsets > 1) mfma_set(Ah, Al, F1, b1, D1, nrows, row0w, l);
    if (nsets > 2) mfma_set(Ah, Al, F2, b2, D2, nrows, row0w, l);
}

// ---------------- 7-slot flat COO view ------------------------------------
struct Bin7 {
    const int *r0, *r1, *r2, *r3, *r4, *r5, *r6;
    const int *c0, *c1, *c2, *c3, *c4, *c5, *c6;
    const float *v0, *v1, *v2, *v3, *v4, *v5, *v6;
    int p1, p2, p3, p4, p5, p6, p7;   // cumulative prefix ends
    int t0, t1, t2, t3, t4, t5, t6;   // bucket-tile base per slot
};

struct CBase { int b[8]; };           // per-did combined-column row base

struct Ent { int r; int tb; unsigned cw; float v; };

template<bool FULL>
__device__ __forceinline__ Ent decode(const Bin7& B, int i) {
    Ent e;
    if (i < B.p1) {
        int li = i;
        e.r = ntld_i(B.r0 + li); e.tb = B.t0;
        if (FULL) { e.cw = (unsigned)ntld_i(B.c0 + li) | (0u << DID_SH); e.v = ntld_f(B.v0 + li); }
    } else if (i < B.p2) {
        int li = i - B.p1;
        e.r = ntld_i(B.r1 + li); e.tb = B.t1;
        if (FULL) { e.cw = (unsigned)ntld_i(B.c1 + li) | (1u << DID_SH); e.v = ntld_f(B.v1 + li); }
    } else if (i < B.p3) {
        int li = i - B.p2;
        e.r = ntld_i(B.r2 + li); e.tb = B.t2;
        if (FULL) { e.cw = (unsigned)ntld_i(B.c2 + li) | (2u << DID_SH); e.v = ntld_f(B.v2 + li); }
    } else if (i < B.p4) {
        int li = i - B.p3;
        e.r = ntld_i(B.r3 + li); e.tb = B.t3;
        if (FULL) { e.cw = (unsigned)ntld_i(B.c3 + li) | (3u << DID_SH); e.v = ntld_f(B.v3 + li); }
    } else if (i < B.p5) {
        int li = i - B.p4;
        e.r = ntld_i(B.r4 + li); e.tb = B.t4;
        if (FULL) { e.cw = (unsigned)ntld_i(B.c4 + li) | (4u << DID_SH); e.v = ntld_f(B.v4 + li); }
    } else if (i < B.p6) {
        int li = i - B.p5;
        e.r = ntld_i(B.r5 + li); e.tb = B.t5;
        if (FULL) { e.cw = (unsigned)ntld_i(B.c5 + li) | (5u << DID_SH); e.v = ntld_f(B.v5 + li); }
    } else {
        int li = i - B.p6;
        e.r = ntld_i(B.r6 + li); e.tb = B.t6;
        if (FULL) { e.cw = (unsigned)ntld_i(B.c6 + li) | (6u << DID_SH); e.v = ntld_f(B.v6 + li); }
    }
    return e;
}

// ---------------- group histogram (8 buckets per group) -------------------
__global__ __launch_bounds__(1024) void bhist_grp(
    Bin7 B, int* __restrict__ gcount, int NG, int chunk)
{
    __shared__ int h[MAXNG];
    for (int i = threadIdx.x; i < NG; i += 1024) h[i] = 0;
    __syncthreads();
    const int s = blockIdx.x * chunk;
    int e = s + chunk;  if (e > B.p7) e = B.p7;
    for (int i = s + threadIdx.x; i < e; i += 1024) {
        Ent en = decode<false>(B, i);
        atomicAdd(&h[(en.tb + (en.r >> 7)) >> 3], 1);
    }
    __syncthreads();
    for (int i = threadIdx.x; i < NG; i += 1024)
        if (h[i]) atomicAdd(&gcount[i], h[i]);
}

// ---------------- pass A (tier 1): scatter with combined column -----------
// payA word: colC(21) | lrow(7)<<21 | (bucket&7)<<28
__global__ __launch_bounds__(1024) void scatter_grpC(
    Bin7 B, CBase cb, int* __restrict__ gcur, uint2* __restrict__ payA,
    int NG, int chunk)
{
    __shared__ int lbase[MAXNG];
    __shared__ int lcur[MAXNG];
    __shared__ int cbs[8];
    if (threadIdx.x < 8) cbs[threadIdx.x] = cb.b[threadIdx.x];
    for (int i = threadIdx.x; i < NG; i += 1024) lcur[i] = 0;
    __syncthreads();
    const int s = blockIdx.x * chunk;
    int e = s + chunk;  if (e > B.p7) e = B.p7;

    for (int i = s + threadIdx.x; i < e; i += 1024) {
        Ent en = decode<false>(B, i);
        atomicAdd(&lcur[(en.tb + (en.r >> 7)) >> 3], 1);
    }
    __syncthreads();
    for (int i = threadIdx.x; i < NG; i += 1024) {
        int c = lcur[i];
        lbase[i] = c ? atomicAdd(&gcur[i], c) : 0;
        lcur[i] = 0;
    }
    __syncthreads();
    for (int i = s + threadIdx.x; i < e; i += 1024) {
        Ent en = decode<true>(B, i);
        int b = en.tb + (en.r >> 7);
        int g = b >> 3;
        int pos = lbase[g] + atomicAdd(&lcur[g], 1);
        int did = (int)(en.cw >> DID_SH);
        unsigned colC = (en.cw & COL_MASK) + (unsigned)cbs[did];
        unsigned cwA = colC | ((unsigned)(en.r & 127) << CLROW_SH)
                     | ((unsigned)(b & 7) << CBKT_SH);
        payA[pos] = make_uint2(cwA, __float_as_uint(en.v));
    }
}

// ---------------- pass B (tier 1): 1024-bin LDS-staged counting sort ------
// Sort key = bits 21..30 (lrow | (bucket&7)<<7). payB.x = pure colC.
// Emits rowoff, bend, and rowperm (rows ranked by descending length).
__global__ __launch_bounds__(1024) void sort_grpC(
    const uint2* __restrict__ payA, const int* __restrict__ goff,
    const int* __restrict__ gcur, int* __restrict__ rowoff,
    int* __restrict__ bend, uint2* __restrict__ payB,
    unsigned char* __restrict__ rowperm, int NBtot)
{
    __shared__ uint2 lpay[SORT_CAP];      // 144 KB
    __shared__ int cnt[1024];             // hist, then cur
    __shared__ int off[1024];             // exclusive scan (immutable)
    __shared__ unsigned char cnts8[1024]; // clamped counts for ranking
    __shared__ int wsum[16];
    __shared__ int phstart[MAXPH + 1];
    __shared__ int s_nph, s_maxbin;

    const int g = blockIdx.x;
    const int tid = threadIdx.x;
    const int seg0 = goff[g], seg1 = gcur[g];
    const int n = seg1 - seg0;

    cnt[tid] = 0;
    if (tid == 0) s_maxbin = 0;
    __syncthreads();
    for (int i = seg0 + tid; i < seg1; i += 1024) {
        unsigned w = __builtin_nontemporal_load(&payA[i].x);
        atomicAdd(&cnt[(w >> CLROW_SH) & 1023], 1);
    }
    __syncthreads();

    const int lane = tid & 63, wv = tid >> 6;
    const int tot = cnt[tid];
    atomicMax(&s_maxbin, tot);
    cnts8[tid] = (unsigned char)(tot > 255 ? 255 : tot);
    int x = tot;
    #pragma unroll
    for (int o = 1; o < 64; o <<= 1) {
        int y = __shfl_up(x, o);
        if (lane >= o) x += y;
    }
    if (lane == 63) wsum[wv] = x;
    __syncthreads();
    if (tid < 16) {
        int ss = wsum[tid];
        #pragma unroll
        for (int o = 1; o < 16; o <<= 1) {
            int y = __shfl_up(ss, o, 16);
            if (tid >= o) ss += y;
        }
        wsum[tid] = ss;
    }
    __syncthreads();
    const int excl = (x - tot) + ((wv == 0) ? 0 : wsum[wv - 1]);
    off[tid] = excl;
    rowoff[(size_t)g * 1024 + tid] = seg0 + excl;
    {
        int b = g * 8 + (tid >> 7);
        if (b < NBtot && (tid & 127) == 127) bend[b] = seg0 + excl + tot;
    }
    __syncthreads();   // off[] + cnts8[] complete
    cnt[tid] = excl;   // cnt becomes cur
    {
        int p = excl >> SORT_LOG;
        int pprev = (tid == 0) ? -1 : (off[tid - 1] >> SORT_LOG);
        for (int q = pprev + 1; q <= p && q <= MAXPH; ++q) phstart[q] = excl;
        if (tid == 1023) s_nph = p + 1;
    }

    // rank rows by descending length within each 128-row bucket (bijective)
    {
        const int myr = tid & 127, b0 = tid & ~127;
        const unsigned char myc = cnts8[tid];
        int rank = 0;
        #pragma unroll 8
        for (int r = 0; r < 128; ++r) {
            unsigned char c = cnts8[b0 + r];
            rank += (c > myc) || (c == myc && r < myr);
        }
        rowperm[(size_t)g * 1024 + b0 + rank] = (unsigned char)myr;
    }
    __syncthreads();

    const int nph = s_nph;
    if (n <= 0) return;

    if (s_maxbin <= SORT_MAXBIN && nph <= MAXPH) {
        for (int ph = 0; ph < nph; ++ph) {
            const int ps = phstart[ph];
            const int pe = (ph + 1 < nph) ? phstart[ph + 1] : n;
            for (int i = seg0 + tid; i < seg1; i += 1024) {
                unsigned long long pv = __builtin_nontemporal_load(
                    (const unsigned long long*)(payA + i));
                unsigned w = (unsigned)pv;
                int bin = (w >> CLROW_SH) & 1023;
                if ((off[bin] >> SORT_LOG) == ph) {
                    int pos = atomicAdd(&cnt[bin], 1);
                    lpay[pos - ps] = make_uint2(w, (unsigned)(pv >> 32));
                }
            }
            __syncthreads();
            for (int k = tid; k < pe - ps; k += 1024) {
                uint2 pv = lpay[k];
                unsigned long long o2 = (unsigned long long)(pv.x & CCOL_MASK)
                                      | ((unsigned long long)pv.y << 32);
                __builtin_nontemporal_store(o2,
                    (unsigned long long*)(payB + seg0 + ps + k));
            }
            __syncthreads();
        }
    } else {
        // fallback: direct global scatter (pathological bin sizes only)
        for (int i = seg0 + tid; i < seg1; i += 1024) {
            unsigned long long pv = __builtin_nontemporal_load(
                (const unsigned long long*)(payA + i));
            unsigned w = (unsigned)pv;
            int bin = (w >> CLROW_SH) & 1023;
            int pos = seg0 + atomicAdd(&cnt[bin], 1);
            payB[pos] = make_uint2(w & CCOL_MASK, (unsigned)(pv >> 32));
        }
    }
}

// ---------------- tier-2 kernels (old did-encoded scheme, unchanged) ------
__global__ __launch_bounds__(1024) void scatter_grp(
    Bin7 B, int* __restrict__ gcur, uint2* __restrict__ payA,
    int NG, int chunk)
{
    __shared__ int lbase[MAXNG];
    __shared__ int lcur[MAXNG];
    for (int i = threadIdx.x; i < NG; i += 1024) lcur[i] = 0;
    __syncthreads();
    const int s = blockIdx.x * chunk;
    int e = s + chunk;  if (e > B.p7) e = B.p7;

    for (int i = s + threadIdx.x; i < e; i += 1024) {
        Ent en = decode<false>(B, i);
        atomicAdd(&lcur[(en.tb + (en.r >> 7)) >> 3], 1);
    }
    __syncthreads();
    for (int i = threadIdx.x; i < NG; i += 1024) {
        int c = lcur[i];
        lbase[i] = c ? atomicAdd(&gcur[i], c) : 0;
        lcur[i] = 0;
    }
    __syncthreads();
    for (int i = s + threadIdx.x; i < e; i += 1024) {
        Ent en = decode<true>(B, i);
        int b = en.tb + (en.r >> 7);
        int g = b >> 3;
        int pos = lbase[g] + atomicAdd(&lcur[g], 1);
        unsigned col = en.cw & COL_MASK;
        unsigned did = en.cw >> DID_SH;
        unsigned cwA = col | ((unsigned)(en.r & 127) << LROW_SH)
                     | ((unsigned)(b & 7) << 26) | (did << 29);
        payA[pos] = make_uint2(cwA, __float_as_uint(en.v));
    }
}

__global__ __launch_bounds__(1024) void sort_grp(
    const uint2* __restrict__ payA, const int* __restrict__ goff,
    const int* __restrict__ gcur, int* __restrict__ rowoff,
    int* __restrict__ bend, uint2* __restrict__ payB,
    unsigned char* __restrict__ rowperm, int NBtot)
{
    __shared__ uint2 lpay[SORT_CAP];
    __shared__ int cnt[1024];
    __shared__ int off[1024];
    __shared__ unsigned char cnts8[1024];
    __shared__ int wsum[16];
    __shared__ int phstart[MAXPH + 1];
    __shared__ int s_nph, s_maxbin;

    const int g = blockIdx.x;
    const int tid = threadIdx.x;
    const int seg0 = goff[g], seg1 = gcur[g];
    const int n = seg1 - seg0;

    cnt[tid] = 0;
    if (tid == 0) s_maxbin = 0;
    __syncthreads();
    for (int i = seg0 + tid; i < seg1; i += 1024) {
        unsigned w = __builtin_nontemporal_load(&payA[i].x);
        atomicAdd(&cnt[(w >> 19) & 1023], 1);
    }
    __syncthreads();

    const int lane = tid & 63, wv = tid >> 6;
    const int tot = cnt[tid];
    atomicMax(&s_maxbin, tot);
    cnts8[tid] = (unsigned char)(tot > 255 ? 255 : tot);
    int x = tot;
    #pragma unroll
    for (int o = 1; o < 64; o <<= 1) {
        int y = __shfl_up(x, o);
        if (lane >= o) x += y;
    }
    if (lane == 63) wsum[wv] = x;
    __syncthreads();
    if (tid < 16) {
        int ss = wsum[tid];
        #pragma unroll
        for (int o = 1; o < 16; o <<= 1) {
            int y = __shfl_up(ss, o, 16);
            if (tid >= o) ss += y;
        }
        wsum[tid] = ss;
    }
    __syncthreads();
    const int excl = (x - tot) + ((wv == 0) ? 0 : wsum[wv - 1]);
    off[tid] = excl;
    rowoff[(size_t)g * 1024 + tid] = seg0 + excl;
    {
        int b = g * 8 + (tid >> 7);
        if (b < NBtot && (tid & 127) == 127) bend[b] = seg0 + excl + tot;
    }
    __syncthreads();
    cnt[tid] = excl;
    {
        int p = excl >> SORT_LOG;
        int pprev = (tid == 0) ? -1 : (off[tid - 1] >> SORT_LOG);
        for (int q = pprev + 1; q <= p && q <= MAXPH; ++q) phstart[q] = excl;
        if (tid == 1023) s_nph = p + 1;
    }

    {
        const int myr = tid & 127, b0 = tid & ~127;
        const unsigned char myc = cnts8[tid];
        int rank = 0;
        #pragma unroll 8
        for (int r = 0; r < 128; ++r) {
            unsigned char c = cnts8[b0 + r];
            rank += (c > myc) || (c == myc && r < myr);
        }
        rowperm[(size_t)g * 1024 + b0 + rank] = (unsigned char)myr;
    }
    __syncthreads();

    const int nph = s_nph;
    if (n <= 0) return;

    if (s_maxbin <= SORT_MAXBIN && nph <= MAXPH) {
        for (int ph = 0; ph < nph; ++ph) {
            const int ps = phstart[ph];
            const int pe = (ph + 1 < nph) ? phstart[ph + 1] : n;
            for (int i = seg0 + tid; i < seg1; i += 1024) {
                unsigned long long pv = __builtin_nontemporal_load(
                    (const unsigned long long*)(payA + i));
                unsigned w = (unsigned)pv;
                int bin = (w >> 19) & 1023;
                if ((off[bin] >> SORT_LOG) == ph) {
                    int pos = atomicAdd(&cnt[bin], 1);
                    lpay[pos - ps] = make_uint2(w, (unsigned)(pv >> 32));
                }
            }
            __syncthreads();
            for (int k = tid; k < pe - ps; k += 1024) {
                uint2 pv = lpay[k];
                unsigned cw = (pv.x & 0x03FFFFFFu) | ((pv.x >> 29) << 26);
                unsigned long long o2 = (unsigned long long)cw
                                      | ((unsigned long long)pv.y << 32);
                __builtin_nontemporal_store(o2,
                    (unsigned long long*)(payB + seg0 + ps + k));
            }
            __syncthreads();
        }
    } else {
        for (int i = seg0 + tid; i < seg1; i += 1024) {
            unsigned long long pv = __builtin_nontemporal_load(
                (const unsigned long long*)(payA + i));
            unsigned w = (unsigned)pv;
            int bin = (w >> 19) & 1023;
            int pos = seg0 + atomicAdd(&cnt[bin], 1);
            unsigned cw = (w & 0x03FFFFFFu) | ((w >> 29) << 26);
            payB[pos] = make_uint2(cw, (unsigned)(pv >> 32));
        }
    }
}

// ---------------- shfl-based single-block exclusive scan ------------------
__global__ __launch_bounds__(1024) void scan_small(
    const int* __restrict__ in, int* __restrict__ boff,
    int* __restrict__ bcur, int n)
{
    __shared__ int wsum[16];
    __shared__ int carry;
    const int tid = threadIdx.x, lane = tid & 63, wv = tid >> 6;
    if (tid == 0) carry = 0;
    __syncthreads();
    for (int base = 0; base < n; base += 4096) {
        int i = base + tid * 4;
        int v0 = (i + 0 < n) ? in[i + 0] : 0;
        int v1 = (i + 1 < n) ? in[i + 1] : 0;
        int v2 = (i + 2 < n) ? in[i + 2] : 0;
        int v3 = (i + 3 < n) ? in[i + 3] : 0;
        int tsum = v0 + v1 + v2 + v3;
        int x = tsum;
        #pragma unroll
        for (int off = 1; off < 64; off <<= 1) {
            int y = __shfl_up(x, off);
            if (lane >= off) x += y;
        }
        if (lane == 63) wsum[wv] = x;
        int c0 = carry;
        __syncthreads();
        if (tid < 16) {
            int ss = wsum[tid];
            #pragma unroll
            for (int off = 1; off < 16; off <<= 1) {
                int y = __shfl_up(ss, off, 16);
                if (tid >= off) ss += y;
            }
            wsum[tid] = ss;
        }
        __syncthreads();
        int wpre = (wv == 0) ? 0 : wsum[wv - 1];
        int excl = c0 + wpre + (x - tsum);
        if (i + 0 < n) { boff[i + 0] = excl; bcur[i + 0] = excl; } excl += v0;
        if (i + 1 < n) { boff[i + 1] = excl; bcur[i + 1] = excl; } excl += v1;
        if (i + 2 < n) { boff[i + 2] = excl; bcur[i + 2] = excl; } excl += v2;
        if (i + 3 < n) { boff[i + 3] = excl; bcur[i + 3] = excl; }
        __syncthreads();
        if (tid == 0) carry = c0 + wsum[15];
        __syncthreads();
    }
}

// ---------------- combined-table row accumulate: 8 lanes/row, dwordx4 -----
// Each lane covers 16 B (8 bf16 columns) of the dense row; a wave covers
// 8 rows. Depth-2 pipelined gathers; payload broadcast within 8-lane group.
__device__ __forceinline__ void facc8(float4& alo, float4& ahi, float v, uint4 d) {
    alo.x = fmaf(v, __uint_as_float((d.x & 0xFFFFu) << 16), alo.x);
    alo.y = fmaf(v, __uint_as_float(d.x & 0xFFFF0000u), alo.y);
    alo.z = fmaf(v, __uint_as_float((d.y & 0xFFFFu) << 16), alo.z);
    alo.w = fmaf(v, __uint_as_float(d.y & 0xFFFF0000u), alo.w);
    ahi.x = fmaf(v, __uint_as_float((d.z & 0xFFFFu) << 16), ahi.x);
    ahi.y = fmaf(v, __uint_as_float(d.z & 0xFFFF0000u), ahi.y);
    ahi.z = fmaf(v, __uint_as_float((d.w & 0xFFFFu) << 16), ahi.z);
    ahi.w = fmaf(v, __uint_as_float(d.w & 0xFFFF0000u), ahi.w);
}

__device__ __forceinline__ void row_accumC8(
    const uint2* __restrict__ payB, int js, int je,
    const uint4* __restrict__ Dg, int l8, float4& alo, float4& ahi)
{
    alo = make_float4(0.f, 0.f, 0.f, 0.f);
    ahi = make_float4(0.f, 0.f, 0.f, 0.f);
    const int n = je - js;
    if (n <= 0) return;
    const uint2* base = payB + js;
    uint2 p0 = base[0];
    uint2 p1 = base[(n > 1) ? 1 : 0];
    float v0 = __uint_as_float(p0.y);
    float v1 = (n > 1) ? __uint_as_float(p1.y) : 0.f;
    uint4 d0 = Dg[(size_t)p0.x * 8 + l8];
    uint4 d1 = Dg[(size_t)p1.x * 8 + l8];
    int i = 0;
    while (true) {
        int i2 = (i + 2 < n) ? i + 2 : n - 1;
        int i3 = (i + 3 < n) ? i + 3 : n - 1;
        uint2 q0 = base[i2];
        uint2 q1 = base[i3];
        float w0 = (i + 2 < n) ? __uint_as_float(q0.y) : 0.f;
        float w1 = (i + 3 < n) ? __uint_as_float(q1.y) : 0.f;
        uint4 e0 = Dg[(size_t)q0.x * 8 + l8];   // issued before d0/d1 waited on
        uint4 e1 = Dg[(size_t)q1.x * 8 + l8];   // -> 2 gathers in flight
        facc8(alo, ahi, v0, d0);
        facc8(alo, ahi, v1, d1);
        i += 2;
        if (i >= n) break;
        v0 = w0; v1 = w1; d0 = e0; d1 = e1;
    }
}

// ---------------- merged streaming SpMM (tier 1, combined table) ----------
__global__ __launch_bounds__(256) void spmm_stream_allC(
    const uint2* __restrict__ payB, const int* __restrict__ rowoff,
    const int* __restrict__ bend, const unsigned char* __restrict__ rowperm,
    const unsigned short* __restrict__ dense,
    float* __restrict__ out, int NB0, int NB01, int NBall,
    int N0, int N1, int N2)
{
    const uint4* __restrict__ Dg = reinterpret_cast<const uint4*>(dense);
    const int tid = threadIdx.x;
    const int slot = tid >> 3;   // 0..31: row slot (8 per wave, ranks adjacent)
    const int l8 = tid & 7;      // 16-B chunk within the 128-B dense row

    for (int t = blockIdx.x; t < NBall; t += gridDim.x) {
        int tb, nrows; float scale; float* oseg;
        if (t < NB0)       { tb = 0;    nrows = N0; oseg = out;                          scale = 0.5f; }
        else if (t < NB01) { tb = NB0;  nrows = N1; oseg = out + (size_t)N0 * 64;        scale = 1.0f / 3.0f; }
        else               { tb = NB01; nrows = N2; oseg = out + (size_t)(N0 + N1) * 64; scale = 0.5f; }
        const int row0 = (t - tb) * RPB;
        const int rbase = t * RPB;
        const int bendt = bend[t];
        const unsigned char* perm = rowperm + (size_t)t * RPB;

        #pragma unroll 1
        for (int rr = 0; rr < 4; ++rr) {
            const int lr = perm[rr * 32 + slot];   // length-balanced wave rows
            const int row = row0 + lr;
            const int js = rowoff[rbase + lr];
            const int je = (lr == 127) ? bendt : rowoff[rbase + lr + 1];
            float4 alo, ahi;
            row_accumC8(payB, js, je, Dg, l8, alo, ahi);
            if (row < nrows) {
                float* o = oseg + (size_t)row * 64 + l8 * 8;
                alo.x = fmaxf(alo.x, 0.f) * scale;
                alo.y = fmaxf(alo.y, 0.f) * scale;
                alo.z = fmaxf(alo.z, 0.f) * scale;
                alo.w = fmaxf(alo.w, 0.f) * scale;
                ahi.x = fmaxf(ahi.x, 0.f) * scale;
                ahi.y = fmaxf(ahi.y, 0.f) * scale;
                ahi.z = fmaxf(ahi.z, 0.f) * scale;
                ahi.w = fmaxf(ahi.w, 0.f) * scale;
                ntst_f4(o, alo);
                ntst_f4(o + 4, ahi);
            }
        }
    }
}

// ---------------- tier-2 per-segment SpMM (old scheme, unchanged) ---------
__device__ __forceinline__ void facc(float4& a, float v, uint2 d) {
    a.x = fmaf(v, __uint_as_float((d.x & 0xFFFFu) << 16), a.x);
    a.y = fmaf(v, __uint_as_float(d.x & 0xFFFF0000u), a.y);
    a.z = fmaf(v, __uint_as_float((d.y & 0xFFFFu) << 16), a.z);
    a.w = fmaf(v, __uint_as_float(d.y & 0xFFFF0000u), a.w);
}

__device__ __forceinline__ float mval(uint2 p, int didMask) {
    int did = (int)(p.x >> DID_SH) & 7;
    return ((didMask >> did) & 1) ? __uint_as_float(p.y) : 0.f;
}
__device__ __forceinline__ uint2 dgather(uint2 p, int l,
    const unsigned short* const* dptr)
{
    const uint2* Dg = reinterpret_cast<const uint2*>(dptr[(p.x >> DID_SH) & 7]);
    return Dg[(size_t)(p.x & COL_MASK) * 16 + l];
}

__device__ __forceinline__ float4 row_accum(
    const uint2* __restrict__ payB, int js, int je,
    const unsigned short* const* dptr, int l, int didMask)
{
    float4 a = make_float4(0.f, 0.f, 0.f, 0.f);
    const int n = je - js;
    if (n <= 0) return a;
    const uint2* base = payB + js;
    uint2 p0 = base[0];
    uint2 p1 = base[(n > 1) ? 1 : 0];
    float v0 = mval(p0, didMask);
    float v1 = (n > 1) ? mval(p1, didMask) : 0.f;
    uint2 d0 = dgather(p0, l, dptr);
    uint2 d1 = dgather(p1, l, dptr);
    int i = 0;
    while (true) {
        int i2 = (i + 2 < n) ? i + 2 : n - 1;
        int i3 = (i + 3 < n) ? i + 3 : n - 1;
        uint2 q0 = base[i2];
        uint2 q1 = base[i3];
        float w0 = (i + 2 < n) ? mval(q0, didMask) : 0.f;
        float w1 = (i + 3 < n) ? mval(q1, didMask) : 0.f;
        uint2 e0 = dgather(q0, l, dptr);
        uint2 e1 = dgather(q1, l, dptr);
        facc(a, v0, d0);
        facc(a, v1, d1);
        i += 2;
        if (i >= n) break;
        v0 = w0; v1 = w1; d0 = e0; d1 = e1;
    }
    return a;
}

__global__ __launch_bounds__(256) void spmm_stream7(
    const uint2* __restrict__ payB, const int* __restrict__ rowoff,
    const int* __restrict__ bend, const unsigned char* __restrict__ rowperm,
    const unsigned short* __restrict__ d0, const unsigned short* __restrict__ d1,
    const unsigned short* __restrict__ d2, const unsigned short* __restrict__ d3,
    const unsigned short* __restrict__ d4, const unsigned short* __restrict__ d5,
    const unsigned short* __restrict__ d6,
    float* __restrict__ out, int tile0, int nrows,
    int firstWrite, int doRelu, float scale, int didMask)
{
    __shared__ const unsigned short* dptr[8];
    const int tid = threadIdx.x;
    if (tid < 8) {
        const unsigned short* tbl[8] = {d0, d1, d2, d3, d4, d5, d6, d0};
        dptr[tid] = tbl[tid];
    }
    __syncthreads();

    const int t = tile0 + blockIdx.x;
    const int qw = tid >> 4, l = tid & 15;
    const int row0 = blockIdx.x * RPB;
    const int rbase = t * RPB;
    const int bendt = bend[t];
    const unsigned char* perm = rowperm + (size_t)t * RPB;

    #pragma unroll 1
    for (int rr = 0; rr < 8; ++rr) {
        const int lr = perm[rr * 16 + qw];
        const int row = row0 + lr;
        const int js = rowoff[rbase + lr];
        const int je = (lr == 127) ? bendt : rowoff[rbase + lr + 1];
        float4 a = row_accum(payB, js, je, dptr, l, didMask);

        if (row < nrows) {
            float* o = out + (size_t)row * 64 + l * 4;
            if (!firstWrite) {
                float4 cur = *reinterpret_cast<float4*>(o);
                a.x += cur.x; a.y += cur.y; a.z += cur.z; a.w += cur.w;
            }
            if (doRelu) {
                a.x = fmaxf(a.x, 0.f) * scale;
                a.y = fmaxf(a.y, 0.f) * scale;
                a.z = fmaxf(a.z, 0.f) * scale;
                a.w = fmaxf(a.w, 0.f) * scale;
            }
            ntst_f4(o, a);
        }
    }
}

extern "C" void kernel_launch(void* const* d_in, const int* in_sizes, int n_in,
                              void* d_out, int out_size, void* d_ws, size_t ws_size,
                              hipStream_t stream)
{
    const float* X0 = (const float*)d_in[0];
    const float* X1 = (const float*)d_in[1];
    const float* X2 = (const float*)d_in[2];
    const int N0 = in_sizes[0] / 64;
    const int N1 = in_sizes[1] / 64;
    const int N2 = in_sizes[2] / 64;

    auto Wp = [&](int i) { return (const float*)d_in[24 + 2 * i]; };
    auto bp = [&](int i) { return (const float*)d_in[25 + 2 * i]; };
    auto Sr = [&](int i) { return (const int*)d_in[3 + 3 * i]; };
    auto Sc = [&](int i) { return (const int*)d_in[4 + 3 * i]; };
    auto Sv = [&](int i) { return (const float*)d_in[5 + 3 * i]; };
    auto Sn = [&](int i) { return in_sizes[3 + 3 * i]; };

    const size_t offY1 = (size_t)N0 * 64;
    const size_t offY2 = (size_t)(N0 + N1) * 64;
    const float TH = 1.0f / 3.0f;

    const int NB0 = (N0 + RPB - 1) / RPB;
    const int NB1 = (N1 + RPB - 1) / RPB;
    const int NB2 = (N2 + RPB - 1) / RPB;

    float* out = (float*)d_out;
    auto align256 = [](size_t x) { return (x + 255) & ~(size_t)255; };

    // -------- W fragment precompute (all 7 sets, once) --------
    const size_t FRAG_SET = 16384;  // ushorts per set (32 KB)
    const size_t fragB = align256(7 * FRAG_SET * sizeof(unsigned short));
    if (ws_size <= fragB) return;   // pathological; cannot run
    unsigned short* wfrags = (unsigned short*)d_ws;
    char* ws = (char*)d_ws + fragB;
    const size_t ws_avail = ws_size - fragB;
    auto wf = [&](int i) { return wfrags + (size_t)i * FRAG_SET; };

    WAll wa;
    for (int i = 0; i < 7; ++i) wa.w[i] = Wp(i);
    winit<<<7, 256, 0, stream>>>(wa, wfrags);

    // -------- tier 1: everything at once --------
    const int NBall = NB0 + NB1 + NB2;
    const int NGall = (NBall + 7) / 8;
    const int nnzAll = Sn(0)+Sn(1)+Sn(2)+Sn(3)+Sn(4)+Sn(5)+Sn(6);
    const size_t payT1 = align256((size_t)nnzAll * sizeof(uint2));
    const size_t cntT1 = align256((size_t)(NBall + 8) * sizeof(int));
    const size_t rowT1 = align256((size_t)NGall * 1024 * sizeof(int));
    const size_t permT1 = align256((size_t)NGall * 1024);
    const size_t denseT1 = ((size_t)2*N0 + 3*N1 + 2*N2) * 64 * sizeof(unsigned short);
    const size_t regionT1 = denseT1 > payT1 ? denseT1 : payT1;  // dense ∪ payA
    const size_t needT1 = payT1 + 4 * cntT1 + rowT1 + permT1 + regionT1;
    const long long denseRows = (long long)2*N0 + 3LL*N1 + 2LL*N2;

    if (ws_avail >= needT1 && NBall <= MAXNB && denseRows < (1LL << 21)) {
        uint2* payB  = (uint2*)ws;
        int* goff    = (int*)(ws + payT1);
        int* gcur    = (int*)(ws + payT1 + 1 * cntT1);
        int* bend    = (int*)(ws + payT1 + 2 * cntT1);
        int* gcount  = (int*)(ws + payT1 + 3 * cntT1);
        int* rowoff  = (int*)(ws + payT1 + 4 * cntT1);
        unsigned char* rowperm = (unsigned char*)(ws + payT1 + 4 * cntT1 + rowT1);
        char* region = ws + payT1 + 4 * cntT1 + rowT1 + permT1;
        uint2* payA  = (uint2*)region;                // dead after sort_grpC
        unsigned short* db = (unsigned short*)region; // gemms write after sort
        unsigned short* dn2n = db;
        unsigned short* de2n = dn2n + (size_t)N0 * 64;
        unsigned short* dn2e = de2n + (size_t)N1 * 64;
        unsigned short* de2e = dn2e + (size_t)N0 * 64;
        unsigned short* dt2e = de2e + (size_t)N1 * 64;
        unsigned short* de2t = dt2e + (size_t)N2 * 64;
        unsigned short* dt2t = de2t + (size_t)N1 * 64;

        Bin7 B;
        // did: 0 n2n(L0) 1 e2n(D1invB1) 2 n2e(D2B1TD1inv) 3 e2e(L1) 4 t2e(B2D3) 5 e2t(B2TD2inv) 6 t2t(L2)
        B.r0 = Sr(0); B.c0 = Sc(0); B.v0 = Sv(0);
        B.r1 = Sr(3); B.c1 = Sc(3); B.v1 = Sv(3);
        B.r2 = Sr(4); B.c2 = Sc(4); B.v2 = Sv(4);
        B.r3 = Sr(1); B.c3 = Sc(1); B.v3 = Sv(1);
        B.r4 = Sr(6); B.c4 = Sc(6); B.v4 = Sv(6);
        B.r5 = Sr(5); B.c5 = Sc(5); B.v5 = Sv(5);
        B.r6 = Sr(2); B.c6 = Sc(2); B.v6 = Sv(2);
        B.p1 = Sn(0);
        B.p2 = B.p1 + Sn(3);
        B.p3 = B.p2 + Sn(4);
        B.p4 = B.p3 + Sn(1);
        B.p5 = B.p4 + Sn(6);
        B.p6 = B.p5 + Sn(5);
        B.p7 = B.p6 + Sn(2);
        B.t0 = 0;   B.t1 = 0;
        B.t2 = NB0; B.t3 = NB0; B.t4 = NB0;
        B.t5 = NB0 + NB1; B.t6 = NB0 + NB1;

        CBase cb;   // row base of each did's dense table in the combined table
        cb.b[0] = 0;
        cb.b[1] = N0;
        cb.b[2] = N0 + N1;
        cb.b[3] = 2*N0 + N1;
        cb.b[4] = 2*N0 + 2*N1;
        cb.b[5] = 2*N0 + 2*N1 + N2;
        cb.b[6] = 2*N0 + 3*N1 + N2;
        cb.b[7] = 0;

        const int chunk = (B.p7 + GRID_BIN - 1) / GRID_BIN;
        hipMemsetAsync(gcount, 0, (size_t)NGall * sizeof(int), stream);
        bhist_grp<<<GRID_BIN, 1024, 0, stream>>>(B, gcount, NGall, chunk);
        scan_small<<<1, 1024, 0, stream>>>(gcount, goff, gcur, NGall);
        scatter_grpC<<<GRID_BIN, 1024, 0, stream>>>(B, cb, gcur, payA, NGall, chunk);
        sort_grpC<<<NGall, 1024, 0, stream>>>(payA, goff, gcur, rowoff, bend,
                                              payB, rowperm, NBall);

        gemm_powcat_mfma<<<(N0 + 63) / 64, 256, 0, stream>>>(
            X0, N0, 2,
            wf(0), bp(0), dn2n,
            wf(1), bp(1), dn2e,
            wf(0), bp(0), dn2n);
        gemm_powcat_mfma<<<(N1 + 63) / 64, 256, 0, stream>>>(
            X1, N1, 3,
            wf(3), bp(3), de2n,
            wf(2), bp(2), de2e,
            wf(4), bp(4), de2t);
        gemm_powcat_mfma<<<(N2 + 63) / 64, 256, 0, stream>>>(
            X2, N2, 2,
            wf(5), bp(5), dt2e,
            wf(6), bp(6), dt2t,
            wf(5), bp(5), dt2e);

        const int grid = NBall < SPMM_GRID ? NBall : SPMM_GRID;
        spmm_stream_allC<<<grid, 256, 0, stream>>>(payB, rowoff, bend, rowperm,
            db, out, NB0, NB0 + NB1, NBall, N0, N1, N2);
        return;
    }

    // -------- tier 2: two-group phased layout (old did-encoded scheme) ----
    const int NBtotA = NB0 + NB2;
    const int NBmax = NBtotA > NB1 ? NBtotA : NB1;
    const int NGmax = (NBmax + 7) / 8;
    const int nnzA = Sn(0) + Sn(3) + Sn(5) + Sn(2);
    const int nnzB = Sn(4) + Sn(6) + Sn(1);
    const int nnzMax = nnzA > nnzB ? nnzA : nnzB;

    const size_t payBsz = align256((size_t)nnzMax * sizeof(uint2));
    const size_t cntB = align256((size_t)(NBmax + 8) * sizeof(int));
    const size_t rowB = align256((size_t)NGmax * 1024 * sizeof(int));
    const size_t permB = align256((size_t)NGmax * 1024);
    const size_t denseOff = payBsz + 4 * cntB + rowB + permB;

    uint2* bpayB = (uint2*)ws;
    int* goff    = (int*)(ws + payBsz);
    int* gcur    = (int*)(ws + payBsz + 1 * cntB);
    int* bend    = (int*)(ws + payBsz + 2 * cntB);
    int* gcount  = (int*)(ws + payBsz + 3 * cntB);
    int* rowoff  = (int*)(ws + payBsz + 4 * cntB);
    unsigned char* rowperm = (unsigned char*)(ws + payBsz + 4 * cntB + rowB);
    unsigned short* dense = (unsigned short*)(ws + denseOff);
    uint2* payA  = (uint2*)dense;   // transient, dead before gemms write dense

    const size_t need_full = denseOff +
        ((size_t)N0 + N2 + N1) * 64 * sizeof(unsigned short);
    const bool fullB = (ws_avail >= need_full);

    // ---- group A: did 0=n2n(Y0) 1=e2n(Y0) 2=e2t(Y2) 3=t2t(Y2)
    {
        Bin7 B;
        B.r0 = Sr(0); B.c0 = Sc(0); B.v0 = Sv(0);
        B.r1 = Sr(3); B.c1 = Sc(3); B.v1 = Sv(3);
        B.r2 = Sr(5); B.c2 = Sc(5); B.v2 = Sv(5);
        B.r3 = Sr(2); B.c3 = Sc(2); B.v3 = Sv(2);
        B.r4 = B.r3; B.c4 = B.c3; B.v4 = B.v3;
        B.r5 = B.r3; B.c5 = B.c3; B.v5 = B.v3;
        B.r6 = B.r3; B.c6 = B.c3; B.v6 = B.v3;
        B.p1 = Sn(0);
        B.p2 = B.p1 + Sn(3);
        B.p3 = B.p2 + Sn(5);
        B.p4 = B.p3 + Sn(2);
        B.p5 = B.p4; B.p6 = B.p4; B.p7 = B.p4;
        B.t0 = 0; B.t1 = 0; B.t2 = NB0; B.t3 = NB0;
        B.t4 = NB0; B.t5 = NB0; B.t6 = NB0;

        const int NGA = (NBtotA + 7) / 8;
        const int chunk = (B.p7 + GRID_BIN - 1) / GRID_BIN;
        hipMemsetAsync(gcount, 0, (size_t)NGA * sizeof(int), stream);
        bhist_grp<<<GRID_BIN, 1024, 0, stream>>>(B, gcount, NGA, chunk);
        scan_small<<<1, 1024, 0, stream>>>(gcount, goff, gcur, NGA);
        scatter_grp<<<GRID_BIN, 1024, 0, stream>>>(B, gcur, payA, NGA, chunk);
        sort_grp<<<NGA, 1024, 0, stream>>>(payA, goff, gcur, rowoff, bend,
                                           bpayB, rowperm, NBtotA);

        unsigned short* dn2n = dense;
        unsigned short* de2n = dense + (size_t)N0 * 64;
        gemm_powcat_mfma<<<(N0 + 63) / 64, 256, 0, stream>>>(
            X0, N0, 1, wf(0), bp(0), dn2n,
            wf(0), bp(0), dn2n, wf(0), bp(0), dn2n);
        gemm_powcat_mfma<<<(N1 + 63) / 64, 256, 0, stream>>>(
            X1, N1, 1, wf(3), bp(3), de2n,
            wf(3), bp(3), de2n, wf(3), bp(3), de2n);
        spmm_stream7<<<NB0, 256, 0, stream>>>(bpayB, rowoff, bend, rowperm,
            dn2n, de2n, dn2n, dn2n, dn2n, dn2n, dn2n,
            out, 0, N0, 1, 1, 0.5f, 0x7F);

        unsigned short* de2t = dense;
        unsigned short* dt2t = dense + (size_t)N1 * 64;
        gemm_powcat_mfma<<<(N1 + 63) / 64, 256, 0, stream>>>(
            X1, N1, 1, wf(4), bp(4), de2t,
            wf(4), bp(4), de2t, wf(4), bp(4), de2t);
        gemm_powcat_mfma<<<(N2 + 63) / 64, 256, 0, stream>>>(
            X2, N2, 1, wf(6), bp(6), dt2t,
            wf(6), bp(6), dt2t, wf(6), bp(6), dt2t);
        spmm_stream7<<<NB2, 256, 0, stream>>>(bpayB, rowoff, bend, rowperm,
            de2t, de2t, de2t, dt2t, de2t, de2t, de2t,
            out + offY2, NB0, N2, 1, 1, 0.5f, 0x7F);
    }

    // ---- group B (Y1): did 0=n2e 1=t2e 2=e2e
    {
        Bin7 B;
        B.r0 = Sr(4); B.c0 = Sc(4); B.v0 = Sv(4);
        B.r1 = Sr(6); B.c1 = Sc(6); B.v1 = Sv(6);
        B.r2 = Sr(1); B.c2 = Sc(1); B.v2 = Sv(1);
        B.r3 = B.r2; B.c3 = B.c2; B.v3 = B.v2;
        B.r4 = B.r2; B.c4 = B.c2; B.v4 = B.v2;
        B.r5 = B.r2; B.c5 = B.c2; B.v5 = B.v2;
        B.r6 = B.r2; B.c6 = B.c2; B.v6 = B.v2;
        B.p1 = Sn(4);
        B.p2 = B.p1 + Sn(6);
        B.p3 = B.p2 + Sn(1);
        B.p4 = B.p3; B.p5 = B.p3; B.p6 = B.p3; B.p7 = B.p3;
        B.t0 = 0; B.t1 = 0; B.t2 = 0; B.t3 = 0; B.t4 = 0; B.t5 = 0; B.t6 = 0;

        const int NGB = (NB1 + 7) / 8;
        const int chunk = (B.p7 + GRID_BIN - 1) / GRID_BIN;
        hipMemsetAsync(gcount, 0, (size_t)NGB * sizeof(int), stream);
        bhist_grp<<<GRID_BIN, 1024, 0, stream>>>(B, gcount, NGB, chunk);
        scan_small<<<1, 1024, 0, stream>>>(gcount, goff, gcur, NGB);
        scatter_grp<<<GRID_BIN, 1024, 0, stream>>>(B, gcur, payA, NGB, chunk);
        sort_grp<<<NGB, 1024, 0, stream>>>(payA, goff, gcur, rowoff, bend,
                                           bpayB, rowperm, NB1);

        if (fullB) {
            unsigned short* dn2e = dense;
            unsigned short* dt2e = dense + (size_t)N0 * 64;
            unsigned short* de2e = dense + ((size_t)N0 + N2) * 64;
            gemm_powcat_mfma<<<(N0 + 63) / 64, 256, 0, stream>>>(
                X0, N0, 1, wf(1), bp(1), dn2e,
                wf(1), bp(1), dn2e, wf(1), bp(1), dn2e);
            gemm_powcat_mfma<<<(N2 + 63) / 64, 256, 0, stream>>>(
                X2, N2, 1, wf(5), bp(5), dt2e,
                wf(5), bp(5), dt2e, wf(5), bp(5), dt2e);
            gemm_powcat_mfma<<<(N1 + 63) / 64, 256, 0, stream>>>(
                X1, N1, 1, wf(2), bp(2), de2e,
                wf(2), bp(2), de2e, wf(2), bp(2), de2e);
            spmm_stream7<<<NB1, 256, 0, stream>>>(bpayB, rowoff, bend, rowperm,
                dn2e, dt2e, de2e, dn2e, dn2e, dn2e, dn2e,
                out + offY1, 0, N1, 1, 1, TH, 0x7F);
        } else {
            unsigned short* dn2e = dense;
            unsigned short* dt2e = dense + (size_t)N0 * 64;
            gemm_powcat_mfma<<<(N0 + 63) / 64, 256, 0, stream>>>(
                X0, N0, 1, wf(1), bp(1), dn2e,
                wf(1), bp(1), dn2e, wf(1), bp(1), dn2e);
            gemm_powcat_mfma<<<(N2 + 63) / 64, 256, 0, stream>>>(
                X2, N2, 1, wf(5), bp(5), dt2e,
                wf(5), bp(5), dt2e, wf(5), bp(5), dt2e);
            spmm_stream7<<<NB1, 256, 0, stream>>>(bpayB, rowoff, bend, rowperm,
                dn2e, dt2e, dn2e, dn2e, dn2e, dn2e, dn2e,
                out + offY1, 0, N1, 1, 0, 0.f, 0x3);
            unsigned short* de2e = dense;
            gemm_powcat_mfma<<<(N1 + 63) / 64, 256, 0, stream>>>(
                X1, N1, 1, wf(2), bp(2), de2e,
                wf(2), bp(2), de2e, wf(2), bp(2), de2e);
            spmm_stream7<<<NB1, 256, 0, stream>>>(bpayB, rowoff, bend, rowperm,
                de2e, de2e, de2e, de2e, de2e, de2e, de2e,
                out + offY1, 0, N1, 0, 1, TH, 0x4);
        }
    }
}

// Round 12
// 490.493 us; speedup vs baseline: 1.1342x; 1.0272x over previous
//
#include <hip/hip_runtime.h>
#include <hip/hip_bf16.h>

// SCConv: two-level radix binning (pass A: 8-bucket groups, per-block
// histograms saved by bhist so scatter reserves runs without re-counting;
// pass B: per-group 1024-bin LDS-staged counting sort to (bucket,row) order
// with coalesced flush, emitting rowoff/bend + a per-bucket row permutation
// sorted by row length), 3 fused powcat-GEMMs on MFMA (split-bf16 3-term),
// then ONE merged streaming spmm over all output segments (8-lanes-per-row
// dwordx4 gathers, depth-2 pipelined, single combined dense table).

#define RPB 128
#define COL_MASK 0x7FFFFu
#define LROW_SH 19
#define DID_SH 26
#define CCOL_MASK 0x1FFFFFu   // combined column: 21 bits
#define CLROW_SH 21
#define CBKT_SH 28
#define MAXNB 4352
#define MAXNG 544
#define GRID_BIN 256
#define SPMM_GRID 2048

// sort phasing: destination positions are processed in windows of SORT_PH;
// LDS capacity covers PH + max single-bin size.
#define SORT_PH     16384
#define SORT_LOG    14
#define SORT_MAXBIN 2048
#define SORT_CAP    (SORT_PH + SORT_MAXBIN)   // 18432 entries = 144 KB
#define MAXPH 8

typedef __attribute__((ext_vector_type(8))) short short8;
typedef __attribute__((ext_vector_type(4))) float f32x4;

__device__ __forceinline__ int   ntld_i(const int* p)   { return __builtin_nontemporal_load(p); }
__device__ __forceinline__ float ntld_f(const float* p) { return __builtin_nontemporal_load(p); }
__device__ __forceinline__ float4 ntld_f4(const float* p) {
    const unsigned long long* q = (const unsigned long long*)p;
    unsigned long long a = __builtin_nontemporal_load(q);
    unsigned long long b = __builtin_nontemporal_load(q + 1);
    float4 v;
    v.x = __uint_as_float((unsigned)a);
    v.y = __uint_as_float((unsigned)(a >> 32));
    v.z = __uint_as_float((unsigned)b);
    v.w = __uint_as_float((unsigned)(b >> 32));
    return v;
}
__device__ __forceinline__ void ntst_f4(float* p, float4 v) {
    unsigned long long a = (unsigned long long)__float_as_uint(v.x)
                         | ((unsigned long long)__float_as_uint(v.y) << 32);
    unsigned long long b = (unsigned long long)__float_as_uint(v.z)
                         | ((unsigned long long)__float_as_uint(v.w) << 32);
    unsigned long long* q = (unsigned long long*)p;
    __builtin_nontemporal_store(a, q);
    __builtin_nontemporal_store(b, q + 1);
}

// ---------------- bf16 helpers (RNE) --------------------------------------
__device__ __forceinline__ unsigned short f2bf(float f) {
    unsigned u = __float_as_uint(f);
    unsigned r = u + 0x7FFFu + ((u >> 16) & 1u);
    return (unsigned short)(r >> 16);
}

__device__ __forceinline__ void split8(float4 a0, float4 a1, short8& hi, short8& lo) {
    float v[8] = {a0.x, a0.y, a0.z, a0.w, a1.x, a1.y, a1.z, a1.w};
    #pragma unroll
    for (int e = 0; e < 8; ++e) {
        unsigned short h = f2bf(v[e]);
        float hf = __uint_as_float((unsigned)h << 16);
        hi[e] = (short)h;
        lo[e] = (short)f2bf(v[e] - hf);
    }
}

// ---------------- W -> MFMA B-fragment precompute (once per launch) -------
struct WAll { const float* w[7]; };

__global__ __launch_bounds__(256) void winit(WAll wa, unsigned short* __restrict__ frags)
{
    const int s = blockIdx.x;
    const float* __restrict__ W = wa.w[s];
    unsigned short* __restrict__ out = frags + (size_t)s * 16384;
    for (int slot = threadIdx.x; slot < 1024; slot += 256) {
        const int l  = slot & 63;
        const int nf = (slot >> 6) & 3;
        const int kk = slot >> 8;
        const int col = nf * 16 + (l & 15);
        const int kb  = kk * 32 + 8 * (l >> 4);
        short8 vh, vl;
        #pragma unroll
        for (int e = 0; e < 8; ++e) {
            float w = W[(size_t)(kb + e) * 64 + col];
            unsigned short h = f2bf(w);
            float hf = __uint_as_float((unsigned)h << 16);
            vh[e] = (short)h;
            vl[e] = (short)f2bf(w - hf);
        }
        *(short8*)(out + ((size_t)((kk * 4 + nf) * 2 + 0) * 64 + l) * 8) = vh;
        *(short8*)(out + ((size_t)((kk * 4 + nf) * 2 + 1) * 64 + l) * 8) = vl;
    }
}

// ---------------- MFMA powcat-GEMM (up to 3 weight sets per X) ------------
__device__ __forceinline__ void mfma_set(
    const short8 Ah[4], const short8 Al[4],
    const unsigned short* __restrict__ F, const float* __restrict__ bias,
    unsigned short* __restrict__ D, int nrows, int row0w, int l)
{
    const int lg = l >> 4, lr = l & 15;
    const short8* __restrict__ Fv = (const short8*)F;
    f32x4 acc[4];
    #pragma unroll
    for (int nf = 0; nf < 4; ++nf) {
        float b = bias[nf * 16 + lr];
        f32x4 bi = {b, b, b, b};
        acc[nf] = bi;
    }
    #pragma unroll
    for (int kk = 0; kk < 4; ++kk) {
        #pragma unroll
        for (int nf = 0; nf < 4; ++nf) {
            short8 bh = Fv[((kk * 4 + nf) * 2 + 0) * 64 + l];
            short8 bl = Fv[((kk * 4 + nf) * 2 + 1) * 64 + l];
            acc[nf] = __builtin_amdgcn_mfma_f32_16x16x32_bf16(Ah[kk], bh, acc[nf], 0, 0, 0);
            acc[nf] = __builtin_amdgcn_mfma_f32_16x16x32_bf16(Al[kk], bh, acc[nf], 0, 0, 0);
            acc[nf] = __builtin_amdgcn_mfma_f32_16x16x32_bf16(Ah[kk], bl, acc[nf], 0, 0, 0);
        }
    }
    #pragma unroll
    for (int nf = 0; nf < 4; ++nf) {
        #pragma unroll
        for (int j = 0; j < 4; ++j) {
            int row = row0w + lg * 4 + j;   // C/D: col=lane&15, row=4*(lane>>4)+reg
            if (row < nrows)
                D[(size_t)row * 64 + nf * 16 + lr] = f2bf(acc[nf][j]);
        }
    }
}

__global__ __launch_bounds__(256) void gemm_powcat_mfma(
    const float* __restrict__ X, int nrows, int nsets,
    const unsigned short* __restrict__ F0, const float* __restrict__ b0, unsigned short* __restrict__ D0,
    const unsigned short* __restrict__ F1, const float* __restrict__ b1, unsigned short* __restrict__ D1,
    const unsigned short* __restrict__ F2, const float* __restrict__ b2, unsigned short* __restrict__ D2)
{
    __shared__ float Xs[64][68];   // pad stride 68 -> balanced LDS banks
    const int tid = threadIdx.x;
    const int row0 = blockIdx.x * 64;

    #pragma unroll
    for (int it = 0; it < 4; ++it) {
        int idx = tid + it * 256;
        int r = idx >> 4, c4 = idx & 15;
        float4 v = make_float4(0.f, 0.f, 0.f, 0.f);
        if (row0 + r < nrows)
            v = ntld_f4(X + (size_t)(row0 + r) * 64 + c4 * 4);
        *(float4*)&Xs[r][c4 * 4] = v;
    }
    __syncthreads();

    const int w = tid >> 6, l = tid & 63;
    const int lg = l >> 4, lr = l & 15;

    // A-frags (shared across all weight sets): powcat K=128 = [X | X^2]
    short8 Ah[4], Al[4];
    #pragma unroll
    for (int kk = 0; kk < 4; ++kk) {
        const float* p = &Xs[w * 16 + lr][(kk & 1) * 32 + 8 * lg];
        float4 a0 = *(const float4*)p;
        float4 a1 = *(const float4*)(p + 4);
        if (kk >= 2) {
            a0.x *= a0.x; a0.y *= a0.y; a0.z *= a0.z; a0.w *= a0.w;
            a1.x *= a1.x; a1.y *= a1.y; a1.z *= a1.z; a1.w *= a1.w;
        }
        split8(a0, a1, Ah[kk], Al[kk]);
    }

    const int row0w = row0 + w * 16;
    mfma_set(Ah, Al, F0, b0, D0, nrows, row0w, l);
    if (nsets > 1) mfma_set(Ah, Al, F1, b1, D1, nrows, row0w, l);
    if (nsets > 2) mfma_set(Ah, Al, F2, b2, D2, nrows, row0w, l);
}

// ---------------- 7-slot flat COO view ------------------------------------
struct Bin7 {
    const int *r0, *r1, *r2, *r3, *r4, *r5, *r6;
    const int *c0, *c1, *c2, *c3, *c4, *c5, *c6;
    const float *v0, *v1, *v2, *v3, *v4, *v5, *v6;
    int p1, p2, p3, p4, p5, p6, p7;   // cumulative prefix ends
    int t0, t1, t2, t3, t4, t5, t6;   // bucket-tile base per slot
};

struct CBase { int b[8]; };           // per-did combined-column row base

struct Ent { int r; int tb; unsigned cw; float v; };

template<bool FULL>
__device__ __forceinline__ Ent decode(const Bin7& B, int i) {
    Ent e;
    if (i < B.p1) {
        int li = i;
        e.r = ntld_i(B.r0 + li); e.tb = B.t0;
        if (FULL) { e.cw = (unsigned)ntld_i(B.c0 + li) | (0u << DID_SH); e.v = ntld_f(B.v0 + li); }
    } else if (i < B.p2) {
        int li = i - B.p1;
        e.r = ntld_i(B.r1 + li); e.tb = B.t1;
        if (FULL) { e.cw = (unsigned)ntld_i(B.c1 + li) | (1u << DID_SH); e.v = ntld_f(B.v1 + li); }
    } else if (i < B.p3) {
        int li = i - B.p2;
        e.r = ntld_i(B.r2 + li); e.tb = B.t2;
        if (FULL) { e.cw = (unsigned)ntld_i(B.c2 + li) | (2u << DID_SH); e.v = ntld_f(B.v2 + li); }
    } else if (i < B.p4) {
        int li = i - B.p3;
        e.r = ntld_i(B.r3 + li); e.tb = B.t3;
        if (FULL) { e.cw = (unsigned)ntld_i(B.c3 + li) | (3u << DID_SH); e.v = ntld_f(B.v3 + li); }
    } else if (i < B.p5) {
        int li = i - B.p4;
        e.r = ntld_i(B.r4 + li); e.tb = B.t4;
        if (FULL) { e.cw = (unsigned)ntld_i(B.c4 + li) | (4u << DID_SH); e.v = ntld_f(B.v4 + li); }
    } else if (i < B.p6) {
        int li = i - B.p5;
        e.r = ntld_i(B.r5 + li); e.tb = B.t5;
        if (FULL) { e.cw = (unsigned)ntld_i(B.c5 + li) | (5u << DID_SH); e.v = ntld_f(B.v5 + li); }
    } else {
        int li = i - B.p6;
        e.r = ntld_i(B.r6 + li); e.tb = B.t6;
        if (FULL) { e.cw = (unsigned)ntld_i(B.c6 + li) | (6u << DID_SH); e.v = ntld_f(B.v6 + li); }
    }
    return e;
}

// ---------------- group histogram (8 buckets per group) -------------------
// Also stores the per-block histogram to ghist[block*NG + g] so the scatter
// pass can reserve runs without re-decoding the COO.
__global__ __launch_bounds__(1024) void bhist_grp(
    Bin7 B, int* __restrict__ gcount, int* __restrict__ ghist,
    int NG, int chunk)
{
    __shared__ int h[MAXNG];
    for (int i = threadIdx.x; i < NG; i += 1024) h[i] = 0;
    __syncthreads();
    const int s = blockIdx.x * chunk;
    int e = s + chunk;  if (e > B.p7) e = B.p7;
    for (int i = s + threadIdx.x; i < e; i += 1024) {
        Ent en = decode<false>(B, i);
        atomicAdd(&h[(en.tb + (en.r >> 7)) >> 3], 1);
    }
    __syncthreads();
    for (int i = threadIdx.x; i < NG; i += 1024) {
        int c = h[i];
        ghist[(size_t)blockIdx.x * NG + i] = c;
        if (c) atomicAdd(&gcount[i], c);
    }
}

// ---------------- pass A (tier 1): scatter with combined column -----------
// payA word: colC(21) | lrow(7)<<21 | (bucket&7)<<28. Single COO pass:
// per-(block,group) counts come from ghist (written by bhist_grp).
__global__ __launch_bounds__(1024) void scatter_grpC(
    Bin7 B, CBase cb, int* __restrict__ gcur, const int* __restrict__ ghist,
    uint2* __restrict__ payA, int NG, int chunk)
{
    __shared__ int lbase[MAXNG];
    __shared__ int lcur[MAXNG];
    __shared__ int cbs[8];
    if (threadIdx.x < 8) cbs[threadIdx.x] = cb.b[threadIdx.x];
    for (int i = threadIdx.x; i < NG; i += 1024) {
        int c = ghist[(size_t)blockIdx.x * NG + i];
        lbase[i] = c ? atomicAdd(&gcur[i], c) : 0;
        lcur[i] = 0;
    }
    __syncthreads();
    const int s = blockIdx.x * chunk;
    int e = s + chunk;  if (e > B.p7) e = B.p7;
    for (int i = s + threadIdx.x; i < e; i += 1024) {
        Ent en = decode<true>(B, i);
        int b = en.tb + (en.r >> 7);
        int g = b >> 3;
        int pos = lbase[g] + atomicAdd(&lcur[g], 1);
        int did = (int)(en.cw >> DID_SH);
        unsigned colC = (en.cw & COL_MASK) + (unsigned)cbs[did];
        unsigned cwA = colC | ((unsigned)(en.r & 127) << CLROW_SH)
                     | ((unsigned)(b & 7) << CBKT_SH);
        payA[pos] = make_uint2(cwA, __float_as_uint(en.v));
    }
}

// ---------------- pass B (tier 1): 1024-bin LDS-staged counting sort ------
// Sort key = bits 21..30 (lrow | (bucket&7)<<7). payB.x = pure colC.
// Emits rowoff, bend, and rowperm (rows ranked by descending length).
__global__ __launch_bounds__(1024) void sort_grpC(
    const uint2* __restrict__ payA, const int* __restrict__ goff,
    const int* __restrict__ gcur, int* __restrict__ rowoff,
    int* __restrict__ bend, uint2* __restrict__ payB,
    unsigned char* __restrict__ rowperm, int NBtot)
{
    __shared__ uint2 lpay[SORT_CAP];      // 144 KB
    __shared__ int cnt[1024];             // hist, then cur
    __shared__ int off[1024];             // exclusive scan (immutable)
    __shared__ unsigned char cnts8[1024]; // clamped counts for ranking
    __shared__ int wsum[16];
    __shared__ int phstart[MAXPH + 1];
    __shared__ int s_nph, s_maxbin;

    const int g = blockIdx.x;
    const int tid = threadIdx.x;
    const int seg0 = goff[g], seg1 = gcur[g];
    const int n = seg1 - seg0;

    cnt[tid] = 0;
    if (tid == 0) s_maxbin = 0;
    __syncthreads();
    for (int i = seg0 + tid; i < seg1; i += 1024) {
        unsigned w = __builtin_nontemporal_load(&payA[i].x);
        atomicAdd(&cnt[(w >> CLROW_SH) & 1023], 1);
    }
    __syncthreads();

    const int lane = tid & 63, wv = tid >> 6;
    const int tot = cnt[tid];
    atomicMax(&s_maxbin, tot);
    cnts8[tid] = (unsigned char)(tot > 255 ? 255 : tot);
    int x = tot;
    #pragma unroll
    for (int o = 1; o < 64; o <<= 1) {
        int y = __shfl_up(x, o);
        if (lane >= o) x += y;
    }
    if (lane == 63) wsum[wv] = x;
    __syncthreads();
    if (tid < 16) {
        int ss = wsum[tid];
        #pragma unroll
        for (int o = 1; o < 16; o <<= 1) {
            int y = __shfl_up(ss, o, 16);
            if (tid >= o) ss += y;
        }
        wsum[tid] = ss;
    }
    __syncthreads();
    const int excl = (x - tot) + ((wv == 0) ? 0 : wsum[wv - 1]);
    off[tid] = excl;
    rowoff[(size_t)g * 1024 + tid] = seg0 + excl;
    {
        int b = g * 8 + (tid >> 7);
        if (b < NBtot && (tid & 127) == 127) bend[b] = seg0 + excl + tot;
    }
    __syncthreads();   // off[] + cnts8[] complete
    cnt[tid] = excl;   // cnt becomes cur
    {
        int p = excl >> SORT_LOG;
        int pprev = (tid == 0) ? -1 : (off[tid - 1] >> SORT_LOG);
        for (int q = pprev + 1; q <= p && q <= MAXPH; ++q) phstart[q] = excl;
        if (tid == 1023) s_nph = p + 1;
    }

    // rank rows by descending length within each 128-row bucket (bijective)
    {
        const int myr = tid & 127, b0 = tid & ~127;
        const unsigned char myc = cnts8[tid];
        int rank = 0;
        #pragma unroll 8
        for (int r = 0; r < 128; ++r) {
            unsigned char c = cnts8[b0 + r];
            rank += (c > myc) || (c == myc && r < myr);
        }
        rowperm[(size_t)g * 1024 + b0 + rank] = (unsigned char)myr;
    }
    __syncthreads();

    const int nph = s_nph;
    if (n <= 0) return;

    if (s_maxbin <= SORT_MAXBIN && nph <= MAXPH) {
        for (int ph = 0; ph < nph; ++ph) {
            const int ps = phstart[ph];
            const int pe = (ph + 1 < nph) ? phstart[ph + 1] : n;
            for (int i = seg0 + tid; i < seg1; i += 1024) {
                unsigned long long pv = __builtin_nontemporal_load(
                    (const unsigned long long*)(payA + i));
                unsigned w = (unsigned)pv;
                int bin = (w >> CLROW_SH) & 1023;
                if ((off[bin] >> SORT_LOG) == ph) {
                    int pos = atomicAdd(&cnt[bin], 1);
                    lpay[pos - ps] = make_uint2(w, (unsigned)(pv >> 32));
                }
            }
            __syncthreads();
            for (int k = tid; k < pe - ps; k += 1024) {
                uint2 pv = lpay[k];
                unsigned long long o2 = (unsigned long long)(pv.x & CCOL_MASK)
                                      | ((unsigned long long)pv.y << 32);
                __builtin_nontemporal_store(o2,
                    (unsigned long long*)(payB + seg0 + ps + k));
            }
            __syncthreads();
        }
    } else {
        // fallback: direct global scatter (pathological bin sizes only)
        for (int i = seg0 + tid; i < seg1; i += 1024) {
            unsigned long long pv = __builtin_nontemporal_load(
                (const unsigned long long*)(payA + i));
            unsigned w = (unsigned)pv;
            int bin = (w >> CLROW_SH) & 1023;
            int pos = seg0 + atomicAdd(&cnt[bin], 1);
            payB[pos] = make_uint2(w & CCOL_MASK, (unsigned)(pv >> 32));
        }
    }
}

// ---------------- tier-2 kernels (old did-encoded scheme) -----------------
__global__ __launch_bounds__(1024) void scatter_grp(
    Bin7 B, int* __restrict__ gcur, const int* __restrict__ ghist,
    uint2* __restrict__ payA, int NG, int chunk)
{
    __shared__ int lbase[MAXNG];
    __shared__ int lcur[MAXNG];
    for (int i = threadIdx.x; i < NG; i += 1024) {
        int c = ghist[(size_t)blockIdx.x * NG + i];
        lbase[i] = c ? atomicAdd(&gcur[i], c) : 0;
        lcur[i] = 0;
    }
    __syncthreads();
    const int s = blockIdx.x * chunk;
    int e = s + chunk;  if (e > B.p7) e = B.p7;
    for (int i = s + threadIdx.x; i < e; i += 1024) {
        Ent en = decode<true>(B, i);
        int b = en.tb + (en.r >> 7);
        int g = b >> 3;
        int pos = lbase[g] + atomicAdd(&lcur[g], 1);
        unsigned col = en.cw & COL_MASK;
        unsigned did = en.cw >> DID_SH;
        unsigned cwA = col | ((unsigned)(en.r & 127) << LROW_SH)
                     | ((unsigned)(b & 7) << 26) | (did << 29);
        payA[pos] = make_uint2(cwA, __float_as_uint(en.v));
    }
}

__global__ __launch_bounds__(1024) void sort_grp(
    const uint2* __restrict__ payA, const int* __restrict__ goff,
    const int* __restrict__ gcur, int* __restrict__ rowoff,
    int* __restrict__ bend, uint2* __restrict__ payB,
    unsigned char* __restrict__ rowperm, int NBtot)
{
    __shared__ uint2 lpay[SORT_CAP];
    __shared__ int cnt[1024];
    __shared__ int off[1024];
    __shared__ unsigned char cnts8[1024];
    __shared__ int wsum[16];
    __shared__ int phstart[MAXPH + 1];
    __shared__ int s_nph, s_maxbin;

    const int g = blockIdx.x;
    const int tid = threadIdx.x;
    const int seg0 = goff[g], seg1 = gcur[g];
    const int n = seg1 - seg0;

    cnt[tid] = 0;
    if (tid == 0) s_maxbin = 0;
    __syncthreads();
    for (int i = seg0 + tid; i < seg1; i += 1024) {
        unsigned w = __builtin_nontemporal_load(&payA[i].x);
        atomicAdd(&cnt[(w >> 19) & 1023], 1);
    }
    __syncthreads();

    const int lane = tid & 63, wv = tid >> 6;
    const int tot = cnt[tid];
    atomicMax(&s_maxbin, tot);
    cnts8[tid] = (unsigned char)(tot > 255 ? 255 : tot);
    int x = tot;
    #pragma unroll
    for (int o = 1; o < 64; o <<= 1) {
        int y = __shfl_up(x, o);
        if (lane >= o) x += y;
    }
    if (lane == 63) wsum[wv] = x;
    __syncthreads();
    if (tid < 16) {
        int ss = wsum[tid];
        #pragma unroll
        for (int o = 1; o < 16; o <<= 1) {
            int y = __shfl_up(ss, o, 16);
            if (tid >= o) ss += y;
        }
        wsum[tid] = ss;
    }
    __syncthreads();
    const int excl = (x - tot) + ((wv == 0) ? 0 : wsum[wv - 1]);
    off[tid] = excl;
    rowoff[(size_t)g * 1024 + tid] = seg0 + excl;
    {
        int b = g * 8 + (tid >> 7);
        if (b < NBtot && (tid & 127) == 127) bend[b] = seg0 + excl + tot;
    }
    __syncthreads();
    cnt[tid] = excl;
    {
        int p = excl >> SORT_LOG;
        int pprev = (tid == 0) ? -1 : (off[tid - 1] >> SORT_LOG);
        for (int q = pprev + 1; q <= p && q <= MAXPH; ++q) phstart[q] = excl;
        if (tid == 1023) s_nph = p + 1;
    }

    {
        const int myr = tid & 127, b0 = tid & ~127;
        const unsigned char myc = cnts8[tid];
        int rank = 0;
        #pragma unroll 8
        for (int r = 0; r < 128; ++r) {
            unsigned char c = cnts8[b0 + r];
            rank += (c > myc) || (c == myc && r < myr);
        }
        rowperm[(size_t)g * 1024 + b0 + rank] = (unsigned char)myr;
    }
    __syncthreads();

    const int nph = s_nph;
    if (n <= 0) return;

    if (s_maxbin <= SORT_MAXBIN && nph <= MAXPH) {
        for (int ph = 0; ph < nph; ++ph) {
            const int ps = phstart[ph];
            const int pe = (ph + 1 < nph) ? phstart[ph + 1] : n;
            for (int i = seg0 + tid; i < seg1; i += 1024) {
                unsigned long long pv = __builtin_nontemporal_load(
                    (const unsigned long long*)(payA + i));
                unsigned w = (unsigned)pv;
                int bin = (w >> 19) & 1023;
                if ((off[bin] >> SORT_LOG) == ph) {
                    int pos = atomicAdd(&cnt[bin], 1);
                    lpay[pos - ps] = make_uint2(w, (unsigned)(pv >> 32));
                }
            }
            __syncthreads();
            for (int k = tid; k < pe - ps; k += 1024) {
                uint2 pv = lpay[k];
                unsigned cw = (pv.x & 0x03FFFFFFu) | ((pv.x >> 29) << 26);
                unsigned long long o2 = (unsigned long long)cw
                                      | ((unsigned long long)pv.y << 32);
                __builtin_nontemporal_store(o2,
                    (unsigned long long*)(payB + seg0 + ps + k));
            }
            __syncthreads();
        }
    } else {
        for (int i = seg0 + tid; i < seg1; i += 1024) {
            unsigned long long pv = __builtin_nontemporal_load(
                (const unsigned long long*)(payA + i));
            unsigned w = (unsigned)pv;
            int bin = (w >> 19) & 1023;
            int pos = seg0 + atomicAdd(&cnt[bin], 1);
            unsigned cw = (w & 0x03FFFFFFu) | ((w >> 29) << 26);
            payB[pos] = make_uint2(cw, (unsigned)(pv >> 32));
        }
    }
}

// ---------------- shfl-based single-block exclusive scan ------------------
__global__ __launch_bounds__(1024) void scan_small(
    const int* __restrict__ in, int* __restrict__ boff,
    int* __restrict__ bcur, int n)
{
    __shared__ int wsum[16];
    __shared__ int carry;
    const int tid = threadIdx.x, lane = tid & 63, wv = tid >> 6;
    if (tid == 0) carry = 0;
    __syncthreads();
    for (int base = 0; base < n; base += 4096) {
        int i = base + tid * 4;
        int v0 = (i + 0 < n) ? in[i + 0] : 0;
        int v1 = (i + 1 < n) ? in[i + 1] : 0;
        int v2 = (i + 2 < n) ? in[i + 2] : 0;
        int v3 = (i + 3 < n) ? in[i + 3] : 0;
        int tsum = v0 + v1 + v2 + v3;
        int x = tsum;
        #pragma unroll
        for (int off = 1; off < 64; off <<= 1) {
            int y = __shfl_up(x, off);
            if (lane >= off) x += y;
        }
        if (lane == 63) wsum[wv] = x;
        int c0 = carry;
        __syncthreads();
        if (tid < 16) {
            int ss = wsum[tid];
            #pragma unroll
            for (int off = 1; off < 16; off <<= 1) {
                int y = __shfl_up(ss, off, 16);
                if (tid >= off) ss += y;
            }
            wsum[tid] = ss;
        }
        __syncthreads();
        int wpre = (wv == 0) ? 0 : wsum[wv - 1];
        int excl = c0 + wpre + (x - tsum);
        if (i + 0 < n) { boff[i + 0] = excl; bcur[i + 0] = excl; } excl += v0;
        if (i + 1 < n) { boff[i + 1] = excl; bcur[i + 1] = excl; } excl += v1;
        if (i + 2 < n) { boff[i + 2] = excl; bcur[i + 2] = excl; } excl += v2;
        if (i + 3 < n) { boff[i + 3] = excl; bcur[i + 3] = excl; }
        __syncthreads();
        if (tid == 0) carry = c0 + wsum[15];
        __syncthreads();
    }
}

// ---------------- combined-table row accumulate: 8 lanes/row, dwordx4 -----
// Each lane covers 16 B (8 bf16 columns) of the dense row; a wave covers
// 8 rows. Depth-2 pipelined gathers; payload broadcast within 8-lane group.
__device__ __forceinline__ void facc8(float4& alo, float4& ahi, float v, uint4 d) {
    alo.x = fmaf(v, __uint_as_float((d.x & 0xFFFFu) << 16), alo.x);
    alo.y = fmaf(v, __uint_as_float(d.x & 0xFFFF0000u), alo.y);
    alo.z = fmaf(v, __uint_as_float((d.y & 0xFFFFu) << 16), alo.z);
    alo.w = fmaf(v, __uint_as_float(d.y & 0xFFFF0000u), alo.w);
    ahi.x = fmaf(v, __uint_as_float((d.z & 0xFFFFu) << 16), ahi.x);
    ahi.y = fmaf(v, __uint_as_float(d.z & 0xFFFF0000u), ahi.y);
    ahi.z = fmaf(v, __uint_as_float((d.w & 0xFFFFu) << 16), ahi.z);
    ahi.w = fmaf(v, __uint_as_float(d.w & 0xFFFF0000u), ahi.w);
}

__device__ __forceinline__ void row_accumC8(
    const uint2* __restrict__ payB, int js, int je,
    const uint4* __restrict__ Dg, int l8, float4& alo, float4& ahi)
{
    alo = make_float4(0.f, 0.f, 0.f, 0.f);
    ahi = make_float4(0.f, 0.f, 0.f, 0.f);
    const int n = je - js;
    if (n <= 0) return;
    const uint2* base = payB + js;
    uint2 p0 = base[0];
    uint2 p1 = base[(n > 1) ? 1 : 0];
    float v0 = __uint_as_float(p0.y);
    float v1 = (n > 1) ? __uint_as_float(p1.y) : 0.f;
    uint4 d0 = Dg[(size_t)p0.x * 8 + l8];
    uint4 d1 = Dg[(size_t)p1.x * 8 + l8];
    int i = 0;
    while (true) {
        int i2 = (i + 2 < n) ? i + 2 : n - 1;
        int i3 = (i + 3 < n) ? i + 3 : n - 1;
        uint2 q0 = base[i2];
        uint2 q1 = base[i3];
        float w0 = (i + 2 < n) ? __uint_as_float(q0.y) : 0.f;
        float w1 = (i + 3 < n) ? __uint_as_float(q1.y) : 0.f;
        uint4 e0 = Dg[(size_t)q0.x * 8 + l8];   // issued before d0/d1 waited on
        uint4 e1 = Dg[(size_t)q1.x * 8 + l8];   // -> 2 gathers in flight
        facc8(alo, ahi, v0, d0);
        facc8(alo, ahi, v1, d1);
        i += 2;
        if (i >= n) break;
        v0 = w0; v1 = w1; d0 = e0; d1 = e1;
    }
}

// ---------------- merged streaming SpMM (tier 1, combined table) ----------
__global__ __launch_bounds__(256) void spmm_stream_allC(
    const uint2* __restrict__ payB, const int* __restrict__ rowoff,
    const int* __restrict__ bend, const unsigned char* __restrict__ rowperm,
    const unsigned short* __restrict__ dense,
    float* __restrict__ out, int NB0, int NB01, int NBall,
    int N0, int N1, int N2)
{
    const uint4* __restrict__ Dg = reinterpret_cast<const uint4*>(dense);
    const int tid = threadIdx.x;
    const int slot = tid >> 3;   // 0..31: row slot (8 per wave, ranks adjacent)
    const int l8 = tid & 7;      // 16-B chunk within the 128-B dense row

    for (int t = blockIdx.x; t < NBall; t += gridDim.x) {
        int tb, nrows; float scale; float* oseg;
        if (t < NB0)       { tb = 0;    nrows = N0; oseg = out;                          scale = 0.5f; }
        else if (t < NB01) { tb = NB0;  nrows = N1; oseg = out + (size_t)N0 * 64;        scale = 1.0f / 3.0f; }
        else               { tb = NB01; nrows = N2; oseg = out + (size_t)(N0 + N1) * 64; scale = 0.5f; }
        const int row0 = (t - tb) * RPB;
        const int rbase = t * RPB;
        const int bendt = bend[t];
        const unsigned char* perm = rowperm + (size_t)t * RPB;

        #pragma unroll 1
        for (int rr = 0; rr < 4; ++rr) {
            const int lr = perm[rr * 32 + slot];   // length-balanced wave rows
            const int row = row0 + lr;
            const int js = rowoff[rbase + lr];
            const int je = (lr == 127) ? bendt : rowoff[rbase + lr + 1];
            float4 alo, ahi;
            row_accumC8(payB, js, je, Dg, l8, alo, ahi);
            if (row < nrows) {
                float* o = oseg + (size_t)row * 64 + l8 * 8;
                alo.x = fmaxf(alo.x, 0.f) * scale;
                alo.y = fmaxf(alo.y, 0.f) * scale;
                alo.z = fmaxf(alo.z, 0.f) * scale;
                alo.w = fmaxf(alo.w, 0.f) * scale;
                ahi.x = fmaxf(ahi.x, 0.f) * scale;
                ahi.y = fmaxf(ahi.y, 0.f) * scale;
                ahi.z = fmaxf(ahi.z, 0.f) * scale;
                ahi.w = fmaxf(ahi.w, 0.f) * scale;
                ntst_f4(o, alo);
                ntst_f4(o + 4, ahi);
            }
        }
    }
}

// ---------------- tier-2 per-segment SpMM (old scheme, unchanged) ---------
__device__ __forceinline__ void facc(float4& a, float v, uint2 d) {
    a.x = fmaf(v, __uint_as_float((d.x & 0xFFFFu) << 16), a.x);
    a.y = fmaf(v, __uint_as_float(d.x & 0xFFFF0000u), a.y);
    a.z = fmaf(v, __uint_as_float((d.y & 0xFFFFu) << 16), a.z);
    a.w = fmaf(v, __uint_as_float(d.y & 0xFFFF0000u), a.w);
}

__device__ __forceinline__ float mval(uint2 p, int didMask) {
    int did = (int)(p.x >> DID_SH) & 7;
    return ((didMask >> did) & 1) ? __uint_as_float(p.y) : 0.f;
}
__device__ __forceinline__ uint2 dgather(uint2 p, int l,
    const unsigned short* const* dptr)
{
    const uint2* Dg = reinterpret_cast<const uint2*>(dptr[(p.x >> DID_SH) & 7]);
    return Dg[(size_t)(p.x & COL_MASK) * 16 + l];
}

__device__ __forceinline__ float4 row_accum(
    const uint2* __restrict__ payB, int js, int je,
    const unsigned short* const* dptr, int l, int didMask)
{
    float4 a = make_float4(0.f, 0.f, 0.f, 0.f);
    const int n = je - js;
    if (n <= 0) return a;
    const uint2* base = payB + js;
    uint2 p0 = base[0];
    uint2 p1 = base[(n > 1) ? 1 : 0];
    float v0 = mval(p0, didMask);
    float v1 = (n > 1) ? mval(p1, didMask) : 0.f;
    uint2 d0 = dgather(p0, l, dptr);
    uint2 d1 = dgather(p1, l, dptr);
    int i = 0;
    while (true) {
        int i2 = (i + 2 < n) ? i + 2 : n - 1;
        int i3 = (i + 3 < n) ? i + 3 : n - 1;
        uint2 q0 = base[i2];
        uint2 q1 = base[i3];
        float w0 = (i + 2 < n) ? mval(q0, didMask) : 0.f;
        float w1 = (i + 3 < n) ? mval(q1, didMask) : 0.f;
        uint2 e0 = dgather(q0, l, dptr);
        uint2 e1 = dgather(q1, l, dptr);
        facc(a, v0, d0);
        facc(a, v1, d1);
        i += 2;
        if (i >= n) break;
        v0 = w0; v1 = w1; d0 = e0; d1 = e1;
    }
    return a;
}

__global__ __launch_bounds__(256) void spmm_stream7(
    const uint2* __restrict__ payB, const int* __restrict__ rowoff,
    const int* __restrict__ bend, const unsigned char* __restrict__ rowperm,
    const unsigned short* __restrict__ d0, const unsigned short* __restrict__ d1,
    const unsigned short* __restrict__ d2, const unsigned short* __restrict__ d3,
    const unsigned short* __restrict__ d4, const unsigned short* __restrict__ d5,
    const unsigned short* __restrict__ d6,
    float* __restrict__ out, int tile0, int nrows,
    int firstWrite, int doRelu, float scale, int didMask)
{
    __shared__ const unsigned short* dptr[8];
    const int tid = threadIdx.x;
    if (tid < 8) {
        const unsigned short* tbl[8] = {d0, d1, d2, d3, d4, d5, d6, d0};
        dptr[tid] = tbl[tid];
    }
    __syncthreads();

    const int t = tile0 + blockIdx.x;
    const int qw = tid >> 4, l = tid & 15;
    const int row0 = blockIdx.x * RPB;
    const int rbase = t * RPB;
    const int bendt = bend[t];
    const unsigned char* perm = rowperm + (size_t)t * RPB;

    #pragma unroll 1
    for (int rr = 0; rr < 8; ++rr) {
        const int lr = perm[rr * 16 + qw];
        const int row = row0 + lr;
        const int js = rowoff[rbase + lr];
        const int je = (lr == 127) ? bendt : rowoff[rbase + lr + 1];
        float4 a = row_accum(payB, js, je, dptr, l, didMask);

        if (row < nrows) {
            float* o = out + (size_t)row * 64 + l * 4;
            if (!firstWrite) {
                float4 cur = *reinterpret_cast<float4*>(o);
                a.x += cur.x; a.y += cur.y; a.z += cur.z; a.w += cur.w;
            }
            if (doRelu) {
                a.x = fmaxf(a.x, 0.f) * scale;
                a.y = fmaxf(a.y, 0.f) * scale;
                a.z = fmaxf(a.z, 0.f) * scale;
                a.w = fmaxf(a.w, 0.f) * scale;
            }
            ntst_f4(o, a);
        }
    }
}

extern "C" void kernel_launch(void* const* d_in, const int* in_sizes, int n_in,
                              void* d_out, int out_size, void* d_ws, size_t ws_size,
                              hipStream_t stream)
{
    const float* X0 = (const float*)d_in[0];
    const float* X1 = (const float*)d_in[1];
    const float* X2 = (const float*)d_in[2];
    const int N0 = in_sizes[0] / 64;
    const int N1 = in_sizes[1] / 64;
    const int N2 = in_sizes[2] / 64;

    auto Wp = [&](int i) { return (const float*)d_in[24 + 2 * i]; };
    auto bp = [&](int i) { return (const float*)d_in[25 + 2 * i]; };
    auto Sr = [&](int i) { return (const int*)d_in[3 + 3 * i]; };
    auto Sc = [&](int i) { return (const int*)d_in[4 + 3 * i]; };
    auto Sv = [&](int i) { return (const float*)d_in[5 + 3 * i]; };
    auto Sn = [&](int i) { return in_sizes[3 + 3 * i]; };

    const size_t offY1 = (size_t)N0 * 64;
    const size_t offY2 = (size_t)(N0 + N1) * 64;
    const float TH = 1.0f / 3.0f;

    const int NB0 = (N0 + RPB - 1) / RPB;
    const int NB1 = (N1 + RPB - 1) / RPB;
    const int NB2 = (N2 + RPB - 1) / RPB;

    float* out = (float*)d_out;
    auto align256 = [](size_t x) { return (x + 255) & ~(size_t)255; };

    // -------- W fragment precompute (all 7 sets, once) --------
    const size_t FRAG_SET = 16384;  // ushorts per set (32 KB)
    const size_t fragB = align256(7 * FRAG_SET * sizeof(unsigned short));
    if (ws_size <= fragB) return;   // pathological; cannot run
    unsigned short* wfrags = (unsigned short*)d_ws;
    char* ws = (char*)d_ws + fragB;
    const size_t ws_avail = ws_size - fragB;
    auto wf = [&](int i) { return wfrags + (size_t)i * FRAG_SET; };

    WAll wa;
    for (int i = 0; i < 7; ++i) wa.w[i] = Wp(i);
    winit<<<7, 256, 0, stream>>>(wa, wfrags);

    // -------- tier 1: everything at once --------
    const int NBall = NB0 + NB1 + NB2;
    const int NGall = (NBall + 7) / 8;
    const int nnzAll = Sn(0)+Sn(1)+Sn(2)+Sn(3)+Sn(4)+Sn(5)+Sn(6);
    const size_t payT1 = align256((size_t)nnzAll * sizeof(uint2));
    const size_t cntT1 = align256((size_t)(NBall + 8) * sizeof(int));
    const size_t rowT1 = align256((size_t)NGall * 1024 * sizeof(int));
    const size_t permT1 = align256((size_t)NGall * 1024);
    const size_t ghT1 = align256((size_t)GRID_BIN * NGall * sizeof(int));
    const size_t denseT1 = ((size_t)2*N0 + 3*N1 + 2*N2) * 64 * sizeof(unsigned short);
    const size_t regionT1 = denseT1 > payT1 ? denseT1 : payT1;  // dense ∪ payA
    const size_t needT1 = payT1 + 4 * cntT1 + rowT1 + permT1 + ghT1 + regionT1;
    const long long denseRows = (long long)2*N0 + 3LL*N1 + 2LL*N2;

    if (ws_avail >= needT1 && NBall <= MAXNB && denseRows < (1LL << 21)) {
        uint2* payB  = (uint2*)ws;
        int* goff    = (int*)(ws + payT1);
        int* gcur    = (int*)(ws + payT1 + 1 * cntT1);
        int* bend    = (int*)(ws + payT1 + 2 * cntT1);
        int* gcount  = (int*)(ws + payT1 + 3 * cntT1);
        int* rowoff  = (int*)(ws + payT1 + 4 * cntT1);
        unsigned char* rowperm = (unsigned char*)(ws + payT1 + 4 * cntT1 + rowT1);
        int* ghist   = (int*)(ws + payT1 + 4 * cntT1 + rowT1 + permT1);
        char* region = ws + payT1 + 4 * cntT1 + rowT1 + permT1 + ghT1;
        uint2* payA  = (uint2*)region;                // dead after sort_grpC
        unsigned short* db = (unsigned short*)region; // gemms write after sort
        unsigned short* dn2n = db;
        unsigned short* de2n = dn2n + (size_t)N0 * 64;
        unsigned short* dn2e = de2n + (size_t)N1 * 64;
        unsigned short* de2e = dn2e + (size_t)N0 * 64;
        unsigned short* dt2e = de2e + (size_t)N1 * 64;
        unsigned short* de2t = dt2e + (size_t)N2 * 64;
        unsigned short* dt2t = de2t + (size_t)N1 * 64;

        Bin7 B;
        // did: 0 n2n(L0) 1 e2n(D1invB1) 2 n2e(D2B1TD1inv) 3 e2e(L1) 4 t2e(B2D3) 5 e2t(B2TD2inv) 6 t2t(L2)
        B.r0 = Sr(0); B.c0 = Sc(0); B.v0 = Sv(0);
        B.r1 = Sr(3); B.c1 = Sc(3); B.v1 = Sv(3);
        B.r2 = Sr(4); B.c2 = Sc(4); B.v2 = Sv(4);
        B.r3 = Sr(1); B.c3 = Sc(1); B.v3 = Sv(1);
        B.r4 = Sr(6); B.c4 = Sc(6); B.v4 = Sv(6);
        B.r5 = Sr(5); B.c5 = Sc(5); B.v5 = Sv(5);
        B.r6 = Sr(2); B.c6 = Sc(2); B.v6 = Sv(2);
        B.p1 = Sn(0);
        B.p2 = B.p1 + Sn(3);
        B.p3 = B.p2 + Sn(4);
        B.p4 = B.p3 + Sn(1);
        B.p5 = B.p4 + Sn(6);
        B.p6 = B.p5 + Sn(5);
        B.p7 = B.p6 + Sn(2);
        B.t0 = 0;   B.t1 = 0;
        B.t2 = NB0; B.t3 = NB0; B.t4 = NB0;
        B.t5 = NB0 + NB1; B.t6 = NB0 + NB1;

        CBase cb;   // row base of each did's dense table in the combined table
        cb.b[0] = 0;
        cb.b[1] = N0;
        cb.b[2] = N0 + N1;
        cb.b[3] = 2*N0 + N1;
        cb.b[4] = 2*N0 + 2*N1;
        cb.b[5] = 2*N0 + 2*N1 + N2;
        cb.b[6] = 2*N0 + 3*N1 + N2;
        cb.b[7] = 0;

        const int chunk = (B.p7 + GRID_BIN - 1) / GRID_BIN;
        hipMemsetAsync(gcount, 0, (size_t)NGall * sizeof(int), stream);
        bhist_grp<<<GRID_BIN, 1024, 0, stream>>>(B, gcount, ghist, NGall, chunk);
        scan_small<<<1, 1024, 0, stream>>>(gcount, goff, gcur, NGall);
        scatter_grpC<<<GRID_BIN, 1024, 0, stream>>>(B, cb, gcur, ghist, payA,
                                                    NGall, chunk);
        sort_grpC<<<NGall, 1024, 0, stream>>>(payA, goff, gcur, rowoff, bend,
                                              payB, rowperm, NBall);

        gemm_powcat_mfma<<<(N0 + 63) / 64, 256, 0, stream>>>(
            X0, N0, 2,
            wf(0), bp(0), dn2n,
            wf(1), bp(1), dn2e,
            wf(0), bp(0), dn2n);
        gemm_powcat_mfma<<<(N1 + 63) / 64, 256, 0, stream>>>(
            X1, N1, 3,
            wf(3), bp(3), de2n,
            wf(2), bp(2), de2e,
            wf(4), bp(4), de2t);
        gemm_powcat_mfma<<<(N2 + 63) / 64, 256, 0, stream>>>(
            X2, N2, 2,
            wf(5), bp(5), dt2e,
            wf(6), bp(6), dt2t,
            wf(5), bp(5), dt2e);

        const int grid = NBall < SPMM_GRID ? NBall : SPMM_GRID;
        spmm_stream_allC<<<grid, 256, 0, stream>>>(payB, rowoff, bend, rowperm,
            db, out, NB0, NB0 + NB1, NBall, N0, N1, N2);
        return;
    }

    // -------- tier 2: two-group phased layout (old did-encoded scheme) ----
    const int NBtotA = NB0 + NB2;
    const int NBmax = NBtotA > NB1 ? NBtotA : NB1;
    const int NGmax = (NBmax + 7) / 8;
    const int nnzA = Sn(0) + Sn(3) + Sn(5) + Sn(2);
    const int nnzB = Sn(4) + Sn(6) + Sn(1);
    const int nnzMax = nnzA > nnzB ? nnzA : nnzB;

    const size_t payBsz = align256((size_t)nnzMax * sizeof(uint2));
    const size_t cntB = align256((size_t)(NBmax + 8) * sizeof(int));
    const size_t rowB = align256((size_t)NGmax * 1024 * sizeof(int));
    const size_t permB = align256((size_t)NGmax * 1024);
    const size_t ghB = align256((size_t)GRID_BIN * NGmax * sizeof(int));
    const size_t denseOff = payBsz + 4 * cntB + rowB + permB + ghB;

    uint2* bpayB = (uint2*)ws;
    int* goff    = (int*)(ws + payBsz);
    int* gcur    = (int*)(ws + payBsz + 1 * cntB);
    int* bend    = (int*)(ws + payBsz + 2 * cntB);
    int* gcount  = (int*)(ws + payBsz + 3 * cntB);
    int* rowoff  = (int*)(ws + payBsz + 4 * cntB);
    unsigned char* rowperm = (unsigned char*)(ws + payBsz + 4 * cntB + rowB);
    int* ghist   = (int*)(ws + payBsz + 4 * cntB + rowB + permB);
    unsigned short* dense = (unsigned short*)(ws + denseOff);
    uint2* payA  = (uint2*)dense;   // transient, dead before gemms write dense

    const size_t need_full = denseOff +
        ((size_t)N0 + N2 + N1) * 64 * sizeof(unsigned short);
    const bool fullB = (ws_avail >= need_full);

    // ---- group A: did 0=n2n(Y0) 1=e2n(Y0) 2=e2t(Y2) 3=t2t(Y2)
    {
        Bin7 B;
        B.r0 = Sr(0); B.c0 = Sc(0); B.v0 = Sv(0);
        B.r1 = Sr(3); B.c1 = Sc(3); B.v1 = Sv(3);
        B.r2 = Sr(5); B.c2 = Sc(5); B.v2 = Sv(5);
        B.r3 = Sr(2); B.c3 = Sc(2); B.v3 = Sv(2);
        B.r4 = B.r3; B.c4 = B.c3; B.v4 = B.v3;
        B.r5 = B.r3; B.c5 = B.c3; B.v5 = B.v3;
        B.r6 = B.r3; B.c6 = B.c3; B.v6 = B.v3;
        B.p1 = Sn(0);
        B.p2 = B.p1 + Sn(3);
        B.p3 = B.p2 + Sn(5);
        B.p4 = B.p3 + Sn(2);
        B.p5 = B.p4; B.p6 = B.p4; B.p7 = B.p4;
        B.t0 = 0; B.t1 = 0; B.t2 = NB0; B.t3 = NB0;
        B.t4 = NB0; B.t5 = NB0; B.t6 = NB0;

        const int NGA = (NBtotA + 7) / 8;
        const int chunk = (B.p7 + GRID_BIN - 1) / GRID_BIN;
        hipMemsetAsync(gcount, 0, (size_t)NGA * sizeof(int), stream);
        bhist_grp<<<GRID_BIN, 1024, 0, stream>>>(B, gcount, ghist, NGA, chunk);
        scan_small<<<1, 1024, 0, stream>>>(gcount, goff, gcur, NGA);
        scatter_grp<<<GRID_BIN, 1024, 0, stream>>>(B, gcur, ghist, payA, NGA, chunk);
        sort_grp<<<NGA, 1024, 0, stream>>>(payA, goff, gcur, rowoff, bend,
                                           bpayB, rowperm, NBtotA);

        unsigned short* dn2n = dense;
        unsigned short* de2n = dense + (size_t)N0 * 64;
        gemm_powcat_mfma<<<(N0 + 63) / 64, 256, 0, stream>>>(
            X0, N0, 1, wf(0), bp(0), dn2n,
            wf(0), bp(0), dn2n, wf(0), bp(0), dn2n);
        gemm_powcat_mfma<<<(N1 + 63) / 64, 256, 0, stream>>>(
            X1, N1, 1, wf(3), bp(3), de2n,
            wf(3), bp(3), de2n, wf(3), bp(3), de2n);
        spmm_stream7<<<NB0, 256, 0, stream>>>(bpayB, rowoff, bend, rowperm,
            dn2n, de2n, dn2n, dn2n, dn2n, dn2n, dn2n,
            out, 0, N0, 1, 1, 0.5f, 0x7F);

        unsigned short* de2t = dense;
        unsigned short* dt2t = dense + (size_t)N1 * 64;
        gemm_powcat_mfma<<<(N1 + 63) / 64, 256, 0, stream>>>(
            X1, N1, 1, wf(4), bp(4), de2t,
            wf(4), bp(4), de2t, wf(4), bp(4), de2t);
        gemm_powcat_mfma<<<(N2 + 63) / 64, 256, 0, stream>>>(
            X2, N2, 1, wf(6), bp(6), dt2t,
            wf(6), bp(6), dt2t, wf(6), bp(6), dt2t);
        spmm_stream7<<<NB2, 256, 0, stream>>>(bpayB, rowoff, bend, rowperm,
            de2t, de2t, de2t, dt2t, de2t, de2t, de2t,
            out + offY2, NB0, N2, 1, 1, 0.5f, 0x7F);
    }

    // ---- group B (Y1): did 0=n2e 1=t2e 2=e2e
    {
        Bin7 B;
        B.r0 = Sr(4); B.c0 = Sc(4); B.v0 = Sv(4);
        B.r1 = Sr(6); B.c1 = Sc(6); B.v1 = Sv(6);
        B.r2 = Sr(1); B.c2 = Sc(1); B.v2 = Sv(1);
        B.r3 = B.r2; B.c3 = B.c2; B.v3 = B.v2;
        B.r4 = B.r2; B.c4 = B.c2; B.v4 = B.v2;
        B.r5 = B.r2; B.c5 = B.c2; B.v5 = B.v2;
        B.r6 = B.r2; B.c6 = B.c2; B.v6 = B.v2;
        B.p1 = Sn(4);
        B.p2 = B.p1 + Sn(6);
        B.p3 = B.p2 + Sn(1);
        B.p4 = B.p3; B.p5 = B.p3; B.p6 = B.p3; B.p7 = B.p3;
        B.t0 = 0; B.t1 = 0; B.t2 = 0; B.t3 = 0; B.t4 = 0; B.t5 = 0; B.t6 = 0;

        const int NGB = (NB1 + 7) / 8;
        const int chunk = (B.p7 + GRID_BIN - 1) / GRID_BIN;
        hipMemsetAsync(gcount, 0, (size_t)NGB * sizeof(int), stream);
        bhist_grp<<<GRID_BIN, 1024, 0, stream>>>(B, gcount, ghist, NGB, chunk);
        scan_small<<<1, 1024, 0, stream>>>(gcount, goff, gcur, NGB);
        scatter_grp<<<GRID_BIN, 1024, 0, stream>>>(B, gcur, ghist, payA, NGB, chunk);
        sort_grp<<<NGB, 1024, 0, stream>>>(payA, goff, gcur, rowoff, bend,
                                           bpayB, rowperm, NB1);

        if (fullB) {
            unsigned short* dn2e = dense;
            unsigned short* dt2e = dense + (size_t)N0 * 64;
            unsigned short* de2e = dense + ((size_t)N0 + N2) * 64;
            gemm_powcat_mfma<<<(N0 + 63) / 64, 256, 0, stream>>>(
                X0, N0, 1, wf(1), bp(1), dn2e,
                wf(1), bp(1), dn2e, wf(1), bp(1), dn2e);
            gemm_powcat_mfma<<<(N2 + 63) / 64, 256, 0, stream>>>(
                X2, N2, 1, wf(5), bp(5), dt2e,
                wf(5), bp(5), dt2e, wf(5), bp(5), dt2e);
            gemm_powcat_mfma<<<(N1 + 63) / 64, 256, 0, stream>>>(
                X1, N1, 1, wf(2), bp(2), de2e,
                wf(2), bp(2), de2e, wf(2), bp(2), de2e);
            spmm_stream7<<<NB1, 256, 0, stream>>>(bpayB, rowoff, bend, rowperm,
                dn2e, dt2e, de2e, dn2e, dn2e, dn2e, dn2e,
                out + offY1, 0, N1, 1, 1, TH, 0x7F);
        } else {
            unsigned short* dn2e = dense;
            unsigned short* dt2e = dense + (size_t)N0 * 64;
            gemm_powcat_mfma<<<(N0 + 63) / 64, 256, 0, stream>>>(
                X0, N0, 1, wf(1), bp(1), dn2e,
                wf(1), bp(1), dn2e, wf(1), bp(1), dn2e);
            gemm_powcat_mfma<<<(N2 + 63) / 64, 256, 0, stream>>>(
                X2, N2, 1, wf(5), bp(5), dt2e,
                wf(5), bp(5), dt2e, wf(5), bp(5), dt2e);
            spmm_stream7<<<NB1, 256, 0, stream>>>(bpayB, rowoff, bend, rowperm,
                dn2e, dt2e, dn2e, dn2e, dn2e, dn2e, dn2e,
                out + offY1, 0, N1, 1, 0, 0.f, 0x3);
            unsigned short* de2e = dense;
            gemm_powcat_mfma<<<(N1 + 63) / 64, 256, 0, stream>>>(
                X1, N1, 1, wf(2), bp(2), de2e,
                wf(2), bp(2), de2e, wf(2), bp(2), de2e);
            spmm_stream7<<<NB1, 256, 0, stream>>>(bpayB, rowoff, bend, rowperm,
                de2e, de2e, de2e, de2e, de2e, de2e, de2e,
                out + offY1, 0, N1, 0, 1, TH, 0x4);
        }
    }
}